// Round 9
// baseline (647.292 us; speedup 1.0000x reference)
//
#include <hip/hip_runtime.h>
#include <hip/hip_bf16.h>
#include <math.h>

// ---------------------------------------------------------------------------
// PMLP_GCN forward:  3x (GEMM -> GCN-agg[+bias]) with BN+ReLU between,
// log_softmax at the end.  N=50000 E=640000 IN=500 HID=128 OUT=64, f32.
// R8: R7's fused agg+BN-stats, but agg grid 1024 -> 4096 blocks (R7 regression
//     was occupancy: 4 blocks/CU halved latency hiding on the gather).
// ---------------------------------------------------------------------------

#define EPS_BN 1e-5f

typedef __attribute__((ext_vector_type(8))) _Float16 f16x8;
typedef __attribute__((ext_vector_type(4))) _Float16 f16x4;
typedef __attribute__((ext_vector_type(2))) _Float16 f16x2;
typedef __attribute__((ext_vector_type(4))) float    f32x4;

__device__ __forceinline__ void gload16(const void* g, void* l) {
    __builtin_amdgcn_global_load_lds(
        (const __attribute__((address_space(1))) void*)g,
        (__attribute__((address_space(3))) void*)l, 16, 0, 0);
}

// ---------------- graph prep ----------------

__global__ void count_k(const int* __restrict__ src, const int* __restrict__ dst,
                        int* __restrict__ cnt, int E) {
    int e = blockIdx.x * 256 + threadIdx.x;
    if (e >= E) return;
    int s = src[e], d = dst[e];
    if (s != d) atomicAdd(&cnt[d], 1);
}

__global__ void prep_k(const int* __restrict__ cnt, float* __restrict__ dinv,
                       float* __restrict__ invdeg, int n) {
    int i = blockIdx.x * 256 + threadIdx.x;
    if (i >= n) return;
    float deg = (float)cnt[i] + 1.0f;   // +1 for added self loop
    dinv[i]   = rsqrtf(deg);
    invdeg[i] = 1.0f / deg;
}

// 3-kernel exclusive prefix scan over cnt[n] -> row_start
__global__ void scan1_k(const int* __restrict__ cnt, int* __restrict__ within,
                        int* __restrict__ btot, int n) {
    __shared__ int s[512];
    int tid = threadIdx.x;
    int i = blockIdx.x * 512 + tid;
    int val = (i < n) ? cnt[i] : 0;
    s[tid] = val;
    __syncthreads();
    for (int off = 1; off < 512; off <<= 1) {
        int v = (tid >= off) ? s[tid - off] : 0;
        __syncthreads();
        s[tid] += v;
        __syncthreads();
    }
    if (i < n) within[i] = s[tid] - val;   // exclusive
    if (tid == 511) btot[blockIdx.x] = s[511];
}

__global__ void scan2_k(const int* __restrict__ btot, int* __restrict__ boff, int nblk) {
    if (threadIdx.x == 0) {
        int run = 0;
        for (int b = 0; b < nblk; ++b) { boff[b] = run; run += btot[b]; }
    }
}

__global__ void scan3_k(const int* __restrict__ within, const int* __restrict__ boff,
                        int* __restrict__ row_start, int* __restrict__ cursor, int n) {
    int i = blockIdx.x * 256 + threadIdx.x;
    if (i >= n) return;
    int v = within[i] + boff[i >> 9];
    row_start[i] = v;
    cursor[i]    = v;
}

__global__ void fill_k(const int* __restrict__ src, const int* __restrict__ dst,
                       const float* __restrict__ dinv, int* __restrict__ cursor,
                       int* __restrict__ eidx, float* __restrict__ ew, int E) {
    int e = blockIdx.x * 256 + threadIdx.x;
    if (e >= E) return;
    int s = src[e], d = dst[e];
    if (s == d) return;
    int pos = atomicAdd(&cursor[d], 1);
    eidx[pos] = s;
    ew[pos]   = dinv[s] * dinv[d];
}

// ---- f32 -> f16 with K padded to Kp (pad zero-filled); used for W and x ----

__global__ void wcvt_k(const float* __restrict__ W, _Float16* __restrict__ Wh,
                       int rows, int K, int Kp) {
    int q = Kp >> 2;
    long long idx = (long long)blockIdx.x * 256 + threadIdx.x;
    if (idx >= (long long)rows * q) return;
    int r = (int)(idx / q), k4 = (int)(idx - (long long)r * q) * 4;
    f16x4 h = {(_Float16)0.f, (_Float16)0.f, (_Float16)0.f, (_Float16)0.f};
    if (k4 < K) {                        // K%4==0 -> all-or-none
        float4 v = *(const float4*)(W + (size_t)r * K + k4);
        h[0] = (_Float16)v.x; h[1] = (_Float16)v.y;
        h[2] = (_Float16)v.z; h[3] = (_Float16)v.w;
    }
    *(f16x4*)(Wh + (size_t)r * Kp + k4) = h;
}

// ---------------- MFMA GEMM: C[M,NC] = A[M,Kp] * Wh[NC,Kp]^T ----------------
// A, Wh f16 (pre-converted, Kp padded with zeros). f32 accumulate, f16 out.
// Block: 256 thr = 4 waves; tile 64 x NC; chunk 64.
// Staging: global_load_lds (16B/lane, 1KB/inst, no VGPR round-trip).
// LDS image: row stride 128B, 16B-slot s of row holds global slot s^(row&7)
// (inverse-swizzled GLOBAL address; LDS dest linear). Fragment ds_read
// applies the same XOR -> 2-way max bank aliasing (free).
// Pipeline: stage(c+1); compute(c); s_waitcnt vmcnt(0); s_barrier.

template <int NC>
__global__ __launch_bounds__(256) void mgemm_k(const _Float16* __restrict__ A,
                                               const _Float16* __restrict__ Wh,
                                               _Float16* __restrict__ C,
                                               int M, int Kp) {
    constexpr int CT = NC / 16;            // col frags per wave
    constexpr int WJ = NC / 32;            // W gload insts per wave
    __shared__ __align__(16) _Float16 As[2][64 * 64];
    __shared__ __align__(16) _Float16 Ws[2][NC * 64];

    const int tid  = threadIdx.x;
    const int lane = tid & 63, wave = tid >> 6;
    const int lrow = lane & 15, kg = lane >> 4;
    const int row0 = blockIdx.x * 64;

    f32x4 acc[CT] = {};

    auto stage = [&](int c0, int b) {
        const int k0 = c0 * 64;
        // A tile: 64 rows x 128B -> 8 insts (2 per wave)
        #pragma unroll
        for (int j = 0; j < 2; ++j) {
            int li  = wave * 128 + j * 64 + lane;      // 0..511
            int row = li >> 3, s = li & 7;
            int gr  = row0 + row;
            int gs  = s ^ (row & 7);
            if (gr < M)
                gload16(A + (size_t)gr * Kp + k0 + gs * 8,
                        (char*)&As[b][0] + (wave * 128 + j * 64) * 16);
        }
        // W tile: NC rows x 128B -> NC/8 insts (WJ per wave)
        #pragma unroll
        for (int j = 0; j < WJ; ++j) {
            int li  = wave * (WJ * 64) + j * 64 + lane;
            int row = li >> 3, s = li & 7;
            int gs  = s ^ (row & 7);
            gload16(Wh + (size_t)row * Kp + k0 + gs * 8,
                    (char*)&Ws[b][0] + (wave * WJ + j) * 1024);
        }
    };

    auto compute = [&](int b) {
        const char* AsB = (const char*)&As[b][0];
        const char* WsB = (const char*)&Ws[b][0];
        #pragma unroll
        for (int ks = 0; ks < 2; ++ks) {
            const int cbase = ks * 64 + kg * 16;       // byte offset in row
            f16x8 af, bf[CT];
            {
                int row = wave * 16 + lrow;
                af = *(const f16x8*)(AsB + row * 128 + (cbase ^ ((row & 7) << 4)));
            }
            #pragma unroll
            for (int ct = 0; ct < CT; ++ct) {
                int row = ct * 16 + lrow;
                bf[ct] = *(const f16x8*)(WsB + row * 128 + (cbase ^ ((row & 7) << 4)));
            }
            #pragma unroll
            for (int ct = 0; ct < CT; ++ct)
                acc[ct] = __builtin_amdgcn_mfma_f32_16x16x32_f16(
                    af, bf[ct], acc[ct], 0, 0, 0);
        }
    };

    const int nchunk = Kp >> 6;            // Kp % 64 == 0
    stage(0, 0);
    asm volatile("s_waitcnt vmcnt(0)" ::: "memory");
    __builtin_amdgcn_s_barrier();
    __builtin_amdgcn_sched_barrier(0);

    for (int c = 0; c < nchunk; ++c) {
        const int b = c & 1;
        if (c + 1 < nchunk) stage(c + 1, b ^ 1);   // loads fly during compute
        compute(b);
        if (c + 1 < nchunk) {
            asm volatile("s_waitcnt vmcnt(0)" ::: "memory");
            __builtin_amdgcn_s_barrier();
            __builtin_amdgcn_sched_barrier(0);
        }
    }

    // ---- epilogue: D lane map col=lane&15, row=(lane>>4)*4+r ----
    #pragma unroll
    for (int r = 0; r < 4; ++r) {
        int grow = row0 + wave * 16 + kg * 4 + r;
        if (grow >= M) continue;
        #pragma unroll
        for (int ct = 0; ct < CT; ++ct)
            C[(size_t)grow * NC + ct * 16 + lrow] = (_Float16)acc[ct][r];
    }
}

// ------------- GCN aggregation + fused BN stats (gather over CSR) -------------
// out[i] = sum_{e: dst=i} w_e * h[src_e] + invdeg[i]*h[i] + bias   (f16 out)
// Grid-stride: 4096 blocks x 4 waves (16 blocks/CU queued; 8 resident =
// 32 waves/CU at VGPR~20). Each thread owns cols (2*lane, 2*lane+1);
// accumulates (sum, sumsq) in f32; block LDS reduce -> 256 atomics/block.

__global__ void agg128_k(const _Float16* __restrict__ h, const float* __restrict__ invdeg,
                         const int* __restrict__ row_start, const int* __restrict__ cnt,
                         const int* __restrict__ eidx, const float* __restrict__ ew,
                         const float* __restrict__ bias, _Float16* __restrict__ out,
                         float* __restrict__ gsum, float* __restrict__ gsq, int n) {
    const int wv = threadIdx.x >> 6, lane = threadIdx.x & 63;
    const int c = lane * 2;
    const float b0 = bias[c], b1 = bias[c + 1];

    float s0 = 0.f, s1 = 0.f, q0 = 0.f, q1 = 0.f;

    for (int i = blockIdx.x * 4 + wv; i < n; i += gridDim.x * 4) {
        const int st = row_start[i], en = st + cnt[i];
        const float id = invdeg[i];
        f16x2 hv = *(const f16x2*)(h + (size_t)i * 128 + c);
        float a0 = fmaf(id, (float)hv[0], b0);
        float a1 = fmaf(id, (float)hv[1], b1);
        int p = st;
        for (; p + 3 < en; p += 4) {
            int s_0 = eidx[p], s_1 = eidx[p + 1], s_2 = eidx[p + 2], s_3 = eidx[p + 3];
            float w0 = ew[p], w1 = ew[p + 1], w2 = ew[p + 2], w3 = ew[p + 3];
            f16x2 v0 = *(const f16x2*)(h + (size_t)s_0 * 128 + c);
            f16x2 v1 = *(const f16x2*)(h + (size_t)s_1 * 128 + c);
            f16x2 v2 = *(const f16x2*)(h + (size_t)s_2 * 128 + c);
            f16x2 v3 = *(const f16x2*)(h + (size_t)s_3 * 128 + c);
            a0 = fmaf(w0, (float)v0[0], a0); a1 = fmaf(w0, (float)v0[1], a1);
            a0 = fmaf(w1, (float)v1[0], a0); a1 = fmaf(w1, (float)v1[1], a1);
            a0 = fmaf(w2, (float)v2[0], a0); a1 = fmaf(w2, (float)v2[1], a1);
            a0 = fmaf(w3, (float)v3[0], a0); a1 = fmaf(w3, (float)v3[1], a1);
        }
        for (; p < en; ++p) {
            int s_0 = eidx[p]; float w0 = ew[p];
            f16x2 v0 = *(const f16x2*)(h + (size_t)s_0 * 128 + c);
            a0 = fmaf(w0, (float)v0[0], a0); a1 = fmaf(w0, (float)v0[1], a1);
        }
        // stats from pre-rounding f32 values
        s0 += a0; s1 += a1;
        q0 = fmaf(a0, a0, q0); q1 = fmaf(a1, a1, q1);
        f16x2 o; o[0] = (_Float16)a0; o[1] = (_Float16)a1;
        *(f16x2*)(out + (size_t)i * 128 + c) = o;
    }

    // ---- block reduce across the 4 waves (per column pair) ----
    __shared__ float red[4][4][64];      // [quantity][wave][lane]
    red[0][wv][lane] = s0; red[1][wv][lane] = s1;
    red[2][wv][lane] = q0; red[3][wv][lane] = q1;
    __syncthreads();
    if (threadIdx.x < 64) {
        int l = threadIdx.x;
        float t0 = red[0][0][l] + red[0][1][l] + red[0][2][l] + red[0][3][l];
        float t1 = red[1][0][l] + red[1][1][l] + red[1][2][l] + red[1][3][l];
        float u0 = red[2][0][l] + red[2][1][l] + red[2][2][l] + red[2][3][l];
        float u1 = red[3][0][l] + red[3][1][l] + red[3][2][l] + red[3][3][l];
        atomicAdd(&gsum[2 * l],     t0);
        atomicAdd(&gsum[2 * l + 1], t1);
        atomicAdd(&gsq[2 * l],      u0);
        atomicAdd(&gsq[2 * l + 1],  u1);
    }
}

// ---- classifier agg (64 cols) with log_softmax fused (row == wave) ----

__global__ void aggsm_k(const _Float16* __restrict__ h, const float* __restrict__ invdeg,
                        const int* __restrict__ row_start, const int* __restrict__ cnt,
                        const int* __restrict__ eidx, const float* __restrict__ ew,
                        const float* __restrict__ bias, float* __restrict__ out, int n) {
    const int wv = threadIdx.x >> 6, lane = threadIdx.x & 63;
    const int i = blockIdx.x * 4 + wv;
    if (i >= n) return;
    const int st = row_start[i], en = st + cnt[i];
    const float id = invdeg[i];

    float a0 = fmaf(id, (float)h[(size_t)i * 64 + lane], bias[lane]);
    int p = st;
    for (; p + 3 < en; p += 4) {
        int s0 = eidx[p], s1 = eidx[p + 1], s2 = eidx[p + 2], s3 = eidx[p + 3];
        float w0 = ew[p], w1 = ew[p + 1], w2 = ew[p + 2], w3 = ew[p + 3];
        float v0 = (float)h[(size_t)s0 * 64 + lane];
        float v1 = (float)h[(size_t)s1 * 64 + lane];
        float v2 = (float)h[(size_t)s2 * 64 + lane];
        float v3 = (float)h[(size_t)s3 * 64 + lane];
        a0 = fmaf(w0, v0, a0); a0 = fmaf(w1, v1, a0);
        a0 = fmaf(w2, v2, a0); a0 = fmaf(w3, v3, a0);
    }
    for (; p < en; ++p)
        a0 = fmaf(ew[p], (float)h[(size_t)eidx[p] * 64 + lane], a0);

    // fused log_softmax over the 64-wide row held by this wave
    float m = a0;
    #pragma unroll
    for (int d = 32; d >= 1; d >>= 1) m = fmaxf(m, __shfl_xor(m, d, 64));
    float e = __expf(a0 - m);
    float s = e;
    #pragma unroll
    for (int d = 32; d >= 1; d >>= 1) s += __shfl_xor(s, d, 64);
    out[(size_t)i * 64 + lane] = a0 - m - __logf(s);
}

// ---------------- BatchNorm finalize + apply (f16 in/out) ----------------

__global__ void finalize_k(const float* __restrict__ gsum, const float* __restrict__ gsq,
                           float* __restrict__ scale, float* __restrict__ shift, int n) {
    int c = threadIdx.x;   // 128
    float mean = gsum[c] / (float)n;
    float var  = gsq[c] / (float)n - mean * mean;
    float sc   = rsqrtf(var + EPS_BN);
    scale[c] = sc;
    shift[c] = -mean * sc;
}

// BN scale/shift + ReLU, f16 in -> f16 out (16B/lane both ways)
__global__ void norm_k(const _Float16* __restrict__ a, _Float16* __restrict__ o,
                       const float* __restrict__ scale, const float* __restrict__ shift,
                       int total8) {
    int idx = blockIdx.x * 256 + threadIdx.x;
    if (idx >= total8) return;
    f16x8 v = *(const f16x8*)(a + (size_t)idx * 8);
    int c0 = (idx & 15) * 8;
    f16x8 h;
    #pragma unroll
    for (int j = 0; j < 8; ++j)
        h[j] = (_Float16)fmaxf(0.f, fmaf((float)v[j], scale[c0 + j], shift[c0 + j]));
    *(f16x8*)(o + (size_t)idx * 8) = h;
}

// ---------------------------------------------------------------------------

extern "C" void kernel_launch(void* const* d_in, const int* in_sizes, int n_in,
                              void* d_out, int out_size, void* d_ws, size_t ws_size,
                              hipStream_t stream) {
    const float* x  = (const float*)d_in[0];
    const int*   ei = (const int*)d_in[1];
    const float* W0 = (const float*)d_in[2];
    const float* b0 = (const float*)d_in[3];
    const float* W1 = (const float*)d_in[4];
    const float* b1 = (const float*)d_in[5];
    const float* W2 = (const float*)d_in[6];
    const float* b2 = (const float*)d_in[7];

    const int IN = 500;
    const int n = in_sizes[0] / IN;      // 50000
    const int E = in_sizes[1] / 2;       // 640000
    const int* src = ei;
    const int* dst = ei + E;

    // ---- workspace bump allocator (256B aligned) ----
    char* p = (char*)d_ws;
    auto alloc = [&](size_t bytes) -> void* {
        char* r = p;
        p += (bytes + 255) & ~(size_t)255;
        return (void*)r;
    };
    _Float16*  xh      = (_Float16*)alloc((size_t)n * 512 * 2);  // x as f16, K padded
    _Float16*  hb1h    = (_Float16*)alloc((size_t)n * 128 * 2);  // GEMM out / agg in
    _Float16*  hb2a    = (_Float16*)alloc((size_t)n * 128 * 2);  // agg out (f16)
    _Float16*  hb2h    = (_Float16*)alloc((size_t)n * 128 * 2);  // BN out / GEMM in
    _Float16*  W0h     = (_Float16*)alloc((size_t)128 * 512 * 2);
    _Float16*  W1h     = (_Float16*)alloc((size_t)128 * 128 * 2);
    _Float16*  W2h     = (_Float16*)alloc((size_t)64 * 128 * 2);
    int*   deg_cnt  = (int*)alloc((size_t)n * 4);
    float* dinv     = (float*)alloc((size_t)n * 4);
    float* invdeg   = (float*)alloc((size_t)n * 4);
    int*   row_st   = (int*)alloc((size_t)n * 4);
    int*   cursor   = (int*)alloc((size_t)n * 4);
    int*   within   = (int*)alloc((size_t)n * 4);
    int*   btot     = (int*)alloc(256 * 4);
    int*   boff     = (int*)alloc(256 * 4);
    int*   eidx     = (int*)alloc((size_t)E * 4);
    float* ew       = (float*)alloc((size_t)E * 4);
    float* gsum     = (float*)alloc(128 * 4);   // gsum+gsq contiguous: one memset
    float* gsq      = (float*)alloc(128 * 4);
    float* scale    = (float*)alloc(128 * 4);
    float* shift    = (float*)alloc(128 * 4);
    (void)ws_size; (void)n_in; (void)out_size;

    float* out = (float*)d_out;

    const int gE = (E + 255) / 256;
    const int gN = (n + 255) / 256;
    const int nblk = (n + 511) / 512;
    const int gM = (n + 63) / 64;        // 782 blocks
    const int gAgg = 4096;               // grid-stride agg (fused stats)
    const int gA = (n + 3) / 4;          // classifier agg

    // ---- graph prep + f16 conversions (once per call) ----
    hipMemsetAsync(deg_cnt, 0, (size_t)n * 4, stream);
    count_k<<<gE, 256, 0, stream>>>(src, dst, deg_cnt, E);
    prep_k<<<gN, 256, 0, stream>>>(deg_cnt, dinv, invdeg, n);
    scan1_k<<<nblk, 512, 0, stream>>>(deg_cnt, within, btot, n);
    scan2_k<<<1, 64, 0, stream>>>(btot, boff, nblk);
    scan3_k<<<gN, 256, 0, stream>>>(within, boff, row_st, cursor, n);
    fill_k<<<gE, 256, 0, stream>>>(src, dst, dinv, cursor, eidx, ew, E);
    wcvt_k<<<(128 * 512 / 4 + 255) / 256, 256, 0, stream>>>(W0, W0h, 128, 500, 512);
    wcvt_k<<<(128 * 128 / 4 + 255) / 256, 256, 0, stream>>>(W1, W1h, 128, 128, 128);
    wcvt_k<<<(64 * 128 / 4 + 255) / 256, 256, 0, stream>>>(W2, W2h, 64, 128, 128);
    wcvt_k<<<(n * 128 + 255) / 256, 256, 0, stream>>>(x, xh, n, 500, 512);

    // ---- layer 0 ----
    mgemm_k<128><<<gM, 256, 0, stream>>>(xh, W0h, hb1h, n, 512);
    hipMemsetAsync(gsum, 0, 256 * 4, stream);
    agg128_k<<<gAgg, 256, 0, stream>>>(hb1h, invdeg, row_st, deg_cnt, eidx, ew, b0,
                                       hb2a, gsum, gsq, n);
    finalize_k<<<1, 128, 0, stream>>>(gsum, gsq, scale, shift, n);
    norm_k<<<(n * 16 + 255) / 256, 256, 0, stream>>>(hb2a, hb2h, scale, shift, n * 16);

    // ---- layer 1 ----
    mgemm_k<128><<<gM, 256, 0, stream>>>(hb2h, W1h, hb1h, n, 128);
    hipMemsetAsync(gsum, 0, 256 * 4, stream);
    agg128_k<<<gAgg, 256, 0, stream>>>(hb1h, invdeg, row_st, deg_cnt, eidx, ew, b1,
                                       hb2a, gsum, gsq, n);
    finalize_k<<<1, 128, 0, stream>>>(gsum, gsq, scale, shift, n);
    norm_k<<<(n * 16 + 255) / 256, 256, 0, stream>>>(hb2a, hb2h, scale, shift, n * 16);

    // ---- classifier (log_softmax fused into agg) ----
    mgemm_k<64><<<gM, 256, 0, stream>>>(hb2h, W2h, hb1h, n, 128);
    aggsm_k<<<gA, 256, 0, stream>>>(hb1h, invdeg, row_st, deg_cnt, eidx, ew, b2, out, n);
}

// Round 10
// 309.002 us; speedup vs baseline: 2.0948x; 2.0948x over previous
//
#include <hip/hip_runtime.h>
#include <hip/hip_bf16.h>
#include <math.h>

// ---------------------------------------------------------------------------
// PMLP_GCN forward:  3x (GEMM -> GCN-agg[+bias]) with BN+ReLU between,
// log_softmax at the end.  N=50000 E=640000 IN=500 HID=128 OUT=64, f32.
// R9: un-fuse BN stats from agg (R8's atomic tail: 256 atomics/block x 4096
//     blocks = 262k serialized RMW per cache line ~ 110us). agg back to one
//     node/wave x 12500 blocks, f16 out; separate stats16_k reads the f16
//     output with 256 blocks -> atomic tail ~2us.
// ---------------------------------------------------------------------------

#define EPS_BN 1e-5f

typedef __attribute__((ext_vector_type(8))) _Float16 f16x8;
typedef __attribute__((ext_vector_type(4))) _Float16 f16x4;
typedef __attribute__((ext_vector_type(2))) _Float16 f16x2;
typedef __attribute__((ext_vector_type(4))) float    f32x4;

__device__ __forceinline__ void gload16(const void* g, void* l) {
    __builtin_amdgcn_global_load_lds(
        (const __attribute__((address_space(1))) void*)g,
        (__attribute__((address_space(3))) void*)l, 16, 0, 0);
}

// ---------------- graph prep ----------------

__global__ void count_k(const int* __restrict__ src, const int* __restrict__ dst,
                        int* __restrict__ cnt, int E) {
    int e = blockIdx.x * 256 + threadIdx.x;
    if (e >= E) return;
    int s = src[e], d = dst[e];
    if (s != d) atomicAdd(&cnt[d], 1);
}

__global__ void prep_k(const int* __restrict__ cnt, float* __restrict__ dinv,
                       float* __restrict__ invdeg, int n) {
    int i = blockIdx.x * 256 + threadIdx.x;
    if (i >= n) return;
    float deg = (float)cnt[i] + 1.0f;   // +1 for added self loop
    dinv[i]   = rsqrtf(deg);
    invdeg[i] = 1.0f / deg;
}

// 3-kernel exclusive prefix scan over cnt[n] -> row_start
__global__ void scan1_k(const int* __restrict__ cnt, int* __restrict__ within,
                        int* __restrict__ btot, int n) {
    __shared__ int s[512];
    int tid = threadIdx.x;
    int i = blockIdx.x * 512 + tid;
    int val = (i < n) ? cnt[i] : 0;
    s[tid] = val;
    __syncthreads();
    for (int off = 1; off < 512; off <<= 1) {
        int v = (tid >= off) ? s[tid - off] : 0;
        __syncthreads();
        s[tid] += v;
        __syncthreads();
    }
    if (i < n) within[i] = s[tid] - val;   // exclusive
    if (tid == 511) btot[blockIdx.x] = s[511];
}

__global__ void scan2_k(const int* __restrict__ btot, int* __restrict__ boff, int nblk) {
    if (threadIdx.x == 0) {
        int run = 0;
        for (int b = 0; b < nblk; ++b) { boff[b] = run; run += btot[b]; }
    }
}

__global__ void scan3_k(const int* __restrict__ within, const int* __restrict__ boff,
                        int* __restrict__ row_start, int* __restrict__ cursor, int n) {
    int i = blockIdx.x * 256 + threadIdx.x;
    if (i >= n) return;
    int v = within[i] + boff[i >> 9];
    row_start[i] = v;
    cursor[i]    = v;
}

__global__ void fill_k(const int* __restrict__ src, const int* __restrict__ dst,
                       const float* __restrict__ dinv, int* __restrict__ cursor,
                       int* __restrict__ eidx, float* __restrict__ ew, int E) {
    int e = blockIdx.x * 256 + threadIdx.x;
    if (e >= E) return;
    int s = src[e], d = dst[e];
    if (s == d) return;
    int pos = atomicAdd(&cursor[d], 1);
    eidx[pos] = s;
    ew[pos]   = dinv[s] * dinv[d];
}

// ---- f32 -> f16 with K padded to Kp (pad zero-filled); used for W and x ----

__global__ void wcvt_k(const float* __restrict__ W, _Float16* __restrict__ Wh,
                       int rows, int K, int Kp) {
    int q = Kp >> 2;
    long long idx = (long long)blockIdx.x * 256 + threadIdx.x;
    if (idx >= (long long)rows * q) return;
    int r = (int)(idx / q), k4 = (int)(idx - (long long)r * q) * 4;
    f16x4 h = {(_Float16)0.f, (_Float16)0.f, (_Float16)0.f, (_Float16)0.f};
    if (k4 < K) {                        // K%4==0 -> all-or-none
        float4 v = *(const float4*)(W + (size_t)r * K + k4);
        h[0] = (_Float16)v.x; h[1] = (_Float16)v.y;
        h[2] = (_Float16)v.z; h[3] = (_Float16)v.w;
    }
    *(f16x4*)(Wh + (size_t)r * Kp + k4) = h;
}

// ---------------- MFMA GEMM: C[M,NC] = A[M,Kp] * Wh[NC,Kp]^T ----------------
// A, Wh f16 (pre-converted, Kp padded with zeros). f32 accumulate, f16 out.
// Block: 256 thr = 4 waves; tile 64 x NC; chunk 64.
// Staging: global_load_lds (16B/lane, 1KB/inst, no VGPR round-trip).
// LDS image: row stride 128B, 16B-slot s of row holds global slot s^(row&7)
// (inverse-swizzled GLOBAL address; LDS dest linear). Fragment ds_read
// applies the same XOR -> 2-way max bank aliasing (free).
// Pipeline: stage(c+1); compute(c); s_waitcnt vmcnt(0); s_barrier.

template <int NC>
__global__ __launch_bounds__(256) void mgemm_k(const _Float16* __restrict__ A,
                                               const _Float16* __restrict__ Wh,
                                               _Float16* __restrict__ C,
                                               int M, int Kp) {
    constexpr int CT = NC / 16;            // col frags per wave
    constexpr int WJ = NC / 32;            // W gload insts per wave
    __shared__ __align__(16) _Float16 As[2][64 * 64];
    __shared__ __align__(16) _Float16 Ws[2][NC * 64];

    const int tid  = threadIdx.x;
    const int lane = tid & 63, wave = tid >> 6;
    const int lrow = lane & 15, kg = lane >> 4;
    const int row0 = blockIdx.x * 64;

    f32x4 acc[CT] = {};

    auto stage = [&](int c0, int b) {
        const int k0 = c0 * 64;
        // A tile: 64 rows x 128B -> 8 insts (2 per wave)
        #pragma unroll
        for (int j = 0; j < 2; ++j) {
            int li  = wave * 128 + j * 64 + lane;      // 0..511
            int row = li >> 3, s = li & 7;
            int gr  = row0 + row;
            int gs  = s ^ (row & 7);
            if (gr < M)
                gload16(A + (size_t)gr * Kp + k0 + gs * 8,
                        (char*)&As[b][0] + (wave * 128 + j * 64) * 16);
        }
        // W tile: NC rows x 128B -> NC/8 insts (WJ per wave)
        #pragma unroll
        for (int j = 0; j < WJ; ++j) {
            int li  = wave * (WJ * 64) + j * 64 + lane;
            int row = li >> 3, s = li & 7;
            int gs  = s ^ (row & 7);
            gload16(Wh + (size_t)row * Kp + k0 + gs * 8,
                    (char*)&Ws[b][0] + (wave * WJ + j) * 1024);
        }
    };

    auto compute = [&](int b) {
        const char* AsB = (const char*)&As[b][0];
        const char* WsB = (const char*)&Ws[b][0];
        #pragma unroll
        for (int ks = 0; ks < 2; ++ks) {
            const int cbase = ks * 64 + kg * 16;       // byte offset in row
            f16x8 af, bf[CT];
            {
                int row = wave * 16 + lrow;
                af = *(const f16x8*)(AsB + row * 128 + (cbase ^ ((row & 7) << 4)));
            }
            #pragma unroll
            for (int ct = 0; ct < CT; ++ct) {
                int row = ct * 16 + lrow;
                bf[ct] = *(const f16x8*)(WsB + row * 128 + (cbase ^ ((row & 7) << 4)));
            }
            #pragma unroll
            for (int ct = 0; ct < CT; ++ct)
                acc[ct] = __builtin_amdgcn_mfma_f32_16x16x32_f16(
                    af, bf[ct], acc[ct], 0, 0, 0);
        }
    };

    const int nchunk = Kp >> 6;            // Kp % 64 == 0
    stage(0, 0);
    asm volatile("s_waitcnt vmcnt(0)" ::: "memory");
    __builtin_amdgcn_s_barrier();
    __builtin_amdgcn_sched_barrier(0);

    for (int c = 0; c < nchunk; ++c) {
        const int b = c & 1;
        if (c + 1 < nchunk) stage(c + 1, b ^ 1);   // loads fly during compute
        compute(b);
        if (c + 1 < nchunk) {
            asm volatile("s_waitcnt vmcnt(0)" ::: "memory");
            __builtin_amdgcn_s_barrier();
            __builtin_amdgcn_sched_barrier(0);
        }
    }

    // ---- epilogue: D lane map col=lane&15, row=(lane>>4)*4+r ----
    #pragma unroll
    for (int r = 0; r < 4; ++r) {
        int grow = row0 + wave * 16 + kg * 4 + r;
        if (grow >= M) continue;
        #pragma unroll
        for (int ct = 0; ct < CT; ++ct)
            C[(size_t)grow * NC + ct * 16 + lrow] = (_Float16)acc[ct][r];
    }
}

// ---------------- GCN aggregation (gather over CSR, f16 in/out) ----------------
// out[i] = sum_{e: dst=i} w_e * h[src_e] + invdeg[i]*h[i] + bias
// One wave per node, 4 nodes per 256-thread block, 4-edge unroll.

__global__ void agg128_k(const _Float16* __restrict__ h, const float* __restrict__ invdeg,
                         const int* __restrict__ row_start, const int* __restrict__ cnt,
                         const int* __restrict__ eidx, const float* __restrict__ ew,
                         const float* __restrict__ bias, _Float16* __restrict__ out, int n) {
    const int wv = threadIdx.x >> 6, lane = threadIdx.x & 63;
    const int i = blockIdx.x * 4 + wv;
    if (i >= n) return;
    const int st = row_start[i], en = st + cnt[i];
    const float id = invdeg[i];
    const int c = lane * 2;

    f16x2 hv = *(const f16x2*)(h + (size_t)i * 128 + c);
    float a0 = fmaf(id, (float)hv[0], bias[c]);
    float a1 = fmaf(id, (float)hv[1], bias[c + 1]);
    int p = st;
    for (; p + 3 < en; p += 4) {
        int s0 = eidx[p], s1 = eidx[p + 1], s2 = eidx[p + 2], s3 = eidx[p + 3];
        float w0 = ew[p], w1 = ew[p + 1], w2 = ew[p + 2], w3 = ew[p + 3];
        f16x2 v0 = *(const f16x2*)(h + (size_t)s0 * 128 + c);
        f16x2 v1 = *(const f16x2*)(h + (size_t)s1 * 128 + c);
        f16x2 v2 = *(const f16x2*)(h + (size_t)s2 * 128 + c);
        f16x2 v3 = *(const f16x2*)(h + (size_t)s3 * 128 + c);
        a0 = fmaf(w0, (float)v0[0], a0); a1 = fmaf(w0, (float)v0[1], a1);
        a0 = fmaf(w1, (float)v1[0], a0); a1 = fmaf(w1, (float)v1[1], a1);
        a0 = fmaf(w2, (float)v2[0], a0); a1 = fmaf(w2, (float)v2[1], a1);
        a0 = fmaf(w3, (float)v3[0], a0); a1 = fmaf(w3, (float)v3[1], a1);
    }
    for (; p < en; ++p) {
        int s0 = eidx[p]; float w0 = ew[p];
        f16x2 v0 = *(const f16x2*)(h + (size_t)s0 * 128 + c);
        a0 = fmaf(w0, (float)v0[0], a0); a1 = fmaf(w0, (float)v0[1], a1);
    }
    f16x2 o; o[0] = (_Float16)a0; o[1] = (_Float16)a1;
    *(f16x2*)(out + (size_t)i * 128 + c) = o;
}

// ---------------- BN stats over f16 activations (12.8 MB read) ----------------
// 256 blocks x 256 thr, grid-stride f16x8; thread's col group fixed
// ((tid&15)*8 since strides are multiples of 16). Block LDS reduce ->
// 256 atomics per block (tail ~2us total at 256 blocks).

__global__ void stats16_k(const _Float16* __restrict__ a, float* __restrict__ gsum,
                          float* __restrict__ gsq, int total8) {
    const int tid = threadIdx.x;
    float s[8] = {}, q[8] = {};
    for (int idx = blockIdx.x * 256 + tid; idx < total8; idx += gridDim.x * 256) {
        f16x8 v = *(const f16x8*)(a + (size_t)idx * 8);
        #pragma unroll
        for (int j = 0; j < 8; ++j) {
            float f = (float)v[j];
            s[j] += f;
            q[j] = fmaf(f, f, q[j]);
        }
    }
    __shared__ float red[2][16][16][8];     // [sum/sq][k-group][col-group][col]
    const int g = tid & 15, k = tid >> 4;
    #pragma unroll
    for (int j = 0; j < 8; ++j) {
        red[0][k][g][j] = s[j];
        red[1][k][g][j] = q[j];
    }
    __syncthreads();
    if (tid < 128) {
        const int g2 = tid & 15, j2 = tid >> 4;     // j2 in 0..7
        float ts = 0.f, tq = 0.f;
        #pragma unroll
        for (int k2 = 0; k2 < 16; ++k2) {
            ts += red[0][k2][g2][j2];
            tq += red[1][k2][g2][j2];
        }
        atomicAdd(&gsum[g2 * 8 + j2], ts);
        atomicAdd(&gsq[g2 * 8 + j2], tq);
    }
}

// ---- classifier agg (64 cols) with log_softmax fused (row == wave) ----

__global__ void aggsm_k(const _Float16* __restrict__ h, const float* __restrict__ invdeg,
                        const int* __restrict__ row_start, const int* __restrict__ cnt,
                        const int* __restrict__ eidx, const float* __restrict__ ew,
                        const float* __restrict__ bias, float* __restrict__ out, int n) {
    const int wv = threadIdx.x >> 6, lane = threadIdx.x & 63;
    const int i = blockIdx.x * 4 + wv;
    if (i >= n) return;
    const int st = row_start[i], en = st + cnt[i];
    const float id = invdeg[i];

    float a0 = fmaf(id, (float)h[(size_t)i * 64 + lane], bias[lane]);
    int p = st;
    for (; p + 3 < en; p += 4) {
        int s0 = eidx[p], s1 = eidx[p + 1], s2 = eidx[p + 2], s3 = eidx[p + 3];
        float w0 = ew[p], w1 = ew[p + 1], w2 = ew[p + 2], w3 = ew[p + 3];
        float v0 = (float)h[(size_t)s0 * 64 + lane];
        float v1 = (float)h[(size_t)s1 * 64 + lane];
        float v2 = (float)h[(size_t)s2 * 64 + lane];
        float v3 = (float)h[(size_t)s3 * 64 + lane];
        a0 = fmaf(w0, v0, a0); a0 = fmaf(w1, v1, a0);
        a0 = fmaf(w2, v2, a0); a0 = fmaf(w3, v3, a0);
    }
    for (; p < en; ++p)
        a0 = fmaf(ew[p], (float)h[(size_t)eidx[p] * 64 + lane], a0);

    // fused log_softmax over the 64-wide row held by this wave
    float m = a0;
    #pragma unroll
    for (int d = 32; d >= 1; d >>= 1) m = fmaxf(m, __shfl_xor(m, d, 64));
    float e = __expf(a0 - m);
    float s = e;
    #pragma unroll
    for (int d = 32; d >= 1; d >>= 1) s += __shfl_xor(s, d, 64);
    out[(size_t)i * 64 + lane] = a0 - m - __logf(s);
}

// ---------------- BatchNorm finalize + apply (f16 in/out) ----------------

__global__ void finalize_k(const float* __restrict__ gsum, const float* __restrict__ gsq,
                           float* __restrict__ scale, float* __restrict__ shift, int n) {
    int c = threadIdx.x;   // 128
    float mean = gsum[c] / (float)n;
    float var  = gsq[c] / (float)n - mean * mean;
    float sc   = rsqrtf(var + EPS_BN);
    scale[c] = sc;
    shift[c] = -mean * sc;
}

// BN scale/shift + ReLU, f16 in -> f16 out (16B/lane both ways)
__global__ void norm_k(const _Float16* __restrict__ a, _Float16* __restrict__ o,
                       const float* __restrict__ scale, const float* __restrict__ shift,
                       int total8) {
    int idx = blockIdx.x * 256 + threadIdx.x;
    if (idx >= total8) return;
    f16x8 v = *(const f16x8*)(a + (size_t)idx * 8);
    int c0 = (idx & 15) * 8;
    f16x8 h;
    #pragma unroll
    for (int j = 0; j < 8; ++j)
        h[j] = (_Float16)fmaxf(0.f, fmaf((float)v[j], scale[c0 + j], shift[c0 + j]));
    *(f16x8*)(o + (size_t)idx * 8) = h;
}

// ---------------------------------------------------------------------------

extern "C" void kernel_launch(void* const* d_in, const int* in_sizes, int n_in,
                              void* d_out, int out_size, void* d_ws, size_t ws_size,
                              hipStream_t stream) {
    const float* x  = (const float*)d_in[0];
    const int*   ei = (const int*)d_in[1];
    const float* W0 = (const float*)d_in[2];
    const float* b0 = (const float*)d_in[3];
    const float* W1 = (const float*)d_in[4];
    const float* b1 = (const float*)d_in[5];
    const float* W2 = (const float*)d_in[6];
    const float* b2 = (const float*)d_in[7];

    const int IN = 500;
    const int n = in_sizes[0] / IN;      // 50000
    const int E = in_sizes[1] / 2;       // 640000
    const int* src = ei;
    const int* dst = ei + E;

    // ---- workspace bump allocator (256B aligned) ----
    char* p = (char*)d_ws;
    auto alloc = [&](size_t bytes) -> void* {
        char* r = p;
        p += (bytes + 255) & ~(size_t)255;
        return (void*)r;
    };
    _Float16*  xh      = (_Float16*)alloc((size_t)n * 512 * 2);  // x as f16, K padded
    _Float16*  hb1h    = (_Float16*)alloc((size_t)n * 128 * 2);  // GEMM out / agg in
    _Float16*  hb2a    = (_Float16*)alloc((size_t)n * 128 * 2);  // agg out (f16)
    _Float16*  hb2h    = (_Float16*)alloc((size_t)n * 128 * 2);  // BN out / GEMM in
    _Float16*  W0h     = (_Float16*)alloc((size_t)128 * 512 * 2);
    _Float16*  W1h     = (_Float16*)alloc((size_t)128 * 128 * 2);
    _Float16*  W2h     = (_Float16*)alloc((size_t)64 * 128 * 2);
    int*   deg_cnt  = (int*)alloc((size_t)n * 4);
    float* dinv     = (float*)alloc((size_t)n * 4);
    float* invdeg   = (float*)alloc((size_t)n * 4);
    int*   row_st   = (int*)alloc((size_t)n * 4);
    int*   cursor   = (int*)alloc((size_t)n * 4);
    int*   within   = (int*)alloc((size_t)n * 4);
    int*   btot     = (int*)alloc(256 * 4);
    int*   boff     = (int*)alloc(256 * 4);
    int*   eidx     = (int*)alloc((size_t)E * 4);
    float* ew       = (float*)alloc((size_t)E * 4);
    float* gsum     = (float*)alloc(128 * 4);   // gsum+gsq contiguous: one memset
    float* gsq      = (float*)alloc(128 * 4);
    float* scale    = (float*)alloc(128 * 4);
    float* shift    = (float*)alloc(128 * 4);
    (void)ws_size; (void)n_in; (void)out_size;

    float* out = (float*)d_out;

    const int gE = (E + 255) / 256;
    const int gN = (n + 255) / 256;
    const int nblk = (n + 511) / 512;
    const int gM = (n + 63) / 64;        // 782 blocks
    const int gA = (n + 3) / 4;          // 12500 blocks (agg + classifier agg)

    // ---- graph prep + f16 conversions (once per call) ----
    hipMemsetAsync(deg_cnt, 0, (size_t)n * 4, stream);
    count_k<<<gE, 256, 0, stream>>>(src, dst, deg_cnt, E);
    prep_k<<<gN, 256, 0, stream>>>(deg_cnt, dinv, invdeg, n);
    scan1_k<<<nblk, 512, 0, stream>>>(deg_cnt, within, btot, n);
    scan2_k<<<1, 64, 0, stream>>>(btot, boff, nblk);
    scan3_k<<<gN, 256, 0, stream>>>(within, boff, row_st, cursor, n);
    fill_k<<<gE, 256, 0, stream>>>(src, dst, dinv, cursor, eidx, ew, E);
    wcvt_k<<<(128 * 512 / 4 + 255) / 256, 256, 0, stream>>>(W0, W0h, 128, 500, 512);
    wcvt_k<<<(128 * 128 / 4 + 255) / 256, 256, 0, stream>>>(W1, W1h, 128, 128, 128);
    wcvt_k<<<(64 * 128 / 4 + 255) / 256, 256, 0, stream>>>(W2, W2h, 64, 128, 128);
    wcvt_k<<<(n * 128 + 255) / 256, 256, 0, stream>>>(x, xh, n, 500, 512);

    // ---- layer 0 ----
    mgemm_k<128><<<gM, 256, 0, stream>>>(xh, W0h, hb1h, n, 512);
    agg128_k<<<gA, 256, 0, stream>>>(hb1h, invdeg, row_st, deg_cnt, eidx, ew, b0, hb2a, n);
    hipMemsetAsync(gsum, 0, 256 * 4, stream);
    stats16_k<<<256, 256, 0, stream>>>(hb2a, gsum, gsq, n * 16);
    finalize_k<<<1, 128, 0, stream>>>(gsum, gsq, scale, shift, n);
    norm_k<<<(n * 16 + 255) / 256, 256, 0, stream>>>(hb2a, hb2h, scale, shift, n * 16);

    // ---- layer 1 ----
    mgemm_k<128><<<gM, 256, 0, stream>>>(hb2h, W1h, hb1h, n, 128);
    agg128_k<<<gA, 256, 0, stream>>>(hb1h, invdeg, row_st, deg_cnt, eidx, ew, b1, hb2a, n);
    hipMemsetAsync(gsum, 0, 256 * 4, stream);
    stats16_k<<<256, 256, 0, stream>>>(hb2a, gsum, gsq, n * 16);
    finalize_k<<<1, 128, 0, stream>>>(gsum, gsq, scale, shift, n);
    norm_k<<<(n * 16 + 255) / 256, 256, 0, stream>>>(hb2a, hb2h, scale, shift, n * 16);

    // ---- classifier (log_softmax fused into agg) ----
    mgemm_k<64><<<gM, 256, 0, stream>>>(hb2h, W2h, hb1h, n, 128);
    aggsm_k<<<gA, 256, 0, stream>>>(hb1h, invdeg, row_st, deg_cnt, eidx, ew, b2, out, n);
}

// Round 11
// 300.013 us; speedup vs baseline: 2.1575x; 1.0300x over previous
//
#include <hip/hip_runtime.h>
#include <hip/hip_bf16.h>
#include <math.h>

// ---------------------------------------------------------------------------
// PMLP_GCN forward:  3x (GEMM -> GCN-agg[+bias]) with BN+ReLU between,
// log_softmax at the end.  N=50000 E=640000 IN=500 HID=128 OUT=64, f32.
// R10: aggs use 2 nodes/wave (32 lanes x f16x4 per node) -> 2x in-flight
//      bytes + 2 independent gather chains per wave; finalize fused into
//      norm; single up-front memset for both layers' BN stat buffers.
// ---------------------------------------------------------------------------

#define EPS_BN 1e-5f

typedef __attribute__((ext_vector_type(8))) _Float16 f16x8;
typedef __attribute__((ext_vector_type(4))) _Float16 f16x4;
typedef __attribute__((ext_vector_type(2))) _Float16 f16x2;
typedef __attribute__((ext_vector_type(4))) float    f32x4;

__device__ __forceinline__ void gload16(const void* g, void* l) {
    __builtin_amdgcn_global_load_lds(
        (const __attribute__((address_space(1))) void*)g,
        (__attribute__((address_space(3))) void*)l, 16, 0, 0);
}

// ---------------- graph prep ----------------

__global__ void count_k(const int* __restrict__ src, const int* __restrict__ dst,
                        int* __restrict__ cnt, int E) {
    int e = blockIdx.x * 256 + threadIdx.x;
    if (e >= E) return;
    int s = src[e], d = dst[e];
    if (s != d) atomicAdd(&cnt[d], 1);
}

__global__ void prep_k(const int* __restrict__ cnt, float* __restrict__ dinv,
                       float* __restrict__ invdeg, int n) {
    int i = blockIdx.x * 256 + threadIdx.x;
    if (i >= n) return;
    float deg = (float)cnt[i] + 1.0f;   // +1 for added self loop
    dinv[i]   = rsqrtf(deg);
    invdeg[i] = 1.0f / deg;
}

// 3-kernel exclusive prefix scan over cnt[n] -> row_start
__global__ void scan1_k(const int* __restrict__ cnt, int* __restrict__ within,
                        int* __restrict__ btot, int n) {
    __shared__ int s[512];
    int tid = threadIdx.x;
    int i = blockIdx.x * 512 + tid;
    int val = (i < n) ? cnt[i] : 0;
    s[tid] = val;
    __syncthreads();
    for (int off = 1; off < 512; off <<= 1) {
        int v = (tid >= off) ? s[tid - off] : 0;
        __syncthreads();
        s[tid] += v;
        __syncthreads();
    }
    if (i < n) within[i] = s[tid] - val;   // exclusive
    if (tid == 511) btot[blockIdx.x] = s[511];
}

__global__ void scan2_k(const int* __restrict__ btot, int* __restrict__ boff, int nblk) {
    if (threadIdx.x == 0) {
        int run = 0;
        for (int b = 0; b < nblk; ++b) { boff[b] = run; run += btot[b]; }
    }
}

__global__ void scan3_k(const int* __restrict__ within, const int* __restrict__ boff,
                        int* __restrict__ row_start, int* __restrict__ cursor, int n) {
    int i = blockIdx.x * 256 + threadIdx.x;
    if (i >= n) return;
    int v = within[i] + boff[i >> 9];
    row_start[i] = v;
    cursor[i]    = v;
}

__global__ void fill_k(const int* __restrict__ src, const int* __restrict__ dst,
                       const float* __restrict__ dinv, int* __restrict__ cursor,
                       int* __restrict__ eidx, float* __restrict__ ew, int E) {
    int e = blockIdx.x * 256 + threadIdx.x;
    if (e >= E) return;
    int s = src[e], d = dst[e];
    if (s == d) return;
    int pos = atomicAdd(&cursor[d], 1);
    eidx[pos] = s;
    ew[pos]   = dinv[s] * dinv[d];
}

// ---- f32 -> f16 with K padded to Kp (pad zero-filled); used for W and x ----

__global__ void wcvt_k(const float* __restrict__ W, _Float16* __restrict__ Wh,
                       int rows, int K, int Kp) {
    int q = Kp >> 2;
    long long idx = (long long)blockIdx.x * 256 + threadIdx.x;
    if (idx >= (long long)rows * q) return;
    int r = (int)(idx / q), k4 = (int)(idx - (long long)r * q) * 4;
    f16x4 h = {(_Float16)0.f, (_Float16)0.f, (_Float16)0.f, (_Float16)0.f};
    if (k4 < K) {                        // K%4==0 -> all-or-none
        float4 v = *(const float4*)(W + (size_t)r * K + k4);
        h[0] = (_Float16)v.x; h[1] = (_Float16)v.y;
        h[2] = (_Float16)v.z; h[3] = (_Float16)v.w;
    }
    *(f16x4*)(Wh + (size_t)r * Kp + k4) = h;
}

// ---------------- MFMA GEMM: C[M,NC] = A[M,Kp] * Wh[NC,Kp]^T ----------------
// A, Wh f16 (pre-converted, Kp padded with zeros). f32 accumulate, f16 out.
// Block: 256 thr = 4 waves; tile 64 x NC; chunk 64.
// Staging: global_load_lds (16B/lane, 1KB/inst, no VGPR round-trip).
// LDS image: row stride 128B, 16B-slot s of row holds global slot s^(row&7)
// (inverse-swizzled GLOBAL address; LDS dest linear). Fragment ds_read
// applies the same XOR -> 2-way max bank aliasing (free).
// Pipeline: stage(c+1); compute(c); s_waitcnt vmcnt(0); s_barrier.

template <int NC>
__global__ __launch_bounds__(256) void mgemm_k(const _Float16* __restrict__ A,
                                               const _Float16* __restrict__ Wh,
                                               _Float16* __restrict__ C,
                                               int M, int Kp) {
    constexpr int CT = NC / 16;            // col frags per wave
    constexpr int WJ = NC / 32;            // W gload insts per wave
    __shared__ __align__(16) _Float16 As[2][64 * 64];
    __shared__ __align__(16) _Float16 Ws[2][NC * 64];

    const int tid  = threadIdx.x;
    const int lane = tid & 63, wave = tid >> 6;
    const int lrow = lane & 15, kg = lane >> 4;
    const int row0 = blockIdx.x * 64;

    f32x4 acc[CT] = {};

    auto stage = [&](int c0, int b) {
        const int k0 = c0 * 64;
        // A tile: 64 rows x 128B -> 8 insts (2 per wave)
        #pragma unroll
        for (int j = 0; j < 2; ++j) {
            int li  = wave * 128 + j * 64 + lane;      // 0..511
            int row = li >> 3, s = li & 7;
            int gr  = row0 + row;
            int gs  = s ^ (row & 7);
            if (gr < M)
                gload16(A + (size_t)gr * Kp + k0 + gs * 8,
                        (char*)&As[b][0] + (wave * 128 + j * 64) * 16);
        }
        // W tile: NC rows x 128B -> NC/8 insts (WJ per wave)
        #pragma unroll
        for (int j = 0; j < WJ; ++j) {
            int li  = wave * (WJ * 64) + j * 64 + lane;
            int row = li >> 3, s = li & 7;
            int gs  = s ^ (row & 7);
            gload16(Wh + (size_t)row * Kp + k0 + gs * 8,
                    (char*)&Ws[b][0] + (wave * WJ + j) * 1024);
        }
    };

    auto compute = [&](int b) {
        const char* AsB = (const char*)&As[b][0];
        const char* WsB = (const char*)&Ws[b][0];
        #pragma unroll
        for (int ks = 0; ks < 2; ++ks) {
            const int cbase = ks * 64 + kg * 16;       // byte offset in row
            f16x8 af, bf[CT];
            {
                int row = wave * 16 + lrow;
                af = *(const f16x8*)(AsB + row * 128 + (cbase ^ ((row & 7) << 4)));
            }
            #pragma unroll
            for (int ct = 0; ct < CT; ++ct) {
                int row = ct * 16 + lrow;
                bf[ct] = *(const f16x8*)(WsB + row * 128 + (cbase ^ ((row & 7) << 4)));
            }
            #pragma unroll
            for (int ct = 0; ct < CT; ++ct)
                acc[ct] = __builtin_amdgcn_mfma_f32_16x16x32_f16(
                    af, bf[ct], acc[ct], 0, 0, 0);
        }
    };

    const int nchunk = Kp >> 6;            // Kp % 64 == 0
    stage(0, 0);
    asm volatile("s_waitcnt vmcnt(0)" ::: "memory");
    __builtin_amdgcn_s_barrier();
    __builtin_amdgcn_sched_barrier(0);

    for (int c = 0; c < nchunk; ++c) {
        const int b = c & 1;
        if (c + 1 < nchunk) stage(c + 1, b ^ 1);   // loads fly during compute
        compute(b);
        if (c + 1 < nchunk) {
            asm volatile("s_waitcnt vmcnt(0)" ::: "memory");
            __builtin_amdgcn_s_barrier();
            __builtin_amdgcn_sched_barrier(0);
        }
    }

    // ---- epilogue: D lane map col=lane&15, row=(lane>>4)*4+r ----
    #pragma unroll
    for (int r = 0; r < 4; ++r) {
        int grow = row0 + wave * 16 + kg * 4 + r;
        if (grow >= M) continue;
        #pragma unroll
        for (int ct = 0; ct < CT; ++ct)
            C[(size_t)grow * NC + ct * 16 + lrow] = (_Float16)acc[ct][r];
    }
}

// ---------------- GCN aggregation (gather over CSR, f16 in/out) ----------------
// out[i] = sum_{e: dst=i} w_e * h[src_e] + invdeg[i]*h[i] + bias
// TWO nodes per wave: 32 lanes per node, f16x4 (4 cols) per lane, 4-edge
// unroll -> 32 B/lane in flight + 2 independent gather chains per wave.

__global__ void agg128_k(const _Float16* __restrict__ h, const float* __restrict__ invdeg,
                         const int* __restrict__ row_start, const int* __restrict__ cnt,
                         const int* __restrict__ eidx, const float* __restrict__ ew,
                         const float* __restrict__ bias, _Float16* __restrict__ out, int n) {
    const int half = threadIdx.x >> 5;          // 0..7 within block
    const int l = threadIdx.x & 31;
    const int i = blockIdx.x * 8 + half;
    if (i >= n) return;
    const int st = row_start[i], en = st + cnt[i];
    const float id = invdeg[i];
    const int c = l * 4;

    f16x4 hv = *(const f16x4*)(h + (size_t)i * 128 + c);
    float a0 = fmaf(id, (float)hv[0], bias[c]);
    float a1 = fmaf(id, (float)hv[1], bias[c + 1]);
    float a2 = fmaf(id, (float)hv[2], bias[c + 2]);
    float a3 = fmaf(id, (float)hv[3], bias[c + 3]);
    int p = st;
    for (; p + 3 < en; p += 4) {
        int s0 = eidx[p], s1 = eidx[p + 1], s2 = eidx[p + 2], s3 = eidx[p + 3];
        float w0 = ew[p], w1 = ew[p + 1], w2 = ew[p + 2], w3 = ew[p + 3];
        f16x4 v0 = *(const f16x4*)(h + (size_t)s0 * 128 + c);
        f16x4 v1 = *(const f16x4*)(h + (size_t)s1 * 128 + c);
        f16x4 v2 = *(const f16x4*)(h + (size_t)s2 * 128 + c);
        f16x4 v3 = *(const f16x4*)(h + (size_t)s3 * 128 + c);
        a0 = fmaf(w0, (float)v0[0], a0); a1 = fmaf(w0, (float)v0[1], a1);
        a2 = fmaf(w0, (float)v0[2], a2); a3 = fmaf(w0, (float)v0[3], a3);
        a0 = fmaf(w1, (float)v1[0], a0); a1 = fmaf(w1, (float)v1[1], a1);
        a2 = fmaf(w1, (float)v1[2], a2); a3 = fmaf(w1, (float)v1[3], a3);
        a0 = fmaf(w2, (float)v2[0], a0); a1 = fmaf(w2, (float)v2[1], a1);
        a2 = fmaf(w2, (float)v2[2], a2); a3 = fmaf(w2, (float)v2[3], a3);
        a0 = fmaf(w3, (float)v3[0], a0); a1 = fmaf(w3, (float)v3[1], a1);
        a2 = fmaf(w3, (float)v3[2], a2); a3 = fmaf(w3, (float)v3[3], a3);
    }
    for (; p < en; ++p) {
        int s0 = eidx[p]; float w0 = ew[p];
        f16x4 v0 = *(const f16x4*)(h + (size_t)s0 * 128 + c);
        a0 = fmaf(w0, (float)v0[0], a0); a1 = fmaf(w0, (float)v0[1], a1);
        a2 = fmaf(w0, (float)v0[2], a2); a3 = fmaf(w0, (float)v0[3], a3);
    }
    f16x4 o;
    o[0] = (_Float16)a0; o[1] = (_Float16)a1;
    o[2] = (_Float16)a2; o[3] = (_Float16)a3;
    *(f16x4*)(out + (size_t)i * 128 + c) = o;
}

// ---------------- BN stats over f16 activations (12.8 MB read) ----------------
// 256 blocks x 256 thr, grid-stride f16x8. Block LDS reduce -> 256 atomics
// per block (tail ~2us total at 256 blocks).

__global__ void stats16_k(const _Float16* __restrict__ a, float* __restrict__ gsum,
                          float* __restrict__ gsq, int total8) {
    const int tid = threadIdx.x;
    float s[8] = {}, q[8] = {};
    for (int idx = blockIdx.x * 256 + tid; idx < total8; idx += gridDim.x * 256) {
        f16x8 v = *(const f16x8*)(a + (size_t)idx * 8);
        #pragma unroll
        for (int j = 0; j < 8; ++j) {
            float f = (float)v[j];
            s[j] += f;
            q[j] = fmaf(f, f, q[j]);
        }
    }
    __shared__ float red[2][16][16][8];     // [sum/sq][k-group][col-group][col]
    const int g = tid & 15, k = tid >> 4;
    #pragma unroll
    for (int j = 0; j < 8; ++j) {
        red[0][k][g][j] = s[j];
        red[1][k][g][j] = q[j];
    }
    __syncthreads();
    if (tid < 128) {
        const int g2 = tid & 15, j2 = tid >> 4;     // j2 in 0..7
        float ts = 0.f, tq = 0.f;
        #pragma unroll
        for (int k2 = 0; k2 < 16; ++k2) {
            ts += red[0][k2][g2][j2];
            tq += red[1][k2][g2][j2];
        }
        atomicAdd(&gsum[g2 * 8 + j2], ts);
        atomicAdd(&gsq[g2 * 8 + j2], tq);
    }
}

// ---- classifier agg (64 cols) with log_softmax fused; 2 nodes per wave ----
// 32 lanes per node, f16x2 per lane; shfl_xor d<=16 stays within the half.

__global__ void aggsm_k(const _Float16* __restrict__ h, const float* __restrict__ invdeg,
                        const int* __restrict__ row_start, const int* __restrict__ cnt,
                        const int* __restrict__ eidx, const float* __restrict__ ew,
                        const float* __restrict__ bias, float* __restrict__ out, int n) {
    const int half = threadIdx.x >> 5;
    const int l = threadIdx.x & 31;
    const int i = blockIdx.x * 8 + half;
    if (i >= n) return;
    const int st = row_start[i], en = st + cnt[i];
    const float id = invdeg[i];
    const int c = l * 2;

    f16x2 hv = *(const f16x2*)(h + (size_t)i * 64 + c);
    float a0 = fmaf(id, (float)hv[0], bias[c]);
    float a1 = fmaf(id, (float)hv[1], bias[c + 1]);
    int p = st;
    for (; p + 3 < en; p += 4) {
        int s0 = eidx[p], s1 = eidx[p + 1], s2 = eidx[p + 2], s3 = eidx[p + 3];
        float w0 = ew[p], w1 = ew[p + 1], w2 = ew[p + 2], w3 = ew[p + 3];
        f16x2 v0 = *(const f16x2*)(h + (size_t)s0 * 64 + c);
        f16x2 v1 = *(const f16x2*)(h + (size_t)s1 * 64 + c);
        f16x2 v2 = *(const f16x2*)(h + (size_t)s2 * 64 + c);
        f16x2 v3 = *(const f16x2*)(h + (size_t)s3 * 64 + c);
        a0 = fmaf(w0, (float)v0[0], a0); a1 = fmaf(w0, (float)v0[1], a1);
        a0 = fmaf(w1, (float)v1[0], a0); a1 = fmaf(w1, (float)v1[1], a1);
        a0 = fmaf(w2, (float)v2[0], a0); a1 = fmaf(w2, (float)v2[1], a1);
        a0 = fmaf(w3, (float)v3[0], a0); a1 = fmaf(w3, (float)v3[1], a1);
    }
    for (; p < en; ++p) {
        int s0 = eidx[p]; float w0 = ew[p];
        f16x2 v0 = *(const f16x2*)(h + (size_t)s0 * 64 + c);
        a0 = fmaf(w0, (float)v0[0], a0); a1 = fmaf(w0, (float)v0[1], a1);
    }

    // fused log_softmax over 64 cols held by this 32-lane half
    float m = fmaxf(a0, a1);
    #pragma unroll
    for (int d = 16; d >= 1; d >>= 1) m = fmaxf(m, __shfl_xor(m, d, 64));
    float e0 = __expf(a0 - m), e1 = __expf(a1 - m);
    float s = e0 + e1;
    #pragma unroll
    for (int d = 16; d >= 1; d >>= 1) s += __shfl_xor(s, d, 64);
    float ls = __logf(s);
    float2 o = make_float2(a0 - m - ls, a1 - m - ls);
    *(float2*)(out + (size_t)i * 64 + c) = o;
}

// ---------- BatchNorm finalize (per-thread) + apply + ReLU (f16 io) ----------

__global__ void norm_k(const _Float16* __restrict__ a, _Float16* __restrict__ o,
                       const float* __restrict__ gsum, const float* __restrict__ gsq,
                       float inv_n, int total8) {
    int idx = blockIdx.x * 256 + threadIdx.x;
    if (idx >= total8) return;
    int c0 = (idx & 15) * 8;
    f16x8 v = *(const f16x8*)(a + (size_t)idx * 8);
    f16x8 h;
    #pragma unroll
    for (int j = 0; j < 8; ++j) {
        float mean = gsum[c0 + j] * inv_n;
        float var  = gsq[c0 + j] * inv_n - mean * mean;
        float sc   = rsqrtf(var + EPS_BN);
        h[j] = (_Float16)fmaxf(0.f, (float(v[j]) - mean) * sc);
    }
    *(f16x8*)(o + (size_t)idx * 8) = h;
}

// ---------------------------------------------------------------------------

extern "C" void kernel_launch(void* const* d_in, const int* in_sizes, int n_in,
                              void* d_out, int out_size, void* d_ws, size_t ws_size,
                              hipStream_t stream) {
    const float* x  = (const float*)d_in[0];
    const int*   ei = (const int*)d_in[1];
    const float* W0 = (const float*)d_in[2];
    const float* b0 = (const float*)d_in[3];
    const float* W1 = (const float*)d_in[4];
    const float* b1 = (const float*)d_in[5];
    const float* W2 = (const float*)d_in[6];
    const float* b2 = (const float*)d_in[7];

    const int IN = 500;
    const int n = in_sizes[0] / IN;      // 50000
    const int E = in_sizes[1] / 2;       // 640000
    const int* src = ei;
    const int* dst = ei + E;

    // ---- workspace bump allocator (256B aligned) ----
    char* p = (char*)d_ws;
    auto alloc = [&](size_t bytes) -> void* {
        char* r = p;
        p += (bytes + 255) & ~(size_t)255;
        return (void*)r;
    };
    _Float16*  xh      = (_Float16*)alloc((size_t)n * 512 * 2);  // x as f16, K padded
    _Float16*  hb1h    = (_Float16*)alloc((size_t)n * 128 * 2);  // GEMM out / agg in
    _Float16*  hb2a    = (_Float16*)alloc((size_t)n * 128 * 2);  // agg out (f16)
    _Float16*  hb2h    = (_Float16*)alloc((size_t)n * 128 * 2);  // BN out / GEMM in
    _Float16*  W0h     = (_Float16*)alloc((size_t)128 * 512 * 2);
    _Float16*  W1h     = (_Float16*)alloc((size_t)128 * 128 * 2);
    _Float16*  W2h     = (_Float16*)alloc((size_t)64 * 128 * 2);
    int*   deg_cnt  = (int*)alloc((size_t)n * 4);
    float* dinv     = (float*)alloc((size_t)n * 4);
    float* invdeg   = (float*)alloc((size_t)n * 4);
    int*   row_st   = (int*)alloc((size_t)n * 4);
    int*   cursor   = (int*)alloc((size_t)n * 4);
    int*   within   = (int*)alloc((size_t)n * 4);
    int*   btot     = (int*)alloc(256 * 4);
    int*   boff     = (int*)alloc(256 * 4);
    int*   eidx     = (int*)alloc((size_t)E * 4);
    float* ew       = (float*)alloc((size_t)E * 4);
    // BN stat buffers for both layers, contiguous -> ONE memset (2 KB)
    float* gsum0    = (float*)alloc(128 * 4);
    float* gsq0     = (float*)alloc(128 * 4);
    float* gsum1    = (float*)alloc(128 * 4);
    float* gsq1     = (float*)alloc(128 * 4);
    (void)ws_size; (void)n_in; (void)out_size;

    float* out = (float*)d_out;
    const float inv_n = 1.0f / (float)n;

    const int gE = (E + 255) / 256;
    const int gN = (n + 255) / 256;
    const int nblk = (n + 511) / 512;
    const int gM = (n + 63) / 64;        // 782 blocks
    const int gA = (n + 7) / 8;          // 6250 blocks (2 nodes/wave aggs)

    // ---- graph prep + f16 conversions (once per call) ----
    hipMemsetAsync(deg_cnt, 0, (size_t)n * 4, stream);
    hipMemsetAsync(gsum0, 0, 4 * 128 * 4, stream);   // gsum0,gsq0,gsum1,gsq1
    count_k<<<gE, 256, 0, stream>>>(src, dst, deg_cnt, E);
    prep_k<<<gN, 256, 0, stream>>>(deg_cnt, dinv, invdeg, n);
    scan1_k<<<nblk, 512, 0, stream>>>(deg_cnt, within, btot, n);
    scan2_k<<<1, 64, 0, stream>>>(btot, boff, nblk);
    scan3_k<<<gN, 256, 0, stream>>>(within, boff, row_st, cursor, n);
    fill_k<<<gE, 256, 0, stream>>>(src, dst, dinv, cursor, eidx, ew, E);
    wcvt_k<<<(128 * 512 / 4 + 255) / 256, 256, 0, stream>>>(W0, W0h, 128, 500, 512);
    wcvt_k<<<(128 * 128 / 4 + 255) / 256, 256, 0, stream>>>(W1, W1h, 128, 128, 128);
    wcvt_k<<<(64 * 128 / 4 + 255) / 256, 256, 0, stream>>>(W2, W2h, 64, 128, 128);
    wcvt_k<<<(n * 128 + 255) / 256, 256, 0, stream>>>(x, xh, n, 500, 512);

    // ---- layer 0 ----
    mgemm_k<128><<<gM, 256, 0, stream>>>(xh, W0h, hb1h, n, 512);
    agg128_k<<<gA, 256, 0, stream>>>(hb1h, invdeg, row_st, deg_cnt, eidx, ew, b0, hb2a, n);
    stats16_k<<<256, 256, 0, stream>>>(hb2a, gsum0, gsq0, n * 16);
    norm_k<<<(n * 16 + 255) / 256, 256, 0, stream>>>(hb2a, hb2h, gsum0, gsq0, inv_n, n * 16);

    // ---- layer 1 ----
    mgemm_k<128><<<gM, 256, 0, stream>>>(hb2h, W1h, hb1h, n, 128);
    agg128_k<<<gA, 256, 0, stream>>>(hb1h, invdeg, row_st, deg_cnt, eidx, ew, b1, hb2a, n);
    stats16_k<<<256, 256, 0, stream>>>(hb2a, gsum1, gsq1, n * 16);
    norm_k<<<(n * 16 + 255) / 256, 256, 0, stream>>>(hb2a, hb2h, gsum1, gsq1, inv_n, n * 16);

    // ---- classifier (log_softmax fused into agg) ----
    mgemm_k<64><<<gM, 256, 0, stream>>>(hb2h, W2h, hb1h, n, 128);
    aggsm_k<<<gA, 256, 0, stream>>>(hb1h, invdeg, row_st, deg_cnt, eidx, ew, b2, out, n);
}

// Round 12
// 278.425 us; speedup vs baseline: 2.3248x; 1.0775x over previous
//
#include <hip/hip_runtime.h>
#include <hip/hip_bf16.h>
#include <math.h>

// ---------------------------------------------------------------------------
// PMLP_GCN forward:  3x (GEMM -> GCN-agg[+bias]) with BN+ReLU between,
// log_softmax at the end.  N=50000 E=640000 IN=500 HID=128 OUT=64, f32.
// R11: BN+ReLU fused into the consuming GEMM's A-fragment path (per-k
//      scale/shift from LDS, applied in registers after ds_read) -> norm_k
//      and hb2h removed. 3 W-conversions merged into 1 kernel; deg_cnt and
//      BN stat buffers zeroed by a single memset. 21 -> 17 dispatches.
// ---------------------------------------------------------------------------

#define EPS_BN 1e-5f

typedef __attribute__((ext_vector_type(8))) _Float16 f16x8;
typedef __attribute__((ext_vector_type(4))) _Float16 f16x4;
typedef __attribute__((ext_vector_type(2))) _Float16 f16x2;
typedef __attribute__((ext_vector_type(4))) float    f32x4;

__device__ __forceinline__ void gload16(const void* g, void* l) {
    __builtin_amdgcn_global_load_lds(
        (const __attribute__((address_space(1))) void*)g,
        (__attribute__((address_space(3))) void*)l, 16, 0, 0);
}

// ---------------- graph prep ----------------

__global__ void count_k(const int* __restrict__ src, const int* __restrict__ dst,
                        int* __restrict__ cnt, int E) {
    int e = blockIdx.x * 256 + threadIdx.x;
    if (e >= E) return;
    int s = src[e], d = dst[e];
    if (s != d) atomicAdd(&cnt[d], 1);
}

__global__ void prep_k(const int* __restrict__ cnt, float* __restrict__ dinv,
                       float* __restrict__ invdeg, int n) {
    int i = blockIdx.x * 256 + threadIdx.x;
    if (i >= n) return;
    float deg = (float)cnt[i] + 1.0f;   // +1 for added self loop
    dinv[i]   = rsqrtf(deg);
    invdeg[i] = 1.0f / deg;
}

// 3-kernel exclusive prefix scan over cnt[n] -> row_start
__global__ void scan1_k(const int* __restrict__ cnt, int* __restrict__ within,
                        int* __restrict__ btot, int n) {
    __shared__ int s[512];
    int tid = threadIdx.x;
    int i = blockIdx.x * 512 + tid;
    int val = (i < n) ? cnt[i] : 0;
    s[tid] = val;
    __syncthreads();
    for (int off = 1; off < 512; off <<= 1) {
        int v = (tid >= off) ? s[tid - off] : 0;
        __syncthreads();
        s[tid] += v;
        __syncthreads();
    }
    if (i < n) within[i] = s[tid] - val;   // exclusive
    if (tid == 511) btot[blockIdx.x] = s[511];
}

__global__ void scan2_k(const int* __restrict__ btot, int* __restrict__ boff, int nblk) {
    if (threadIdx.x == 0) {
        int run = 0;
        for (int b = 0; b < nblk; ++b) { boff[b] = run; run += btot[b]; }
    }
}

__global__ void scan3_k(const int* __restrict__ within, const int* __restrict__ boff,
                        int* __restrict__ row_start, int* __restrict__ cursor, int n) {
    int i = blockIdx.x * 256 + threadIdx.x;
    if (i >= n) return;
    int v = within[i] + boff[i >> 9];
    row_start[i] = v;
    cursor[i]    = v;
}

__global__ void fill_k(const int* __restrict__ src, const int* __restrict__ dst,
                       const float* __restrict__ dinv, int* __restrict__ cursor,
                       int* __restrict__ eidx, float* __restrict__ ew, int E) {
    int e = blockIdx.x * 256 + threadIdx.x;
    if (e >= E) return;
    int s = src[e], d = dst[e];
    if (s == d) return;
    int pos = atomicAdd(&cursor[d], 1);
    eidx[pos] = s;
    ew[pos]   = dinv[s] * dinv[d];
}

// ---- x f32 -> f16 with K padded (500 -> 512) ----

__global__ void wcvt_k(const float* __restrict__ W, _Float16* __restrict__ Wh,
                       int rows, int K, int Kp) {
    int q = Kp >> 2;
    long long idx = (long long)blockIdx.x * 256 + threadIdx.x;
    if (idx >= (long long)rows * q) return;
    int r = (int)(idx / q), k4 = (int)(idx - (long long)r * q) * 4;
    f16x4 h = {(_Float16)0.f, (_Float16)0.f, (_Float16)0.f, (_Float16)0.f};
    if (k4 < K) {                        // K%4==0 -> all-or-none
        float4 v = *(const float4*)(W + (size_t)r * K + k4);
        h[0] = (_Float16)v.x; h[1] = (_Float16)v.y;
        h[2] = (_Float16)v.z; h[3] = (_Float16)v.w;
    }
    *(f16x4*)(Wh + (size_t)r * Kp + k4) = h;
}

// ---- all three weight matrices converted in ONE launch ----
// W0: 128x500 -> 128x512 (16384 f16x4 items), W1: 128x128 (4096), W2: 64x128 (2048)

__global__ void wcvt3_k(const float* __restrict__ W0, _Float16* __restrict__ W0h,
                        const float* __restrict__ W1, _Float16* __restrict__ W1h,
                        const float* __restrict__ W2, _Float16* __restrict__ W2h) {
    int idx = blockIdx.x * 256 + threadIdx.x;
    if (idx < 16384) {
        int r = idx >> 7, k4 = (idx & 127) * 4;
        f16x4 h = {(_Float16)0.f, (_Float16)0.f, (_Float16)0.f, (_Float16)0.f};
        if (k4 < 500) {
            float4 v = *(const float4*)(W0 + (size_t)r * 500 + k4);
            h[0] = (_Float16)v.x; h[1] = (_Float16)v.y;
            h[2] = (_Float16)v.z; h[3] = (_Float16)v.w;
        }
        *(f16x4*)(W0h + (size_t)r * 512 + k4) = h;
    } else if (idx < 16384 + 4096) {
        int t = idx - 16384;
        float4 v = *(const float4*)(W1 + (size_t)t * 4);
        f16x4 h;
        h[0] = (_Float16)v.x; h[1] = (_Float16)v.y;
        h[2] = (_Float16)v.z; h[3] = (_Float16)v.w;
        *(f16x4*)(W1h + (size_t)t * 4) = h;
    } else if (idx < 16384 + 4096 + 2048) {
        int t = idx - 20480;
        float4 v = *(const float4*)(W2 + (size_t)t * 4);
        f16x4 h;
        h[0] = (_Float16)v.x; h[1] = (_Float16)v.y;
        h[2] = (_Float16)v.z; h[3] = (_Float16)v.w;
        *(f16x4*)(W2h + (size_t)t * 4) = h;
    }
}

// ---------------- MFMA GEMM: C[M,NC] = BN?(A)[M,Kp] * Wh[NC,Kp]^T ------------
// A, Wh f16. f32 accumulate, f16 out. Block: 4 waves; tile 64 x NC; chunk 64.
// Staging: global_load_lds; LDS image row 128B with slot s <- global s^(row&7)
// (inverse-swizzled global source; linear LDS dest); fragment ds_read applies
// the same XOR -> 2-way max bank aliasing.
// BN=true (Kp==128): prologue derives per-k sc/shift from gsum/gsq into LDS;
// after each A ds_read, af = relu(fma(af, sc[k], shift[k])) in f32, repacked
// to f16 (fuses the BatchNorm+ReLU that used to be a separate pass).

template <int NC, bool BN>
__global__ __launch_bounds__(256) void mgemm_k(const _Float16* __restrict__ A,
                                               const _Float16* __restrict__ Wh,
                                               _Float16* __restrict__ C,
                                               const float* __restrict__ gsum,
                                               const float* __restrict__ gsq,
                                               float inv_n, int M, int Kp) {
    constexpr int CT = NC / 16;            // col frags per wave
    constexpr int WJ = NC / 32;            // W gload insts per wave
    __shared__ __align__(16) _Float16 As[2][64 * 64];
    __shared__ __align__(16) _Float16 Ws[2][NC * 64];
    __shared__ __align__(16) float ssc[128], ssh[128];

    const int tid  = threadIdx.x;
    const int lane = tid & 63, wave = tid >> 6;
    const int lrow = lane & 15, kg = lane >> 4;
    const int row0 = blockIdx.x * 64;

    f32x4 acc[CT] = {};

    auto stage = [&](int c0, int b) {
        const int k0 = c0 * 64;
        #pragma unroll
        for (int j = 0; j < 2; ++j) {
            int li  = wave * 128 + j * 64 + lane;      // 0..511
            int row = li >> 3, s = li & 7;
            int gr  = row0 + row;
            int gs  = s ^ (row & 7);
            if (gr < M)
                gload16(A + (size_t)gr * Kp + k0 + gs * 8,
                        (char*)&As[b][0] + (wave * 128 + j * 64) * 16);
        }
        #pragma unroll
        for (int j = 0; j < WJ; ++j) {
            int li  = wave * (WJ * 64) + j * 64 + lane;
            int row = li >> 3, s = li & 7;
            int gs  = s ^ (row & 7);
            gload16(Wh + (size_t)row * Kp + k0 + gs * 8,
                    (char*)&Ws[b][0] + (wave * WJ + j) * 1024);
        }
    };

    auto compute = [&](int b, int kofs) {
        const char* AsB = (const char*)&As[b][0];
        const char* WsB = (const char*)&Ws[b][0];
        #pragma unroll
        for (int ks = 0; ks < 2; ++ks) {
            const int cbase = ks * 64 + kg * 16;       // byte offset in row
            f16x8 af, bf[CT];
            {
                int row = wave * 16 + lrow;
                af = *(const f16x8*)(AsB + row * 128 + (cbase ^ ((row & 7) << 4)));
            }
            if constexpr (BN) {
                const int kb = kofs + ks * 32 + kg * 8;     // 32B aligned
                f32x4 sc0 = *(const f32x4*)&ssc[kb];
                f32x4 sc1 = *(const f32x4*)&ssc[kb + 4];
                f32x4 sh0 = *(const f32x4*)&ssh[kb];
                f32x4 sh1 = *(const f32x4*)&ssh[kb + 4];
                f16x8 a2;
                #pragma unroll
                for (int j = 0; j < 4; ++j) {
                    a2[j]     = (_Float16)fmaxf(0.f, fmaf((float)af[j],     sc0[j], sh0[j]));
                    a2[j + 4] = (_Float16)fmaxf(0.f, fmaf((float)af[j + 4], sc1[j], sh1[j]));
                }
                af = a2;
            }
            #pragma unroll
            for (int ct = 0; ct < CT; ++ct) {
                int row = ct * 16 + lrow;
                bf[ct] = *(const f16x8*)(WsB + row * 128 + (cbase ^ ((row & 7) << 4)));
            }
            #pragma unroll
            for (int ct = 0; ct < CT; ++ct)
                acc[ct] = __builtin_amdgcn_mfma_f32_16x16x32_f16(
                    af, bf[ct], acc[ct], 0, 0, 0);
        }
    };

    if constexpr (BN) {
        if (tid < 128) {                   // Kp == 128 on the BN path
            float mean = gsum[tid] * inv_n;
            float var  = gsq[tid] * inv_n - mean * mean;
            float sc   = rsqrtf(var + EPS_BN);
            ssc[tid] = sc;
            ssh[tid] = -mean * sc;
        }
    }

    const int nchunk = Kp >> 6;            // Kp % 64 == 0
    stage(0, 0);
    asm volatile("s_waitcnt vmcnt(0) lgkmcnt(0)" ::: "memory");
    __builtin_amdgcn_s_barrier();
    __builtin_amdgcn_sched_barrier(0);

    for (int c = 0; c < nchunk; ++c) {
        const int b = c & 1;
        if (c + 1 < nchunk) stage(c + 1, b ^ 1);   // loads fly during compute
        compute(b, c * 64);
        if (c + 1 < nchunk) {
            asm volatile("s_waitcnt vmcnt(0)" ::: "memory");
            __builtin_amdgcn_s_barrier();
            __builtin_amdgcn_sched_barrier(0);
        }
    }

    // ---- epilogue: D lane map col=lane&15, row=(lane>>4)*4+r ----
    #pragma unroll
    for (int r = 0; r < 4; ++r) {
        int grow = row0 + wave * 16 + kg * 4 + r;
        if (grow >= M) continue;
        #pragma unroll
        for (int ct = 0; ct < CT; ++ct)
            C[(size_t)grow * NC + ct * 16 + lrow] = (_Float16)acc[ct][r];
    }
}

// ---------------- GCN aggregation (gather over CSR, f16 in/out) ----------------
// out[i] = sum_{e: dst=i} w_e * h[src_e] + invdeg[i]*h[i] + bias
// TWO nodes per wave: 32 lanes per node, f16x4 per lane, 4-edge unroll.

__global__ void agg128_k(const _Float16* __restrict__ h, const float* __restrict__ invdeg,
                         const int* __restrict__ row_start, const int* __restrict__ cnt,
                         const int* __restrict__ eidx, const float* __restrict__ ew,
                         const float* __restrict__ bias, _Float16* __restrict__ out, int n) {
    const int half = threadIdx.x >> 5;          // 0..7 within block
    const int l = threadIdx.x & 31;
    const int i = blockIdx.x * 8 + half;
    if (i >= n) return;
    const int st = row_start[i], en = st + cnt[i];
    const float id = invdeg[i];
    const int c = l * 4;

    f16x4 hv = *(const f16x4*)(h + (size_t)i * 128 + c);
    float a0 = fmaf(id, (float)hv[0], bias[c]);
    float a1 = fmaf(id, (float)hv[1], bias[c + 1]);
    float a2 = fmaf(id, (float)hv[2], bias[c + 2]);
    float a3 = fmaf(id, (float)hv[3], bias[c + 3]);
    int p = st;
    for (; p + 3 < en; p += 4) {
        int s0 = eidx[p], s1 = eidx[p + 1], s2 = eidx[p + 2], s3 = eidx[p + 3];
        float w0 = ew[p], w1 = ew[p + 1], w2 = ew[p + 2], w3 = ew[p + 3];
        f16x4 v0 = *(const f16x4*)(h + (size_t)s0 * 128 + c);
        f16x4 v1 = *(const f16x4*)(h + (size_t)s1 * 128 + c);
        f16x4 v2 = *(const f16x4*)(h + (size_t)s2 * 128 + c);
        f16x4 v3 = *(const f16x4*)(h + (size_t)s3 * 128 + c);
        a0 = fmaf(w0, (float)v0[0], a0); a1 = fmaf(w0, (float)v0[1], a1);
        a2 = fmaf(w0, (float)v0[2], a2); a3 = fmaf(w0, (float)v0[3], a3);
        a0 = fmaf(w1, (float)v1[0], a0); a1 = fmaf(w1, (float)v1[1], a1);
        a2 = fmaf(w1, (float)v1[2], a2); a3 = fmaf(w1, (float)v1[3], a3);
        a0 = fmaf(w2, (float)v2[0], a0); a1 = fmaf(w2, (float)v2[1], a1);
        a2 = fmaf(w2, (float)v2[2], a2); a3 = fmaf(w2, (float)v2[3], a3);
        a0 = fmaf(w3, (float)v3[0], a0); a1 = fmaf(w3, (float)v3[1], a1);
        a2 = fmaf(w3, (float)v3[2], a2); a3 = fmaf(w3, (float)v3[3], a3);
    }
    for (; p < en; ++p) {
        int s0 = eidx[p]; float w0 = ew[p];
        f16x4 v0 = *(const f16x4*)(h + (size_t)s0 * 128 + c);
        a0 = fmaf(w0, (float)v0[0], a0); a1 = fmaf(w0, (float)v0[1], a1);
        a2 = fmaf(w0, (float)v0[2], a2); a3 = fmaf(w0, (float)v0[3], a3);
    }
    f16x4 o;
    o[0] = (_Float16)a0; o[1] = (_Float16)a1;
    o[2] = (_Float16)a2; o[3] = (_Float16)a3;
    *(f16x4*)(out + (size_t)i * 128 + c) = o;
}

// ---------------- BN stats over f16 activations (12.8 MB read) ----------------
// 256 blocks x 256 thr, grid-stride f16x8. Block LDS reduce -> 256 atomics
// per block (tail ~2us total at 256 blocks).

__global__ void stats16_k(const _Float16* __restrict__ a, float* __restrict__ gsum,
                          float* __restrict__ gsq, int total8) {
    const int tid = threadIdx.x;
    float s[8] = {}, q[8] = {};
    for (int idx = blockIdx.x * 256 + tid; idx < total8; idx += gridDim.x * 256) {
        f16x8 v = *(const f16x8*)(a + (size_t)idx * 8);
        #pragma unroll
        for (int j = 0; j < 8; ++j) {
            float f = (float)v[j];
            s[j] += f;
            q[j] = fmaf(f, f, q[j]);
        }
    }
    __shared__ float red[2][16][16][8];     // [sum/sq][k-group][col-group][col]
    const int g = tid & 15, k = tid >> 4;
    #pragma unroll
    for (int j = 0; j < 8; ++j) {
        red[0][k][g][j] = s[j];
        red[1][k][g][j] = q[j];
    }
    __syncthreads();
    if (tid < 128) {
        const int g2 = tid & 15, j2 = tid >> 4;     // j2 in 0..7
        float ts = 0.f, tq = 0.f;
        #pragma unroll
        for (int k2 = 0; k2 < 16; ++k2) {
            ts += red[0][k2][g2][j2];
            tq += red[1][k2][g2][j2];
        }
        atomicAdd(&gsum[g2 * 8 + j2], ts);
        atomicAdd(&gsq[g2 * 8 + j2], tq);
    }
}

// ---- classifier agg (64 cols) with log_softmax fused; 2 nodes per wave ----

__global__ void aggsm_k(const _Float16* __restrict__ h, const float* __restrict__ invdeg,
                        const int* __restrict__ row_start, const int* __restrict__ cnt,
                        const int* __restrict__ eidx, const float* __restrict__ ew,
                        const float* __restrict__ bias, float* __restrict__ out, int n) {
    const int half = threadIdx.x >> 5;
    const int l = threadIdx.x & 31;
    const int i = blockIdx.x * 8 + half;
    if (i >= n) return;
    const int st = row_start[i], en = st + cnt[i];
    const float id = invdeg[i];
    const int c = l * 2;

    f16x2 hv = *(const f16x2*)(h + (size_t)i * 64 + c);
    float a0 = fmaf(id, (float)hv[0], bias[c]);
    float a1 = fmaf(id, (float)hv[1], bias[c + 1]);
    int p = st;
    for (; p + 3 < en; p += 4) {
        int s0 = eidx[p], s1 = eidx[p + 1], s2 = eidx[p + 2], s3 = eidx[p + 3];
        float w0 = ew[p], w1 = ew[p + 1], w2 = ew[p + 2], w3 = ew[p + 3];
        f16x2 v0 = *(const f16x2*)(h + (size_t)s0 * 64 + c);
        f16x2 v1 = *(const f16x2*)(h + (size_t)s1 * 64 + c);
        f16x2 v2 = *(const f16x2*)(h + (size_t)s2 * 64 + c);
        f16x2 v3 = *(const f16x2*)(h + (size_t)s3 * 64 + c);
        a0 = fmaf(w0, (float)v0[0], a0); a1 = fmaf(w0, (float)v0[1], a1);
        a0 = fmaf(w1, (float)v1[0], a0); a1 = fmaf(w1, (float)v1[1], a1);
        a0 = fmaf(w2, (float)v2[0], a0); a1 = fmaf(w2, (float)v2[1], a1);
        a0 = fmaf(w3, (float)v3[0], a0); a1 = fmaf(w3, (float)v3[1], a1);
    }
    for (; p < en; ++p) {
        int s0 = eidx[p]; float w0 = ew[p];
        f16x2 v0 = *(const f16x2*)(h + (size_t)s0 * 64 + c);
        a0 = fmaf(w0, (float)v0[0], a0); a1 = fmaf(w0, (float)v0[1], a1);
    }

    // fused log_softmax over 64 cols held by this 32-lane half
    float m = fmaxf(a0, a1);
    #pragma unroll
    for (int d = 16; d >= 1; d >>= 1) m = fmaxf(m, __shfl_xor(m, d, 64));
    float e0 = __expf(a0 - m), e1 = __expf(a1 - m);
    float s = e0 + e1;
    #pragma unroll
    for (int d = 16; d >= 1; d >>= 1) s += __shfl_xor(s, d, 64);
    float ls = __logf(s);
    float2 o = make_float2(a0 - m - ls, a1 - m - ls);
    *(float2*)(out + (size_t)i * 64 + c) = o;
}

// ---------------------------------------------------------------------------

extern "C" void kernel_launch(void* const* d_in, const int* in_sizes, int n_in,
                              void* d_out, int out_size, void* d_ws, size_t ws_size,
                              hipStream_t stream) {
    const float* x  = (const float*)d_in[0];
    const int*   ei = (const int*)d_in[1];
    const float* W0 = (const float*)d_in[2];
    const float* b0 = (const float*)d_in[3];
    const float* W1 = (const float*)d_in[4];
    const float* b1 = (const float*)d_in[5];
    const float* W2 = (const float*)d_in[6];
    const float* b2 = (const float*)d_in[7];

    const int IN = 500;
    const int n = in_sizes[0] / IN;      // 50000
    const int E = in_sizes[1] / 2;       // 640000
    const int* src = ei;
    const int* dst = ei + E;

    // ---- workspace bump allocator (256B aligned) ----
    char* p = (char*)d_ws;
    auto alloc = [&](size_t bytes) -> void* {
        char* r = p;
        p += (bytes + 255) & ~(size_t)255;
        return (void*)r;
    };
    _Float16*  xh      = (_Float16*)alloc((size_t)n * 512 * 2);  // x as f16, K padded
    _Float16*  hb1h    = (_Float16*)alloc((size_t)n * 128 * 2);  // GEMM out / agg in
    _Float16*  hb2a    = (_Float16*)alloc((size_t)n * 128 * 2);  // agg out (pre-BN f16)
    _Float16*  W0h     = (_Float16*)alloc((size_t)128 * 512 * 2);
    _Float16*  W1h     = (_Float16*)alloc((size_t)128 * 128 * 2);
    _Float16*  W2h     = (_Float16*)alloc((size_t)64 * 128 * 2);
    // deg_cnt + BN stat buffers allocated contiguously -> single memset
    int*   deg_cnt  = (int*)alloc((size_t)n * 4);
    float* gsum0    = (float*)alloc(128 * 4);
    float* gsq0     = (float*)alloc(128 * 4);
    float* gsum1    = (float*)alloc(128 * 4);
    float* gsq1     = (float*)alloc(128 * 4);
    char*  zero_end = p;
    float* dinv     = (float*)alloc((size_t)n * 4);
    float* invdeg   = (float*)alloc((size_t)n * 4);
    int*   row_st   = (int*)alloc((size_t)n * 4);
    int*   cursor   = (int*)alloc((size_t)n * 4);
    int*   within   = (int*)alloc((size_t)n * 4);
    int*   btot     = (int*)alloc(256 * 4);
    int*   boff     = (int*)alloc(256 * 4);
    int*   eidx     = (int*)alloc((size_t)E * 4);
    float* ew       = (float*)alloc((size_t)E * 4);
    (void)ws_size; (void)n_in; (void)out_size;

    float* out = (float*)d_out;
    const float inv_n = 1.0f / (float)n;

    const int gE = (E + 255) / 256;
    const int gN = (n + 255) / 256;
    const int nblk = (n + 511) / 512;
    const int gM = (n + 63) / 64;        // 782 blocks
    const int gA = (n + 7) / 8;          // 6250 blocks (2 nodes/wave aggs)

    // ---- graph prep + f16 conversions (once per call) ----
    hipMemsetAsync(deg_cnt, 0, (size_t)(zero_end - (char*)deg_cnt), stream);
    count_k<<<gE, 256, 0, stream>>>(src, dst, deg_cnt, E);
    prep_k<<<gN, 256, 0, stream>>>(deg_cnt, dinv, invdeg, n);
    scan1_k<<<nblk, 512, 0, stream>>>(deg_cnt, within, btot, n);
    scan2_k<<<1, 64, 0, stream>>>(btot, boff, nblk);
    scan3_k<<<gN, 256, 0, stream>>>(within, boff, row_st, cursor, n);
    fill_k<<<gE, 256, 0, stream>>>(src, dst, dinv, cursor, eidx, ew, E);
    wcvt3_k<<<(22528 + 255) / 256, 256, 0, stream>>>(W0, W0h, W1, W1h, W2, W2h);
    wcvt_k<<<(n * 128 + 255) / 256, 256, 0, stream>>>(x, xh, n, 500, 512);

    // ---- layer 0 ----
    mgemm_k<128, false><<<gM, 256, 0, stream>>>(xh, W0h, hb1h,
                                                nullptr, nullptr, 0.f, n, 512);
    agg128_k<<<gA, 256, 0, stream>>>(hb1h, invdeg, row_st, deg_cnt, eidx, ew, b0, hb2a, n);
    stats16_k<<<256, 256, 0, stream>>>(hb2a, gsum0, gsq0, n * 16);

    // ---- layer 1 (BN0+ReLU fused into GEMM1's A path) ----
    mgemm_k<128, true><<<gM, 256, 0, stream>>>(hb2a, W1h, hb1h,
                                               gsum0, gsq0, inv_n, n, 128);
    agg128_k<<<gA, 256, 0, stream>>>(hb1h, invdeg, row_st, deg_cnt, eidx, ew, b1, hb2a, n);
    stats16_k<<<256, 256, 0, stream>>>(hb2a, gsum1, gsq1, n * 16);

    // ---- classifier (BN1+ReLU fused into GEMM2; log_softmax fused into agg) ----
    mgemm_k<64, true><<<gM, 256, 0, stream>>>(hb2a, W2h, hb1h,
                                              gsum1, gsq1, inv_n, n, 128);
    aggsm_k<<<gA, 256, 0, stream>>>(hb1h, invdeg, row_st, deg_cnt, eidx, ew, b2, out, n);
}

// Round 13
// 258.865 us; speedup vs baseline: 2.5005x; 1.0756x over previous
//
#include <hip/hip_runtime.h>
#include <hip/hip_bf16.h>
#include <math.h>

// ---------------------------------------------------------------------------
// PMLP_GCN forward:  3x (GEMM -> GCN-agg[+bias]) with BN+ReLU between,
// log_softmax at the end.  N=50000 E=640000 IN=500 HID=128 OUT=64, f32.
// R12: x f32->f16 conversion fused into mgemm0 (depth-1 reg-staged A with
//      in-thread convert + swizzled ds_write; W stays global_load_lds) ->
//      wcvt(x) pass (151MB) removed. prep_k & scan2_k merged into scan3_k.
//      17 -> 14 dispatches.
// ---------------------------------------------------------------------------

#define EPS_BN 1e-5f

typedef __attribute__((ext_vector_type(8))) _Float16 f16x8;
typedef __attribute__((ext_vector_type(4))) _Float16 f16x4;
typedef __attribute__((ext_vector_type(2))) _Float16 f16x2;
typedef __attribute__((ext_vector_type(4))) float    f32x4;

__device__ __forceinline__ void gload16(const void* g, void* l) {
    __builtin_amdgcn_global_load_lds(
        (const __attribute__((address_space(1))) void*)g,
        (__attribute__((address_space(3))) void*)l, 16, 0, 0);
}

// ---------------- graph prep ----------------

__global__ void count_k(const int* __restrict__ src, const int* __restrict__ dst,
                        int* __restrict__ cnt, int E) {
    int e = blockIdx.x * 256 + threadIdx.x;
    if (e >= E) return;
    int s = src[e], d = dst[e];
    if (s != d) atomicAdd(&cnt[d], 1);
}

// block-level exclusive prefix scan over cnt[n] (512-windows)
__global__ void scan1_k(const int* __restrict__ cnt, int* __restrict__ within,
                        int* __restrict__ btot, int n) {
    __shared__ int s[512];
    int tid = threadIdx.x;
    int i = blockIdx.x * 512 + tid;
    int val = (i < n) ? cnt[i] : 0;
    s[tid] = val;
    __syncthreads();
    for (int off = 1; off < 512; off <<= 1) {
        int v = (tid >= off) ? s[tid - off] : 0;
        __syncthreads();
        s[tid] += v;
        __syncthreads();
    }
    if (i < n) within[i] = s[tid] - val;   // exclusive
    if (tid == 511) btot[blockIdx.x] = s[511];
}

// merged: window-offset reduce (was scan2) + row_start/cursor (was scan3)
// + degree transforms (was prep_k)
__global__ void scan3_k(const int* __restrict__ within, const int* __restrict__ btot,
                        const int* __restrict__ cnt, int* __restrict__ row_start,
                        int* __restrict__ cursor, float* __restrict__ dinv,
                        float* __restrict__ invdeg, int n) {
    __shared__ int sred[256];
    const int tid = threadIdx.x;
    const int w = (blockIdx.x * 256) >> 9;          // 512-window index (<= 97)
    sred[tid] = (tid < w) ? btot[tid] : 0;
    __syncthreads();
    #pragma unroll
    for (int off = 128; off >= 1; off >>= 1) {
        if (tid < off) sred[tid] += sred[tid + off];
        __syncthreads();
    }
    const int base = sred[0];
    int i = blockIdx.x * 256 + tid;
    if (i < n) {
        int rs = within[i] + base;
        row_start[i] = rs;
        cursor[i]    = rs;
        float deg = (float)cnt[i] + 1.0f;           // +1 for added self loop
        dinv[i]   = rsqrtf(deg);
        invdeg[i] = 1.0f / deg;
    }
}

__global__ void fill_k(const int* __restrict__ src, const int* __restrict__ dst,
                       const float* __restrict__ dinv, int* __restrict__ cursor,
                       int* __restrict__ eidx, float* __restrict__ ew, int E) {
    int e = blockIdx.x * 256 + threadIdx.x;
    if (e >= E) return;
    int s = src[e], d = dst[e];
    if (s == d) return;
    int pos = atomicAdd(&cursor[d], 1);
    eidx[pos] = s;
    ew[pos]   = dinv[s] * dinv[d];
}

// ---- all three weight matrices converted in ONE launch ----
// W0: 128x500 -> 128x512 (16384 f16x4 items), W1: 128x128 (4096), W2: 64x128 (2048)

__global__ void wcvt3_k(const float* __restrict__ W0, _Float16* __restrict__ W0h,
                        const float* __restrict__ W1, _Float16* __restrict__ W1h,
                        const float* __restrict__ W2, _Float16* __restrict__ W2h) {
    int idx = blockIdx.x * 256 + threadIdx.x;
    if (idx < 16384) {
        int r = idx >> 7, k4 = (idx & 127) * 4;
        f16x4 h = {(_Float16)0.f, (_Float16)0.f, (_Float16)0.f, (_Float16)0.f};
        if (k4 < 500) {
            float4 v = *(const float4*)(W0 + (size_t)r * 500 + k4);
            h[0] = (_Float16)v.x; h[1] = (_Float16)v.y;
            h[2] = (_Float16)v.z; h[3] = (_Float16)v.w;
        }
        *(f16x4*)(W0h + (size_t)r * 512 + k4) = h;
    } else if (idx < 16384 + 4096) {
        int t = idx - 16384;
        float4 v = *(const float4*)(W1 + (size_t)t * 4);
        f16x4 h;
        h[0] = (_Float16)v.x; h[1] = (_Float16)v.y;
        h[2] = (_Float16)v.z; h[3] = (_Float16)v.w;
        *(f16x4*)(W1h + (size_t)t * 4) = h;
    } else if (idx < 16384 + 4096 + 2048) {
        int t = idx - 20480;
        float4 v = *(const float4*)(W2 + (size_t)t * 4);
        f16x4 h;
        h[0] = (_Float16)v.x; h[1] = (_Float16)v.y;
        h[2] = (_Float16)v.z; h[3] = (_Float16)v.w;
        *(f16x4*)(W2h + (size_t)t * 4) = h;
    }
}

// ---------------- MFMA GEMM: C[M,NC] = BN?(A)[M,K] * Wh[NC,Kp]^T ------------
// Wh f16 (padded Kp). f32 accumulate, f16 out. 4 waves; tile 64 x NC; chunk 64.
// AF32=false: A f16 (padded Kp) staged via global_load_lds with inverse-
//   swizzled global source, linear LDS dest (both-sides rule).
// AF32=true (layer 0): A = raw f32 x (stride K=500); staged depth-1 through
//   registers (local float4[4] + capturing lambdas, constant indices - the
//   R3-proven no-spill shape), converted f32->f16 in-thread, ds_write with
//   the same XOR swizzle -> identical LDS image, no wcvt pass, no padding.
// Fragment ds_read applies byte ^= (row&7)<<4 -> 2-way max bank aliasing.
// BN=true (Kp==128): per-k scale/shift from gsum/gsq in LDS, applied to the
//   A fragment in registers (fused BatchNorm+ReLU).
// Pipeline: stage(c+1)+loadA(c+1); compute(c); storeA(c+1); drain; barrier.

template <int NC, bool BN, bool AF32>
__global__ __launch_bounds__(256) void mgemm_k(const void* __restrict__ Av,
                                               const _Float16* __restrict__ Wh,
                                               _Float16* __restrict__ C,
                                               const float* __restrict__ gsum,
                                               const float* __restrict__ gsq,
                                               float inv_n, int M, int K, int Kp) {
    constexpr int CT = NC / 16;            // col frags per wave
    constexpr int WJ = NC / 32;            // W gload insts per wave
    __shared__ __align__(16) _Float16 As[2][64 * 64];
    __shared__ __align__(16) _Float16 Ws[2][NC * 64];
    __shared__ __align__(16) float ssc[128], ssh[128];

    const int tid  = threadIdx.x;
    const int lane = tid & 63, wave = tid >> 6;
    const int lrow = lane & 15, kg = lane >> 4;
    const int row0 = blockIdx.x * 64;

    f32x4 acc[CT] = {};
    float4 aw[4];                           // depth-1 A prefetch (AF32 path)

    const float*    Af = (const float*)Av;
    const _Float16* Ah = (const _Float16*)Av;

    auto stage = [&](int c0, int b) {
        const int k0 = c0 * 64;
        if constexpr (!AF32) {
            // A tile via gload_lds: 64 rows x 128B -> 2 insts per wave
            #pragma unroll
            for (int j = 0; j < 2; ++j) {
                int li  = wave * 128 + j * 64 + lane;      // 0..511
                int row = li >> 3, s = li & 7;
                int gr  = row0 + row;
                int gs  = s ^ (row & 7);
                if (gr < M)
                    gload16(Ah + (size_t)gr * Kp + k0 + gs * 8,
                            (char*)&As[b][0] + (wave * 128 + j * 64) * 16);
            }
        }
        #pragma unroll
        for (int j = 0; j < WJ; ++j) {
            int li  = wave * (WJ * 64) + j * 64 + lane;
            int row = li >> 3, s = li & 7;
            int gs  = s ^ (row & 7);
            gload16(Wh + (size_t)row * Kp + k0 + gs * 8,
                    (char*)&Ws[b][0] + (wave * WJ + j) * 1024);
        }
    };

    // AF32 path: 64 rows x 16 float4 slots = 1024 lane-slots, 4 per thread
    auto load_a = [&](int c0) {
        const int k0 = c0 * 64;
        #pragma unroll
        for (int it = 0; it < 4; ++it) {
            int idx = tid + it * 256;
            int row = idx >> 4, slot = idx & 15;
            int gr = row0 + row, gk = k0 + slot * 4;
            aw[it] = make_float4(0.f, 0.f, 0.f, 0.f);
            if (gr < M && gk < K)                      // K%4==0 -> all-or-none
                aw[it] = *(const float4*)(Af + (size_t)gr * K + gk);
        }
    };
    auto store_a = [&](int b) {
        #pragma unroll
        for (int it = 0; it < 4; ++it) {
            int idx = tid + it * 256;
            int row = idx >> 4, slot = idx & 15;
            f16x4 h;
            h[0] = (_Float16)aw[it].x; h[1] = (_Float16)aw[it].y;
            h[2] = (_Float16)aw[it].z; h[3] = (_Float16)aw[it].w;
            int cb = (slot * 8) ^ ((row & 7) << 4);
            *(f16x4*)((char*)&As[b][0] + row * 128 + cb) = h;
        }
    };

    auto compute = [&](int b, int kofs) {
        const char* AsB = (const char*)&As[b][0];
        const char* WsB = (const char*)&Ws[b][0];
        #pragma unroll
        for (int ks = 0; ks < 2; ++ks) {
            const int cbase = ks * 64 + kg * 16;       // byte offset in row
            f16x8 af, bf[CT];
            {
                int row = wave * 16 + lrow;
                af = *(const f16x8*)(AsB + row * 128 + (cbase ^ ((row & 7) << 4)));
            }
            if constexpr (BN) {
                const int kb = kofs + ks * 32 + kg * 8;
                f32x4 sc0 = *(const f32x4*)&ssc[kb];
                f32x4 sc1 = *(const f32x4*)&ssc[kb + 4];
                f32x4 sh0 = *(const f32x4*)&ssh[kb];
                f32x4 sh1 = *(const f32x4*)&ssh[kb + 4];
                f16x8 a2;
                #pragma unroll
                for (int j = 0; j < 4; ++j) {
                    a2[j]     = (_Float16)fmaxf(0.f, fmaf((float)af[j],     sc0[j], sh0[j]));
                    a2[j + 4] = (_Float16)fmaxf(0.f, fmaf((float)af[j + 4], sc1[j], sh1[j]));
                }
                af = a2;
            }
            #pragma unroll
            for (int ct = 0; ct < CT; ++ct) {
                int row = ct * 16 + lrow;
                bf[ct] = *(const f16x8*)(WsB + row * 128 + (cbase ^ ((row & 7) << 4)));
            }
            #pragma unroll
            for (int ct = 0; ct < CT; ++ct)
                acc[ct] = __builtin_amdgcn_mfma_f32_16x16x32_f16(
                    af, bf[ct], acc[ct], 0, 0, 0);
        }
    };

    if constexpr (BN) {
        if (tid < 128) {                   // Kp == 128 on the BN path
            float mean = gsum[tid] * inv_n;
            float var  = gsq[tid] * inv_n - mean * mean;
            float sc   = rsqrtf(var + EPS_BN);
            ssc[tid] = sc;
            ssh[tid] = -mean * sc;
        }
    }

    const int nchunk = Kp >> 6;            // Kp % 64 == 0
    if constexpr (AF32) { load_a(0); }
    stage(0, 0);
    if constexpr (AF32) { store_a(0); }
    asm volatile("s_waitcnt vmcnt(0) lgkmcnt(0)" ::: "memory");
    __builtin_amdgcn_s_barrier();
    __builtin_amdgcn_sched_barrier(0);

    for (int c = 0; c < nchunk; ++c) {
        const int b = c & 1;
        const bool more = (c + 1 < nchunk);
        if (more) {
            stage(c + 1, b ^ 1);           // W (and f16-A) loads fly during compute
            if constexpr (AF32) load_a(c + 1);
        }
        compute(b, c * 64);
        if (more) {
            if constexpr (AF32) store_a(b ^ 1);
            asm volatile("s_waitcnt vmcnt(0) lgkmcnt(0)" ::: "memory");
            __builtin_amdgcn_s_barrier();
            __builtin_amdgcn_sched_barrier(0);
        }
    }

    // ---- epilogue: D lane map col=lane&15, row=(lane>>4)*4+r ----
    #pragma unroll
    for (int r = 0; r < 4; ++r) {
        int grow = row0 + wave * 16 + kg * 4 + r;
        if (grow >= M) continue;
        #pragma unroll
        for (int ct = 0; ct < CT; ++ct)
            C[(size_t)grow * NC + ct * 16 + lrow] = (_Float16)acc[ct][r];
    }
}

// ---------------- GCN aggregation (gather over CSR, f16 in/out) ----------------
// out[i] = sum_{e: dst=i} w_e * h[src_e] + invdeg[i]*h[i] + bias
// TWO nodes per wave: 32 lanes per node, f16x4 per lane, 4-edge unroll.

__global__ void agg128_k(const _Float16* __restrict__ h, const float* __restrict__ invdeg,
                         const int* __restrict__ row_start, const int* __restrict__ cnt,
                         const int* __restrict__ eidx, const float* __restrict__ ew,
                         const float* __restrict__ bias, _Float16* __restrict__ out, int n) {
    const int half = threadIdx.x >> 5;          // 0..7 within block
    const int l = threadIdx.x & 31;
    const int i = blockIdx.x * 8 + half;
    if (i >= n) return;
    const int st = row_start[i], en = st + cnt[i];
    const float id = invdeg[i];
    const int c = l * 4;

    f16x4 hv = *(const f16x4*)(h + (size_t)i * 128 + c);
    float a0 = fmaf(id, (float)hv[0], bias[c]);
    float a1 = fmaf(id, (float)hv[1], bias[c + 1]);
    float a2 = fmaf(id, (float)hv[2], bias[c + 2]);
    float a3 = fmaf(id, (float)hv[3], bias[c + 3]);
    int p = st;
    for (; p + 3 < en; p += 4) {
        int s0 = eidx[p], s1 = eidx[p + 1], s2 = eidx[p + 2], s3 = eidx[p + 3];
        float w0 = ew[p], w1 = ew[p + 1], w2 = ew[p + 2], w3 = ew[p + 3];
        f16x4 v0 = *(const f16x4*)(h + (size_t)s0 * 128 + c);
        f16x4 v1 = *(const f16x4*)(h + (size_t)s1 * 128 + c);
        f16x4 v2 = *(const f16x4*)(h + (size_t)s2 * 128 + c);
        f16x4 v3 = *(const f16x4*)(h + (size_t)s3 * 128 + c);
        a0 = fmaf(w0, (float)v0[0], a0); a1 = fmaf(w0, (float)v0[1], a1);
        a2 = fmaf(w0, (float)v0[2], a2); a3 = fmaf(w0, (float)v0[3], a3);
        a0 = fmaf(w1, (float)v1[0], a0); a1 = fmaf(w1, (float)v1[1], a1);
        a2 = fmaf(w1, (float)v1[2], a2); a3 = fmaf(w1, (float)v1[3], a3);
        a0 = fmaf(w2, (float)v2[0], a0); a1 = fmaf(w2, (float)v2[1], a1);
        a2 = fmaf(w2, (float)v2[2], a2); a3 = fmaf(w2, (float)v2[3], a3);
        a0 = fmaf(w3, (float)v3[0], a0); a1 = fmaf(w3, (float)v3[1], a1);
        a2 = fmaf(w3, (float)v3[2], a2); a3 = fmaf(w3, (float)v3[3], a3);
    }
    for (; p < en; ++p) {
        int s0 = eidx[p]; float w0 = ew[p];
        f16x4 v0 = *(const f16x4*)(h + (size_t)s0 * 128 + c);
        a0 = fmaf(w0, (float)v0[0], a0); a1 = fmaf(w0, (float)v0[1], a1);
        a2 = fmaf(w0, (float)v0[2], a2); a3 = fmaf(w0, (float)v0[3], a3);
    }
    f16x4 o;
    o[0] = (_Float16)a0; o[1] = (_Float16)a1;
    o[2] = (_Float16)a2; o[3] = (_Float16)a3;
    *(f16x4*)(out + (size_t)i * 128 + c) = o;
}

// ---------------- BN stats over f16 activations (12.8 MB read) ----------------
// 256 blocks x 256 thr, grid-stride f16x8. Block LDS reduce -> 256 atomics
// per block (tail ~2us total at 256 blocks).

__global__ void stats16_k(const _Float16* __restrict__ a, float* __restrict__ gsum,
                          float* __restrict__ gsq, int total8) {
    const int tid = threadIdx.x;
    float s[8] = {}, q[8] = {};
    for (int idx = blockIdx.x * 256 + tid; idx < total8; idx += gridDim.x * 256) {
        f16x8 v = *(const f16x8*)(a + (size_t)idx * 8);
        #pragma unroll
        for (int j = 0; j < 8; ++j) {
            float f = (float)v[j];
            s[j] += f;
            q[j] = fmaf(f, f, q[j]);
        }
    }
    __shared__ float red[2][16][16][8];     // [sum/sq][k-group][col-group][col]
    const int g = tid & 15, k = tid >> 4;
    #pragma unroll
    for (int j = 0; j < 8; ++j) {
        red[0][k][g][j] = s[j];
        red[1][k][g][j] = q[j];
    }
    __syncthreads();
    if (tid < 128) {
        const int g2 = tid & 15, j2 = tid >> 4;     // j2 in 0..7
        float ts = 0.f, tq = 0.f;
        #pragma unroll
        for (int k2 = 0; k2 < 16; ++k2) {
            ts += red[0][k2][g2][j2];
            tq += red[1][k2][g2][j2];
        }
        atomicAdd(&gsum[g2 * 8 + j2], ts);
        atomicAdd(&gsq[g2 * 8 + j2], tq);
    }
}

// ---- classifier agg (64 cols) with log_softmax fused; 2 nodes per wave ----

__global__ void aggsm_k(const _Float16* __restrict__ h, const float* __restrict__ invdeg,
                        const int* __restrict__ row_start, const int* __restrict__ cnt,
                        const int* __restrict__ eidx, const float* __restrict__ ew,
                        const float* __restrict__ bias, float* __restrict__ out, int n) {
    const int half = threadIdx.x >> 5;
    const int l = threadIdx.x & 31;
    const int i = blockIdx.x * 8 + half;
    if (i >= n) return;
    const int st = row_start[i], en = st + cnt[i];
    const float id = invdeg[i];
    const int c = l * 2;

    f16x2 hv = *(const f16x2*)(h + (size_t)i * 64 + c);
    float a0 = fmaf(id, (float)hv[0], bias[c]);
    float a1 = fmaf(id, (float)hv[1], bias[c + 1]);
    int p = st;
    for (; p + 3 < en; p += 4) {
        int s0 = eidx[p], s1 = eidx[p + 1], s2 = eidx[p + 2], s3 = eidx[p + 3];
        float w0 = ew[p], w1 = ew[p + 1], w2 = ew[p + 2], w3 = ew[p + 3];
        f16x2 v0 = *(const f16x2*)(h + (size_t)s0 * 64 + c);
        f16x2 v1 = *(const f16x2*)(h + (size_t)s1 * 64 + c);
        f16x2 v2 = *(const f16x2*)(h + (size_t)s2 * 64 + c);
        f16x2 v3 = *(const f16x2*)(h + (size_t)s3 * 64 + c);
        a0 = fmaf(w0, (float)v0[0], a0); a1 = fmaf(w0, (float)v0[1], a1);
        a0 = fmaf(w1, (float)v1[0], a0); a1 = fmaf(w1, (float)v1[1], a1);
        a0 = fmaf(w2, (float)v2[0], a0); a1 = fmaf(w2, (float)v2[1], a1);
        a0 = fmaf(w3, (float)v3[0], a0); a1 = fmaf(w3, (float)v3[1], a1);
    }
    for (; p < en; ++p) {
        int s0 = eidx[p]; float w0 = ew[p];
        f16x2 v0 = *(const f16x2*)(h + (size_t)s0 * 64 + c);
        a0 = fmaf(w0, (float)v0[0], a0); a1 = fmaf(w0, (float)v0[1], a1);
    }

    // fused log_softmax over 64 cols held by this 32-lane half
    float m = fmaxf(a0, a1);
    #pragma unroll
    for (int d = 16; d >= 1; d >>= 1) m = fmaxf(m, __shfl_xor(m, d, 64));
    float e0 = __expf(a0 - m), e1 = __expf(a1 - m);
    float s = e0 + e1;
    #pragma unroll
    for (int d = 16; d >= 1; d >>= 1) s += __shfl_xor(s, d, 64);
    float ls = __logf(s);
    float2 o = make_float2(a0 - m - ls, a1 - m - ls);
    *(float2*)(out + (size_t)i * 64 + c) = o;
}

// ---------------------------------------------------------------------------

extern "C" void kernel_launch(void* const* d_in, const int* in_sizes, int n_in,
                              void* d_out, int out_size, void* d_ws, size_t ws_size,
                              hipStream_t stream) {
    const float* x  = (const float*)d_in[0];
    const int*   ei = (const int*)d_in[1];
    const float* W0 = (const float*)d_in[2];
    const float* b0 = (const float*)d_in[3];
    const float* W1 = (const float*)d_in[4];
    const float* b1 = (const float*)d_in[5];
    const float* W2 = (const float*)d_in[6];
    const float* b2 = (const float*)d_in[7];

    const int IN = 500;
    const int n = in_sizes[0] / IN;      // 50000
    const int E = in_sizes[1] / 2;       // 640000
    const int* src = ei;
    const int* dst = ei + E;

    // ---- workspace bump allocator (256B aligned) ----
    char* p = (char*)d_ws;
    auto alloc = [&](size_t bytes) -> void* {
        char* r = p;
        p += (bytes + 255) & ~(size_t)255;
        return (void*)r;
    };
    _Float16*  hb1h    = (_Float16*)alloc((size_t)n * 128 * 2);  // GEMM out / agg in
    _Float16*  hb2a    = (_Float16*)alloc((size_t)n * 128 * 2);  // agg out (pre-BN f16)
    _Float16*  W0h     = (_Float16*)alloc((size_t)128 * 512 * 2);
    _Float16*  W1h     = (_Float16*)alloc((size_t)128 * 128 * 2);
    _Float16*  W2h     = (_Float16*)alloc((size_t)64 * 128 * 2);
    // deg_cnt + BN stat buffers allocated contiguously -> single memset
    int*   deg_cnt  = (int*)alloc((size_t)n * 4);
    float* gsum0    = (float*)alloc(128 * 4);
    float* gsq0     = (float*)alloc(128 * 4);
    float* gsum1    = (float*)alloc(128 * 4);
    float* gsq1     = (float*)alloc(128 * 4);
    char*  zero_end = p;
    float* dinv     = (float*)alloc((size_t)n * 4);
    float* invdeg   = (float*)alloc((size_t)n * 4);
    int*   row_st   = (int*)alloc((size_t)n * 4);
    int*   cursor   = (int*)alloc((size_t)n * 4);
    int*   within   = (int*)alloc((size_t)n * 4);
    int*   btot     = (int*)alloc(256 * 4);
    int*   eidx     = (int*)alloc((size_t)E * 4);
    float* ew       = (float*)alloc((size_t)E * 4);
    (void)ws_size; (void)n_in; (void)out_size;

    float* out = (float*)d_out;
    const float inv_n = 1.0f / (float)n;

    const int gE = (E + 255) / 256;
    const int gN = (n + 255) / 256;
    const int nblk = (n + 511) / 512;
    const int gM = (n + 63) / 64;        // 782 blocks
    const int gA = (n + 7) / 8;          // 6250 blocks (2 nodes/wave aggs)

    // ---- graph prep + weight conversion (once per call) ----
    hipMemsetAsync(deg_cnt, 0, (size_t)(zero_end - (char*)deg_cnt), stream);
    count_k<<<gE, 256, 0, stream>>>(src, dst, deg_cnt, E);
    scan1_k<<<nblk, 512, 0, stream>>>(deg_cnt, within, btot, n);
    scan3_k<<<gN, 256, 0, stream>>>(within, btot, deg_cnt, row_st, cursor,
                                    dinv, invdeg, n);
    fill_k<<<gE, 256, 0, stream>>>(src, dst, dinv, cursor, eidx, ew, E);
    wcvt3_k<<<(22528 + 255) / 256, 256, 0, stream>>>(W0, W0h, W1, W1h, W2, W2h);

    // ---- layer 0 (x read as f32 directly; f16 convert fused into staging) ----
    mgemm_k<128, false, true><<<gM, 256, 0, stream>>>(x, W0h, hb1h,
                                                      nullptr, nullptr, 0.f,
                                                      n, 500, 512);
    agg128_k<<<gA, 256, 0, stream>>>(hb1h, invdeg, row_st, deg_cnt, eidx, ew, b0, hb2a, n);
    stats16_k<<<256, 256, 0, stream>>>(hb2a, gsum0, gsq0, n * 16);

    // ---- layer 1 (BN0+ReLU fused into GEMM1's A path) ----
    mgemm_k<128, true, false><<<gM, 256, 0, stream>>>(hb2a, W1h, hb1h,
                                                      gsum0, gsq0, inv_n,
                                                      n, 128, 128);
    agg128_k<<<gA, 256, 0, stream>>>(hb1h, invdeg, row_st, deg_cnt, eidx, ew, b1, hb2a, n);
    stats16_k<<<256, 256, 0, stream>>>(hb2a, gsum1, gsq1, n * 16);

    // ---- classifier (BN1+ReLU fused into GEMM2; log_softmax fused into agg) ----
    mgemm_k<64, true, false><<<gM, 256, 0, stream>>>(hb2a, W2h, hb1h,
                                                     gsum1, gsq1, inv_n,
                                                     n, 128, 128);
    aggsm_k<<<gA, 256, 0, stream>>>(hb1h, invdeg, row_st, deg_cnt, eidx, ew, b2, out, n);
}

// Round 14
// 233.851 us; speedup vs baseline: 2.7680x; 1.1070x over previous
//
#include <hip/hip_runtime.h>
#include <hip/hip_bf16.h>
#include <math.h>

// ---------------------------------------------------------------------------
// PMLP_GCN forward:  3x (GEMM -> GCN-agg[+bias]) with BN+ReLU between,
// log_softmax at the end.  N=50000 E=640000 IN=500 HID=128 OUT=64, f32.
// R13: aggs use 4 nodes/wave (16 lanes x f16x8 per node) -> 64B/lane in
//      flight + 4 independent gather chains per wave; edge (idx,weight)
//      packed into one int2 record (one load / one store per edge).
// ---------------------------------------------------------------------------

#define EPS_BN 1e-5f

typedef __attribute__((ext_vector_type(8))) _Float16 f16x8;
typedef __attribute__((ext_vector_type(4))) _Float16 f16x4;
typedef __attribute__((ext_vector_type(2))) _Float16 f16x2;
typedef __attribute__((ext_vector_type(4))) float    f32x4;

__device__ __forceinline__ void gload16(const void* g, void* l) {
    __builtin_amdgcn_global_load_lds(
        (const __attribute__((address_space(1))) void*)g,
        (__attribute__((address_space(3))) void*)l, 16, 0, 0);
}

// ---------------- graph prep ----------------

__global__ void count_k(const int* __restrict__ src, const int* __restrict__ dst,
                        int* __restrict__ cnt, int E) {
    int e = blockIdx.x * 256 + threadIdx.x;
    if (e >= E) return;
    int s = src[e], d = dst[e];
    if (s != d) atomicAdd(&cnt[d], 1);
}

// block-level exclusive prefix scan over cnt[n] (512-windows)
__global__ void scan1_k(const int* __restrict__ cnt, int* __restrict__ within,
                        int* __restrict__ btot, int n) {
    __shared__ int s[512];
    int tid = threadIdx.x;
    int i = blockIdx.x * 512 + tid;
    int val = (i < n) ? cnt[i] : 0;
    s[tid] = val;
    __syncthreads();
    for (int off = 1; off < 512; off <<= 1) {
        int v = (tid >= off) ? s[tid - off] : 0;
        __syncthreads();
        s[tid] += v;
        __syncthreads();
    }
    if (i < n) within[i] = s[tid] - val;   // exclusive
    if (tid == 511) btot[blockIdx.x] = s[511];
}

// merged: window-offset reduce + row_start/cursor + degree transforms
__global__ void scan3_k(const int* __restrict__ within, const int* __restrict__ btot,
                        const int* __restrict__ cnt, int* __restrict__ row_start,
                        int* __restrict__ cursor, float* __restrict__ dinv,
                        float* __restrict__ invdeg, int n) {
    __shared__ int sred[256];
    const int tid = threadIdx.x;
    const int w = (blockIdx.x * 256) >> 9;          // 512-window index (<= 97)
    sred[tid] = (tid < w) ? btot[tid] : 0;
    __syncthreads();
    #pragma unroll
    for (int off = 128; off >= 1; off >>= 1) {
        if (tid < off) sred[tid] += sred[tid + off];
        __syncthreads();
    }
    const int base = sred[0];
    int i = blockIdx.x * 256 + tid;
    if (i < n) {
        int rs = within[i] + base;
        row_start[i] = rs;
        cursor[i]    = rs;
        float deg = (float)cnt[i] + 1.0f;           // +1 for added self loop
        dinv[i]   = rsqrtf(deg);
        invdeg[i] = 1.0f / deg;
    }
}

// packed edge record: .x = src node, .y = bitcast f32 weight
__global__ void fill_k(const int* __restrict__ src, const int* __restrict__ dst,
                       const float* __restrict__ dinv, int* __restrict__ cursor,
                       int2* __restrict__ epk, int E) {
    int e = blockIdx.x * 256 + threadIdx.x;
    if (e >= E) return;
    int s = src[e], d = dst[e];
    if (s == d) return;
    int pos = atomicAdd(&cursor[d], 1);
    epk[pos] = make_int2(s, __float_as_int(dinv[s] * dinv[d]));
}

// ---- all three weight matrices converted in ONE launch ----

__global__ void wcvt3_k(const float* __restrict__ W0, _Float16* __restrict__ W0h,
                        const float* __restrict__ W1, _Float16* __restrict__ W1h,
                        const float* __restrict__ W2, _Float16* __restrict__ W2h) {
    int idx = blockIdx.x * 256 + threadIdx.x;
    if (idx < 16384) {
        int r = idx >> 7, k4 = (idx & 127) * 4;
        f16x4 h = {(_Float16)0.f, (_Float16)0.f, (_Float16)0.f, (_Float16)0.f};
        if (k4 < 500) {
            float4 v = *(const float4*)(W0 + (size_t)r * 500 + k4);
            h[0] = (_Float16)v.x; h[1] = (_Float16)v.y;
            h[2] = (_Float16)v.z; h[3] = (_Float16)v.w;
        }
        *(f16x4*)(W0h + (size_t)r * 512 + k4) = h;
    } else if (idx < 16384 + 4096) {
        int t = idx - 16384;
        float4 v = *(const float4*)(W1 + (size_t)t * 4);
        f16x4 h;
        h[0] = (_Float16)v.x; h[1] = (_Float16)v.y;
        h[2] = (_Float16)v.z; h[3] = (_Float16)v.w;
        *(f16x4*)(W1h + (size_t)t * 4) = h;
    } else if (idx < 16384 + 4096 + 2048) {
        int t = idx - 20480;
        float4 v = *(const float4*)(W2 + (size_t)t * 4);
        f16x4 h;
        h[0] = (_Float16)v.x; h[1] = (_Float16)v.y;
        h[2] = (_Float16)v.z; h[3] = (_Float16)v.w;
        *(f16x4*)(W2h + (size_t)t * 4) = h;
    }
}

// ---------------- MFMA GEMM: C[M,NC] = BN?(A)[M,K] * Wh[NC,Kp]^T ------------
// (unchanged from R12 — see comments there)

template <int NC, bool BN, bool AF32>
__global__ __launch_bounds__(256) void mgemm_k(const void* __restrict__ Av,
                                               const _Float16* __restrict__ Wh,
                                               _Float16* __restrict__ C,
                                               const float* __restrict__ gsum,
                                               const float* __restrict__ gsq,
                                               float inv_n, int M, int K, int Kp) {
    constexpr int CT = NC / 16;            // col frags per wave
    constexpr int WJ = NC / 32;            // W gload insts per wave
    __shared__ __align__(16) _Float16 As[2][64 * 64];
    __shared__ __align__(16) _Float16 Ws[2][NC * 64];
    __shared__ __align__(16) float ssc[128], ssh[128];

    const int tid  = threadIdx.x;
    const int lane = tid & 63, wave = tid >> 6;
    const int lrow = lane & 15, kg = lane >> 4;
    const int row0 = blockIdx.x * 64;

    f32x4 acc[CT] = {};
    float4 aw[4];                           // depth-1 A prefetch (AF32 path)

    const float*    Af = (const float*)Av;
    const _Float16* Ah = (const _Float16*)Av;

    auto stage = [&](int c0, int b) {
        const int k0 = c0 * 64;
        if constexpr (!AF32) {
            #pragma unroll
            for (int j = 0; j < 2; ++j) {
                int li  = wave * 128 + j * 64 + lane;      // 0..511
                int row = li >> 3, s = li & 7;
                int gr  = row0 + row;
                int gs  = s ^ (row & 7);
                if (gr < M)
                    gload16(Ah + (size_t)gr * Kp + k0 + gs * 8,
                            (char*)&As[b][0] + (wave * 128 + j * 64) * 16);
            }
        }
        #pragma unroll
        for (int j = 0; j < WJ; ++j) {
            int li  = wave * (WJ * 64) + j * 64 + lane;
            int row = li >> 3, s = li & 7;
            int gs  = s ^ (row & 7);
            gload16(Wh + (size_t)row * Kp + k0 + gs * 8,
                    (char*)&Ws[b][0] + (wave * WJ + j) * 1024);
        }
    };

    auto load_a = [&](int c0) {
        const int k0 = c0 * 64;
        #pragma unroll
        for (int it = 0; it < 4; ++it) {
            int idx = tid + it * 256;
            int row = idx >> 4, slot = idx & 15;
            int gr = row0 + row, gk = k0 + slot * 4;
            aw[it] = make_float4(0.f, 0.f, 0.f, 0.f);
            if (gr < M && gk < K)                      // K%4==0 -> all-or-none
                aw[it] = *(const float4*)(Af + (size_t)gr * K + gk);
        }
    };
    auto store_a = [&](int b) {
        #pragma unroll
        for (int it = 0; it < 4; ++it) {
            int idx = tid + it * 256;
            int row = idx >> 4, slot = idx & 15;
            f16x4 h;
            h[0] = (_Float16)aw[it].x; h[1] = (_Float16)aw[it].y;
            h[2] = (_Float16)aw[it].z; h[3] = (_Float16)aw[it].w;
            int cb = (slot * 8) ^ ((row & 7) << 4);
            *(f16x4*)((char*)&As[b][0] + row * 128 + cb) = h;
        }
    };

    auto compute = [&](int b, int kofs) {
        const char* AsB = (const char*)&As[b][0];
        const char* WsB = (const char*)&Ws[b][0];
        #pragma unroll
        for (int ks = 0; ks < 2; ++ks) {
            const int cbase = ks * 64 + kg * 16;       // byte offset in row
            f16x8 af, bf[CT];
            {
                int row = wave * 16 + lrow;
                af = *(const f16x8*)(AsB + row * 128 + (cbase ^ ((row & 7) << 4)));
            }
            if constexpr (BN) {
                const int kb = kofs + ks * 32 + kg * 8;
                f32x4 sc0 = *(const f32x4*)&ssc[kb];
                f32x4 sc1 = *(const f32x4*)&ssc[kb + 4];
                f32x4 sh0 = *(const f32x4*)&ssh[kb];
                f32x4 sh1 = *(const f32x4*)&ssh[kb + 4];
                f16x8 a2;
                #pragma unroll
                for (int j = 0; j < 4; ++j) {
                    a2[j]     = (_Float16)fmaxf(0.f, fmaf((float)af[j],     sc0[j], sh0[j]));
                    a2[j + 4] = (_Float16)fmaxf(0.f, fmaf((float)af[j + 4], sc1[j], sh1[j]));
                }
                af = a2;
            }
            #pragma unroll
            for (int ct = 0; ct < CT; ++ct) {
                int row = ct * 16 + lrow;
                bf[ct] = *(const f16x8*)(WsB + row * 128 + (cbase ^ ((row & 7) << 4)));
            }
            #pragma unroll
            for (int ct = 0; ct < CT; ++ct)
                acc[ct] = __builtin_amdgcn_mfma_f32_16x16x32_f16(
                    af, bf[ct], acc[ct], 0, 0, 0);
        }
    };

    if constexpr (BN) {
        if (tid < 128) {                   // Kp == 128 on the BN path
            float mean = gsum[tid] * inv_n;
            float var  = gsq[tid] * inv_n - mean * mean;
            float sc   = rsqrtf(var + EPS_BN);
            ssc[tid] = sc;
            ssh[tid] = -mean * sc;
        }
    }

    const int nchunk = Kp >> 6;            // Kp % 64 == 0
    if constexpr (AF32) { load_a(0); }
    stage(0, 0);
    if constexpr (AF32) { store_a(0); }
    asm volatile("s_waitcnt vmcnt(0) lgkmcnt(0)" ::: "memory");
    __builtin_amdgcn_s_barrier();
    __builtin_amdgcn_sched_barrier(0);

    for (int c = 0; c < nchunk; ++c) {
        const int b = c & 1;
        const bool more = (c + 1 < nchunk);
        if (more) {
            stage(c + 1, b ^ 1);
            if constexpr (AF32) load_a(c + 1);
        }
        compute(b, c * 64);
        if (more) {
            if constexpr (AF32) store_a(b ^ 1);
            asm volatile("s_waitcnt vmcnt(0) lgkmcnt(0)" ::: "memory");
            __builtin_amdgcn_s_barrier();
            __builtin_amdgcn_sched_barrier(0);
        }
    }

    // ---- epilogue: D lane map col=lane&15, row=(lane>>4)*4+r ----
    #pragma unroll
    for (int r = 0; r < 4; ++r) {
        int grow = row0 + wave * 16 + kg * 4 + r;
        if (grow >= M) continue;
        #pragma unroll
        for (int ct = 0; ct < CT; ++ct)
            C[(size_t)grow * NC + ct * 16 + lrow] = (_Float16)acc[ct][r];
    }
}

// ---------------- GCN aggregation (gather over CSR, f16 in/out) ----------------
// out[i] = sum_{e: dst=i} w_e * h[src_e] + invdeg[i]*h[i] + bias
// FOUR nodes per wave: 16 lanes per node, f16x8 (16B) per lane, 4-edge
// unroll -> 64B/lane in flight + 4 independent gather chains per wave.
// Edge records packed int2 (idx, bitcast weight).

__global__ void agg128_k(const _Float16* __restrict__ h, const float* __restrict__ invdeg,
                         const int* __restrict__ row_start, const int* __restrict__ cnt,
                         const int2* __restrict__ epk,
                         const float* __restrict__ bias, _Float16* __restrict__ out, int n) {
    const int grp = threadIdx.x >> 4;           // 0..15 node-groups per block
    const int l = threadIdx.x & 15;
    const int i = blockIdx.x * 16 + grp;
    if (i >= n) return;
    const int st = row_start[i], en = st + cnt[i];
    const float id = invdeg[i];
    const int c = l * 8;

    float a[8];
    {
        f16x8 hv = *(const f16x8*)(h + (size_t)i * 128 + c);
        #pragma unroll
        for (int j = 0; j < 8; ++j)
            a[j] = fmaf(id, (float)hv[j], bias[c + j]);
    }
    int p = st;
    for (; p + 3 < en; p += 4) {
        int2 e0 = epk[p], e1 = epk[p + 1], e2 = epk[p + 2], e3 = epk[p + 3];
        f16x8 v0 = *(const f16x8*)(h + (size_t)e0.x * 128 + c);
        f16x8 v1 = *(const f16x8*)(h + (size_t)e1.x * 128 + c);
        f16x8 v2 = *(const f16x8*)(h + (size_t)e2.x * 128 + c);
        f16x8 v3 = *(const f16x8*)(h + (size_t)e3.x * 128 + c);
        float w0 = __int_as_float(e0.y), w1 = __int_as_float(e1.y);
        float w2 = __int_as_float(e2.y), w3 = __int_as_float(e3.y);
        #pragma unroll
        for (int j = 0; j < 8; ++j) {
            a[j] = fmaf(w0, (float)v0[j], a[j]);
            a[j] = fmaf(w1, (float)v1[j], a[j]);
            a[j] = fmaf(w2, (float)v2[j], a[j]);
            a[j] = fmaf(w3, (float)v3[j], a[j]);
        }
    }
    for (; p < en; ++p) {
        int2 e0 = epk[p];
        float w0 = __int_as_float(e0.y);
        f16x8 v0 = *(const f16x8*)(h + (size_t)e0.x * 128 + c);
        #pragma unroll
        for (int j = 0; j < 8; ++j)
            a[j] = fmaf(w0, (float)v0[j], a[j]);
    }
    f16x8 o;
    #pragma unroll
    for (int j = 0; j < 8; ++j) o[j] = (_Float16)a[j];
    *(f16x8*)(out + (size_t)i * 128 + c) = o;
}

// ---------------- BN stats over f16 activations (12.8 MB read) ----------------

__global__ void stats16_k(const _Float16* __restrict__ a, float* __restrict__ gsum,
                          float* __restrict__ gsq, int total8) {
    const int tid = threadIdx.x;
    float s[8] = {}, q[8] = {};
    for (int idx = blockIdx.x * 256 + tid; idx < total8; idx += gridDim.x * 256) {
        f16x8 v = *(const f16x8*)(a + (size_t)idx * 8);
        #pragma unroll
        for (int j = 0; j < 8; ++j) {
            float f = (float)v[j];
            s[j] += f;
            q[j] = fmaf(f, f, q[j]);
        }
    }
    __shared__ float red[2][16][16][8];     // [sum/sq][k-group][col-group][col]
    const int g = tid & 15, k = tid >> 4;
    #pragma unroll
    for (int j = 0; j < 8; ++j) {
        red[0][k][g][j] = s[j];
        red[1][k][g][j] = q[j];
    }
    __syncthreads();
    if (tid < 128) {
        const int g2 = tid & 15, j2 = tid >> 4;     // j2 in 0..7
        float ts = 0.f, tq = 0.f;
        #pragma unroll
        for (int k2 = 0; k2 < 16; ++k2) {
            ts += red[0][k2][g2][j2];
            tq += red[1][k2][g2][j2];
        }
        atomicAdd(&gsum[g2 * 8 + j2], ts);
        atomicAdd(&gsq[g2 * 8 + j2], tq);
    }
}

// ---- classifier agg (64 cols) + log_softmax; 4 nodes per wave ----
// 16 lanes per node, f16x4 per lane; shfl_xor d<=8 stays in the 16-lane group.

__global__ void aggsm_k(const _Float16* __restrict__ h, const float* __restrict__ invdeg,
                        const int* __restrict__ row_start, const int* __restrict__ cnt,
                        const int2* __restrict__ epk,
                        const float* __restrict__ bias, float* __restrict__ out, int n) {
    const int grp = threadIdx.x >> 4;
    const int l = threadIdx.x & 15;
    const int i = blockIdx.x * 16 + grp;
    if (i >= n) return;
    const int st = row_start[i], en = st + cnt[i];
    const float id = invdeg[i];
    const int c = l * 4;

    float a[4];
    {
        f16x4 hv = *(const f16x4*)(h + (size_t)i * 64 + c);
        #pragma unroll
        for (int j = 0; j < 4; ++j)
            a[j] = fmaf(id, (float)hv[j], bias[c + j]);
    }
    int p = st;
    for (; p + 3 < en; p += 4) {
        int2 e0 = epk[p], e1 = epk[p + 1], e2 = epk[p + 2], e3 = epk[p + 3];
        f16x4 v0 = *(const f16x4*)(h + (size_t)e0.x * 64 + c);
        f16x4 v1 = *(const f16x4*)(h + (size_t)e1.x * 64 + c);
        f16x4 v2 = *(const f16x4*)(h + (size_t)e2.x * 64 + c);
        f16x4 v3 = *(const f16x4*)(h + (size_t)e3.x * 64 + c);
        float w0 = __int_as_float(e0.y), w1 = __int_as_float(e1.y);
        float w2 = __int_as_float(e2.y), w3 = __int_as_float(e3.y);
        #pragma unroll
        for (int j = 0; j < 4; ++j) {
            a[j] = fmaf(w0, (float)v0[j], a[j]);
            a[j] = fmaf(w1, (float)v1[j], a[j]);
            a[j] = fmaf(w2, (float)v2[j], a[j]);
            a[j] = fmaf(w3, (float)v3[j], a[j]);
        }
    }
    for (; p < en; ++p) {
        int2 e0 = epk[p];
        float w0 = __int_as_float(e0.y);
        f16x4 v0 = *(const f16x4*)(h + (size_t)e0.x * 64 + c);
        #pragma unroll
        for (int j = 0; j < 4; ++j)
            a[j] = fmaf(w0, (float)v0[j], a[j]);
    }

    // fused log_softmax over 64 cols held by this 16-lane group
    float m = fmaxf(fmaxf(a[0], a[1]), fmaxf(a[2], a[3]));
    #pragma unroll
    for (int d = 8; d >= 1; d >>= 1) m = fmaxf(m, __shfl_xor(m, d, 64));
    float e0 = __expf(a[0] - m), e1 = __expf(a[1] - m);
    float e2 = __expf(a[2] - m), e3 = __expf(a[3] - m);
    float s = (e0 + e1) + (e2 + e3);
    #pragma unroll
    for (int d = 8; d >= 1; d >>= 1) s += __shfl_xor(s, d, 64);
    float ls = __logf(s);
    float4 o = make_float4(a[0] - m - ls, a[1] - m - ls,
                           a[2] - m - ls, a[3] - m - ls);
    *(float4*)(out + (size_t)i * 64 + c) = o;
}

// ---------------------------------------------------------------------------

extern "C" void kernel_launch(void* const* d_in, const int* in_sizes, int n_in,
                              void* d_out, int out_size, void* d_ws, size_t ws_size,
                              hipStream_t stream) {
    const float* x  = (const float*)d_in[0];
    const int*   ei = (const int*)d_in[1];
    const float* W0 = (const float*)d_in[2];
    const float* b0 = (const float*)d_in[3];
    const float* W1 = (const float*)d_in[4];
    const float* b1 = (const float*)d_in[5];
    const float* W2 = (const float*)d_in[6];
    const float* b2 = (const float*)d_in[7];

    const int IN = 500;
    const int n = in_sizes[0] / IN;      // 50000
    const int E = in_sizes[1] / 2;       // 640000
    const int* src = ei;
    const int* dst = ei + E;

    // ---- workspace bump allocator (256B aligned) ----
    char* p = (char*)d_ws;
    auto alloc = [&](size_t bytes) -> void* {
        char* r = p;
        p += (bytes + 255) & ~(size_t)255;
        return (void*)r;
    };
    _Float16*  hb1h    = (_Float16*)alloc((size_t)n * 128 * 2);  // GEMM out / agg in
    _Float16*  hb2a    = (_Float16*)alloc((size_t)n * 128 * 2);  // agg out (pre-BN f16)
    _Float16*  W0h     = (_Float16*)alloc((size_t)128 * 512 * 2);
    _Float16*  W1h     = (_Float16*)alloc((size_t)128 * 128 * 2);
    _Float16*  W2h     = (_Float16*)alloc((size_t)64 * 128 * 2);
    // deg_cnt + BN stat buffers allocated contiguously -> single memset
    int*   deg_cnt  = (int*)alloc((size_t)n * 4);
    float* gsum0    = (float*)alloc(128 * 4);
    float* gsq0     = (float*)alloc(128 * 4);
    float* gsum1    = (float*)alloc(128 * 4);
    float* gsq1     = (float*)alloc(128 * 4);
    char*  zero_end = p;
    float* dinv     = (float*)alloc((size_t)n * 4);
    float* invdeg   = (float*)alloc((size_t)n * 4);
    int*   row_st   = (int*)alloc((size_t)n * 4);
    int*   cursor   = (int*)alloc((size_t)n * 4);
    int*   within   = (int*)alloc((size_t)n * 4);
    int*   btot     = (int*)alloc(256 * 4);
    int2*  epk      = (int2*)alloc((size_t)E * 8);
    (void)ws_size; (void)n_in; (void)out_size;

    float* out = (float*)d_out;
    const float inv_n = 1.0f / (float)n;

    const int gE = (E + 255) / 256;
    const int gN = (n + 255) / 256;
    const int nblk = (n + 511) / 512;
    const int gM = (n + 63) / 64;        // 782 blocks
    const int gA = (n + 15) / 16;        // 3125 blocks (4 nodes/wave aggs)

    // ---- graph prep + weight conversion (once per call) ----
    hipMemsetAsync(deg_cnt, 0, (size_t)(zero_end - (char*)deg_cnt), stream);
    count_k<<<gE, 256, 0, stream>>>(src, dst, deg_cnt, E);
    scan1_k<<<nblk, 512, 0, stream>>>(deg_cnt, within, btot, n);
    scan3_k<<<gN, 256, 0, stream>>>(within, btot, deg_cnt, row_st, cursor,
                                    dinv, invdeg, n);
    fill_k<<<gE, 256, 0, stream>>>(src, dst, dinv, cursor, epk, E);
    wcvt3_k<<<(22528 + 255) / 256, 256, 0, stream>>>(W0, W0h, W1, W1h, W2, W2h);

    // ---- layer 0 (x read as f32 directly; f16 convert fused into staging) ----
    mgemm_k<128, false, true><<<gM, 256, 0, stream>>>(x, W0h, hb1h,
                                                      nullptr, nullptr, 0.f,
                                                      n, 500, 512);
    agg128_k<<<gA, 256, 0, stream>>>(hb1h, invdeg, row_st, deg_cnt, epk, b0, hb2a, n);
    stats16_k<<<256, 256, 0, stream>>>(hb2a, gsum0, gsq0, n * 16);

    // ---- layer 1 (BN0+ReLU fused into GEMM1's A path) ----
    mgemm_k<128, true, false><<<gM, 256, 0, stream>>>(hb2a, W1h, hb1h,
                                                      gsum0, gsq0, inv_n,
                                                      n, 128, 128);
    agg128_k<<<gA, 256, 0, stream>>>(hb1h, invdeg, row_st, deg_cnt, epk, b1, hb2a, n);
    stats16_k<<<256, 256, 0, stream>>>(hb2a, gsum1, gsq1, n * 16);

    // ---- classifier (BN1+ReLU fused into GEMM2; log_softmax fused into agg) ----
    mgemm_k<64, true, false><<<gM, 256, 0, stream>>>(hb2a, W2h, hb1h,
                                                     gsum1, gsq1, inv_n,
                                                     n, 128, 128);
    aggsm_k<<<gA, 256, 0, stream>>>(hb1h, invdeg, row_st, deg_cnt, epk, b2, out, n);
}

// Round 15
// 228.502 us; speedup vs baseline: 2.8328x; 1.0234x over previous
//
#include <hip/hip_runtime.h>
#include <hip/hip_bf16.h>
#include <math.h>

// ---------------------------------------------------------------------------
// PMLP_GCN forward:  3x (GEMM -> GCN-agg[+bias]) with BN+ReLU between,
// log_softmax at the end.  N=50000 E=640000 IN=500 HID=128 OUT=64, f32.
// R14: agg edge-record SOFTWARE PIPELINE (prefetch next 4 epk records before
//      issuing current gathers -> hides the epk->gather serial latency);
//      wcvt3 merged into count_k's launch (88 extra independent blocks).
// ---------------------------------------------------------------------------

#define EPS_BN 1e-5f

typedef __attribute__((ext_vector_type(8))) _Float16 f16x8;
typedef __attribute__((ext_vector_type(4))) _Float16 f16x4;
typedef __attribute__((ext_vector_type(2))) _Float16 f16x2;
typedef __attribute__((ext_vector_type(4))) float    f32x4;

__device__ __forceinline__ void gload16(const void* g, void* l) {
    __builtin_amdgcn_global_load_lds(
        (const __attribute__((address_space(1))) void*)g,
        (__attribute__((address_space(3))) void*)l, 16, 0, 0);
}

// ---------------- graph prep ----------------

// blocks [0,gE): edge counting.  blocks [gE, gE+88): W0/W1/W2 f32->f16
// conversion (independent work piggybacked to save a dispatch).
__global__ void countw_k(const int* __restrict__ src, const int* __restrict__ dst,
                         int* __restrict__ cnt, int E, int gE,
                         const float* __restrict__ W0, _Float16* __restrict__ W0h,
                         const float* __restrict__ W1, _Float16* __restrict__ W1h,
                         const float* __restrict__ W2, _Float16* __restrict__ W2h) {
    if (blockIdx.x < (unsigned)gE) {
        int e = blockIdx.x * 256 + threadIdx.x;
        if (e >= E) return;
        int s = src[e], d = dst[e];
        if (s != d) atomicAdd(&cnt[d], 1);
        return;
    }
    int idx = (blockIdx.x - gE) * 256 + threadIdx.x;   // 0..22527
    if (idx < 16384) {
        int r = idx >> 7, k4 = (idx & 127) * 4;
        f16x4 h = {(_Float16)0.f, (_Float16)0.f, (_Float16)0.f, (_Float16)0.f};
        if (k4 < 500) {
            float4 v = *(const float4*)(W0 + (size_t)r * 500 + k4);
            h[0] = (_Float16)v.x; h[1] = (_Float16)v.y;
            h[2] = (_Float16)v.z; h[3] = (_Float16)v.w;
        }
        *(f16x4*)(W0h + (size_t)r * 512 + k4) = h;
    } else if (idx < 16384 + 4096) {
        int t = idx - 16384;
        float4 v = *(const float4*)(W1 + (size_t)t * 4);
        f16x4 h;
        h[0] = (_Float16)v.x; h[1] = (_Float16)v.y;
        h[2] = (_Float16)v.z; h[3] = (_Float16)v.w;
        *(f16x4*)(W1h + (size_t)t * 4) = h;
    } else if (idx < 22528) {
        int t = idx - 20480;
        float4 v = *(const float4*)(W2 + (size_t)t * 4);
        f16x4 h;
        h[0] = (_Float16)v.x; h[1] = (_Float16)v.y;
        h[2] = (_Float16)v.z; h[3] = (_Float16)v.w;
        *(f16x4*)(W2h + (size_t)t * 4) = h;
    }
}

// block-level exclusive prefix scan over cnt[n] (512-windows)
__global__ void scan1_k(const int* __restrict__ cnt, int* __restrict__ within,
                        int* __restrict__ btot, int n) {
    __shared__ int s[512];
    int tid = threadIdx.x;
    int i = blockIdx.x * 512 + tid;
    int val = (i < n) ? cnt[i] : 0;
    s[tid] = val;
    __syncthreads();
    for (int off = 1; off < 512; off <<= 1) {
        int v = (tid >= off) ? s[tid - off] : 0;
        __syncthreads();
        s[tid] += v;
        __syncthreads();
    }
    if (i < n) within[i] = s[tid] - val;   // exclusive
    if (tid == 511) btot[blockIdx.x] = s[511];
}

// merged: window-offset reduce + row_start/cursor + degree transforms
__global__ void scan3_k(const int* __restrict__ within, const int* __restrict__ btot,
                        const int* __restrict__ cnt, int* __restrict__ row_start,
                        int* __restrict__ cursor, float* __restrict__ dinv,
                        float* __restrict__ invdeg, int n) {
    __shared__ int sred[256];
    const int tid = threadIdx.x;
    const int w = (blockIdx.x * 256) >> 9;          // 512-window index (<= 97)
    sred[tid] = (tid < w) ? btot[tid] : 0;
    __syncthreads();
    #pragma unroll
    for (int off = 128; off >= 1; off >>= 1) {
        if (tid < off) sred[tid] += sred[tid + off];
        __syncthreads();
    }
    const int base = sred[0];
    int i = blockIdx.x * 256 + tid;
    if (i < n) {
        int rs = within[i] + base;
        row_start[i] = rs;
        cursor[i]    = rs;
        float deg = (float)cnt[i] + 1.0f;           // +1 for added self loop
        dinv[i]   = rsqrtf(deg);
        invdeg[i] = 1.0f / deg;
    }
}

// packed edge record: .x = src node, .y = bitcast f32 weight
__global__ void fill_k(const int* __restrict__ src, const int* __restrict__ dst,
                       const float* __restrict__ dinv, int* __restrict__ cursor,
                       int2* __restrict__ epk, int E) {
    int e = blockIdx.x * 256 + threadIdx.x;
    if (e >= E) return;
    int s = src[e], d = dst[e];
    if (s == d) return;
    int pos = atomicAdd(&cursor[d], 1);
    epk[pos] = make_int2(s, __float_as_int(dinv[s] * dinv[d]));
}

// ---------------- MFMA GEMM: C[M,NC] = BN?(A)[M,K] * Wh[NC,Kp]^T ------------
// (unchanged from R12/R13 — see comments there)

template <int NC, bool BN, bool AF32>
__global__ __launch_bounds__(256) void mgemm_k(const void* __restrict__ Av,
                                               const _Float16* __restrict__ Wh,
                                               _Float16* __restrict__ C,
                                               const float* __restrict__ gsum,
                                               const float* __restrict__ gsq,
                                               float inv_n, int M, int K, int Kp) {
    constexpr int CT = NC / 16;            // col frags per wave
    constexpr int WJ = NC / 32;            // W gload insts per wave
    __shared__ __align__(16) _Float16 As[2][64 * 64];
    __shared__ __align__(16) _Float16 Ws[2][NC * 64];
    __shared__ __align__(16) float ssc[128], ssh[128];

    const int tid  = threadIdx.x;
    const int lane = tid & 63, wave = tid >> 6;
    const int lrow = lane & 15, kg = lane >> 4;
    const int row0 = blockIdx.x * 64;

    f32x4 acc[CT] = {};
    float4 aw[4];                           // depth-1 A prefetch (AF32 path)

    const float*    Af = (const float*)Av;
    const _Float16* Ah = (const _Float16*)Av;

    auto stage = [&](int c0, int b) {
        const int k0 = c0 * 64;
        if constexpr (!AF32) {
            #pragma unroll
            for (int j = 0; j < 2; ++j) {
                int li  = wave * 128 + j * 64 + lane;      // 0..511
                int row = li >> 3, s = li & 7;
                int gr  = row0 + row;
                int gs  = s ^ (row & 7);
                if (gr < M)
                    gload16(Ah + (size_t)gr * Kp + k0 + gs * 8,
                            (char*)&As[b][0] + (wave * 128 + j * 64) * 16);
            }
        }
        #pragma unroll
        for (int j = 0; j < WJ; ++j) {
            int li  = wave * (WJ * 64) + j * 64 + lane;
            int row = li >> 3, s = li & 7;
            int gs  = s ^ (row & 7);
            gload16(Wh + (size_t)row * Kp + k0 + gs * 8,
                    (char*)&Ws[b][0] + (wave * WJ + j) * 1024);
        }
    };

    auto load_a = [&](int c0) {
        const int k0 = c0 * 64;
        #pragma unroll
        for (int it = 0; it < 4; ++it) {
            int idx = tid + it * 256;
            int row = idx >> 4, slot = idx & 15;
            int gr = row0 + row, gk = k0 + slot * 4;
            aw[it] = make_float4(0.f, 0.f, 0.f, 0.f);
            if (gr < M && gk < K)                      // K%4==0 -> all-or-none
                aw[it] = *(const float4*)(Af + (size_t)gr * K + gk);
        }
    };
    auto store_a = [&](int b) {
        #pragma unroll
        for (int it = 0; it < 4; ++it) {
            int idx = tid + it * 256;
            int row = idx >> 4, slot = idx & 15;
            f16x4 h;
            h[0] = (_Float16)aw[it].x; h[1] = (_Float16)aw[it].y;
            h[2] = (_Float16)aw[it].z; h[3] = (_Float16)aw[it].w;
            int cb = (slot * 8) ^ ((row & 7) << 4);
            *(f16x4*)((char*)&As[b][0] + row * 128 + cb) = h;
        }
    };

    auto compute = [&](int b, int kofs) {
        const char* AsB = (const char*)&As[b][0];
        const char* WsB = (const char*)&Ws[b][0];
        #pragma unroll
        for (int ks = 0; ks < 2; ++ks) {
            const int cbase = ks * 64 + kg * 16;       // byte offset in row
            f16x8 af, bf[CT];
            {
                int row = wave * 16 + lrow;
                af = *(const f16x8*)(AsB + row * 128 + (cbase ^ ((row & 7) << 4)));
            }
            if constexpr (BN) {
                const int kb = kofs + ks * 32 + kg * 8;
                f32x4 sc0 = *(const f32x4*)&ssc[kb];
                f32x4 sc1 = *(const f32x4*)&ssc[kb + 4];
                f32x4 sh0 = *(const f32x4*)&ssh[kb];
                f32x4 sh1 = *(const f32x4*)&ssh[kb + 4];
                f16x8 a2;
                #pragma unroll
                for (int j = 0; j < 4; ++j) {
                    a2[j]     = (_Float16)fmaxf(0.f, fmaf((float)af[j],     sc0[j], sh0[j]));
                    a2[j + 4] = (_Float16)fmaxf(0.f, fmaf((float)af[j + 4], sc1[j], sh1[j]));
                }
                af = a2;
            }
            #pragma unroll
            for (int ct = 0; ct < CT; ++ct) {
                int row = ct * 16 + lrow;
                bf[ct] = *(const f16x8*)(WsB + row * 128 + (cbase ^ ((row & 7) << 4)));
            }
            #pragma unroll
            for (int ct = 0; ct < CT; ++ct)
                acc[ct] = __builtin_amdgcn_mfma_f32_16x16x32_f16(
                    af, bf[ct], acc[ct], 0, 0, 0);
        }
    };

    if constexpr (BN) {
        if (tid < 128) {                   // Kp == 128 on the BN path
            float mean = gsum[tid] * inv_n;
            float var  = gsq[tid] * inv_n - mean * mean;
            float sc   = rsqrtf(var + EPS_BN);
            ssc[tid] = sc;
            ssh[tid] = -mean * sc;
        }
    }

    const int nchunk = Kp >> 6;            // Kp % 64 == 0
    if constexpr (AF32) { load_a(0); }
    stage(0, 0);
    if constexpr (AF32) { store_a(0); }
    asm volatile("s_waitcnt vmcnt(0) lgkmcnt(0)" ::: "memory");
    __builtin_amdgcn_s_barrier();
    __builtin_amdgcn_sched_barrier(0);

    for (int c = 0; c < nchunk; ++c) {
        const int b = c & 1;
        const bool more = (c + 1 < nchunk);
        if (more) {
            stage(c + 1, b ^ 1);
            if constexpr (AF32) load_a(c + 1);
        }
        compute(b, c * 64);
        if (more) {
            if constexpr (AF32) store_a(b ^ 1);
            asm volatile("s_waitcnt vmcnt(0) lgkmcnt(0)" ::: "memory");
            __builtin_amdgcn_s_barrier();
            __builtin_amdgcn_sched_barrier(0);
        }
    }

    // ---- epilogue: D lane map col=lane&15, row=(lane>>4)*4+r ----
    #pragma unroll
    for (int r = 0; r < 4; ++r) {
        int grow = row0 + wave * 16 + kg * 4 + r;
        if (grow >= M) continue;
        #pragma unroll
        for (int ct = 0; ct < CT; ++ct)
            C[(size_t)grow * NC + ct * 16 + lrow] = (_Float16)acc[ct][r];
    }
}

// ---------------- GCN aggregation (gather over CSR, f16 in/out) ----------------
// out[i] = sum_{e: dst=i} w_e * h[src_e] + invdeg[i]*h[i] + bias
// 4 nodes/wave (16 lanes x f16x8 per node). SOFTWARE-PIPELINED edge records:
// the next 4 epk records are loaded BEFORE issuing the current 4 gathers, so
// gather addresses are always already in registers (no epk->gather serial
// wait); eA=eB moves are SSA-renamed (free).

__global__ void agg128_k(const _Float16* __restrict__ h, const float* __restrict__ invdeg,
                         const int* __restrict__ row_start, const int* __restrict__ cnt,
                         const int2* __restrict__ epk,
                         const float* __restrict__ bias, _Float16* __restrict__ out, int n) {
    const int grp = threadIdx.x >> 4;           // 0..15 node-groups per block
    const int l = threadIdx.x & 15;
    const int i = blockIdx.x * 16 + grp;
    if (i >= n) return;
    const int st = row_start[i], en = st + cnt[i];
    const float id = invdeg[i];
    const int c = l * 8;

    float a[8];
    {
        f16x8 hv = *(const f16x8*)(h + (size_t)i * 128 + c);
        #pragma unroll
        for (int j = 0; j < 8; ++j)
            a[j] = fmaf(id, (float)hv[j], bias[c + j]);
    }

    auto gfma = [&](int2 e0, int2 e1, int2 e2, int2 e3) {
        f16x8 v0 = *(const f16x8*)(h + (size_t)e0.x * 128 + c);
        f16x8 v1 = *(const f16x8*)(h + (size_t)e1.x * 128 + c);
        f16x8 v2 = *(const f16x8*)(h + (size_t)e2.x * 128 + c);
        f16x8 v3 = *(const f16x8*)(h + (size_t)e3.x * 128 + c);
        float w0 = __int_as_float(e0.y), w1 = __int_as_float(e1.y);
        float w2 = __int_as_float(e2.y), w3 = __int_as_float(e3.y);
        #pragma unroll
        for (int j = 0; j < 8; ++j) {
            a[j] = fmaf(w0, (float)v0[j], a[j]);
            a[j] = fmaf(w1, (float)v1[j], a[j]);
            a[j] = fmaf(w2, (float)v2[j], a[j]);
            a[j] = fmaf(w3, (float)v3[j], a[j]);
        }
    };

    int p = st;
    if (p + 3 < en) {
        int2 eA0 = epk[p], eA1 = epk[p + 1], eA2 = epk[p + 2], eA3 = epk[p + 3];
        while (p + 7 < en) {
            int2 eB0 = epk[p + 4], eB1 = epk[p + 5];
            int2 eB2 = epk[p + 6], eB3 = epk[p + 7];
            gfma(eA0, eA1, eA2, eA3);
            eA0 = eB0; eA1 = eB1; eA2 = eB2; eA3 = eB3;
            p += 4;
        }
        gfma(eA0, eA1, eA2, eA3);
        p += 4;
    }
    for (; p < en; ++p) {
        int2 e0 = epk[p];
        float w0 = __int_as_float(e0.y);
        f16x8 v0 = *(const f16x8*)(h + (size_t)e0.x * 128 + c);
        #pragma unroll
        for (int j = 0; j < 8; ++j)
            a[j] = fmaf(w0, (float)v0[j], a[j]);
    }
    f16x8 o;
    #pragma unroll
    for (int j = 0; j < 8; ++j) o[j] = (_Float16)a[j];
    *(f16x8*)(out + (size_t)i * 128 + c) = o;
}

// ---------------- BN stats over f16 activations (12.8 MB read) ----------------

__global__ void stats16_k(const _Float16* __restrict__ a, float* __restrict__ gsum,
                          float* __restrict__ gsq, int total8) {
    const int tid = threadIdx.x;
    float s[8] = {}, q[8] = {};
    for (int idx = blockIdx.x * 256 + tid; idx < total8; idx += gridDim.x * 256) {
        f16x8 v = *(const f16x8*)(a + (size_t)idx * 8);
        #pragma unroll
        for (int j = 0; j < 8; ++j) {
            float f = (float)v[j];
            s[j] += f;
            q[j] = fmaf(f, f, q[j]);
        }
    }
    __shared__ float red[2][16][16][8];     // [sum/sq][k-group][col-group][col]
    const int g = tid & 15, k = tid >> 4;
    #pragma unroll
    for (int j = 0; j < 8; ++j) {
        red[0][k][g][j] = s[j];
        red[1][k][g][j] = q[j];
    }
    __syncthreads();
    if (tid < 128) {
        const int g2 = tid & 15, j2 = tid >> 4;     // j2 in 0..7
        float ts = 0.f, tq = 0.f;
        #pragma unroll
        for (int k2 = 0; k2 < 16; ++k2) {
            ts += red[0][k2][g2][j2];
            tq += red[1][k2][g2][j2];
        }
        atomicAdd(&gsum[g2 * 8 + j2], ts);
        atomicAdd(&gsq[g2 * 8 + j2], tq);
    }
}

// ---- classifier agg (64 cols) + log_softmax; 4 nodes/wave, pipelined ----

__global__ void aggsm_k(const _Float16* __restrict__ h, const float* __restrict__ invdeg,
                        const int* __restrict__ row_start, const int* __restrict__ cnt,
                        const int2* __restrict__ epk,
                        const float* __restrict__ bias, float* __restrict__ out, int n) {
    const int grp = threadIdx.x >> 4;
    const int l = threadIdx.x & 15;
    const int i = blockIdx.x * 16 + grp;
    if (i >= n) return;
    const int st = row_start[i], en = st + cnt[i];
    const float id = invdeg[i];
    const int c = l * 4;

    float a[4];
    {
        f16x4 hv = *(const f16x4*)(h + (size_t)i * 64 + c);
        #pragma unroll
        for (int j = 0; j < 4; ++j)
            a[j] = fmaf(id, (float)hv[j], bias[c + j]);
    }

    auto gfma = [&](int2 e0, int2 e1, int2 e2, int2 e3) {
        f16x4 v0 = *(const f16x4*)(h + (size_t)e0.x * 64 + c);
        f16x4 v1 = *(const f16x4*)(h + (size_t)e1.x * 64 + c);
        f16x4 v2 = *(const f16x4*)(h + (size_t)e2.x * 64 + c);
        f16x4 v3 = *(const f16x4*)(h + (size_t)e3.x * 64 + c);
        float w0 = __int_as_float(e0.y), w1 = __int_as_float(e1.y);
        float w2 = __int_as_float(e2.y), w3 = __int_as_float(e3.y);
        #pragma unroll
        for (int j = 0; j < 4; ++j) {
            a[j] = fmaf(w0, (float)v0[j], a[j]);
            a[j] = fmaf(w1, (float)v1[j], a[j]);
            a[j] = fmaf(w2, (float)v2[j], a[j]);
            a[j] = fmaf(w3, (float)v3[j], a[j]);
        }
    };

    int p = st;
    if (p + 3 < en) {
        int2 eA0 = epk[p], eA1 = epk[p + 1], eA2 = epk[p + 2], eA3 = epk[p + 3];
        while (p + 7 < en) {
            int2 eB0 = epk[p + 4], eB1 = epk[p + 5];
            int2 eB2 = epk[p + 6], eB3 = epk[p + 7];
            gfma(eA0, eA1, eA2, eA3);
            eA0 = eB0; eA1 = eB1; eA2 = eB2; eA3 = eB3;
            p += 4;
        }
        gfma(eA0, eA1, eA2, eA3);
        p += 4;
    }
    for (; p < en; ++p) {
        int2 e0 = epk[p];
        float w0 = __int_as_float(e0.y);
        f16x4 v0 = *(const f16x4*)(h + (size_t)e0.x * 64 + c);
        #pragma unroll
        for (int j = 0; j < 4; ++j)
            a[j] = fmaf(w0, (float)v0[j], a[j]);
    }

    // fused log_softmax over 64 cols held by this 16-lane group
    float m = fmaxf(fmaxf(a[0], a[1]), fmaxf(a[2], a[3]));
    #pragma unroll
    for (int d = 8; d >= 1; d >>= 1) m = fmaxf(m, __shfl_xor(m, d, 64));
    float e0 = __expf(a[0] - m), e1 = __expf(a[1] - m);
    float e2 = __expf(a[2] - m), e3 = __expf(a[3] - m);
    float s = (e0 + e1) + (e2 + e3);
    #pragma unroll
    for (int d = 8; d >= 1; d >>= 1) s += __shfl_xor(s, d, 64);
    float ls = __logf(s);
    float4 o = make_float4(a[0] - m - ls, a[1] - m - ls,
                           a[2] - m - ls, a[3] - m - ls);
    *(float4*)(out + (size_t)i * 64 + c) = o;
}

// ---------------------------------------------------------------------------

extern "C" void kernel_launch(void* const* d_in, const int* in_sizes, int n_in,
                              void* d_out, int out_size, void* d_ws, size_t ws_size,
                              hipStream_t stream) {
    const float* x  = (const float*)d_in[0];
    const int*   ei = (const int*)d_in[1];
    const float* W0 = (const float*)d_in[2];
    const float* b0 = (const float*)d_in[3];
    const float* W1 = (const float*)d_in[4];
    const float* b1 = (const float*)d_in[5];
    const float* W2 = (const float*)d_in[6];
    const float* b2 = (const float*)d_in[7];

    const int IN = 500;
    const int n = in_sizes[0] / IN;      // 50000
    const int E = in_sizes[1] / 2;       // 640000
    const int* src = ei;
    const int* dst = ei + E;

    // ---- workspace bump allocator (256B aligned) ----
    char* p = (char*)d_ws;
    auto alloc = [&](size_t bytes) -> void* {
        char* r = p;
        p += (bytes + 255) & ~(size_t)255;
        return (void*)r;
    };
    _Float16*  hb1h    = (_Float16*)alloc((size_t)n * 128 * 2);  // GEMM out / agg in
    _Float16*  hb2a    = (_Float16*)alloc((size_t)n * 128 * 2);  // agg out (pre-BN f16)
    _Float16*  W0h     = (_Float16*)alloc((size_t)128 * 512 * 2);
    _Float16*  W1h     = (_Float16*)alloc((size_t)128 * 128 * 2);
    _Float16*  W2h     = (_Float16*)alloc((size_t)64 * 128 * 2);
    // deg_cnt + BN stat buffers allocated contiguously -> single memset
    int*   deg_cnt  = (int*)alloc((size_t)n * 4);
    float* gsum0    = (float*)alloc(128 * 4);
    float* gsq0     = (float*)alloc(128 * 4);
    float* gsum1    = (float*)alloc(128 * 4);
    float* gsq1     = (float*)alloc(128 * 4);
    char*  zero_end = p;
    float* dinv     = (float*)alloc((size_t)n * 4);
    float* invdeg   = (float*)alloc((size_t)n * 4);
    int*   row_st   = (int*)alloc((size_t)n * 4);
    int*   cursor   = (int*)alloc((size_t)n * 4);
    int*   within   = (int*)alloc((size_t)n * 4);
    int*   btot     = (int*)alloc(256 * 4);
    int2*  epk      = (int2*)alloc((size_t)E * 8);
    (void)ws_size; (void)n_in; (void)out_size;

    float* out = (float*)d_out;
    const float inv_n = 1.0f / (float)n;

    const int gE = (E + 255) / 256;      // 2500
    const int gN = (n + 255) / 256;
    const int nblk = (n + 511) / 512;
    const int gM = (n + 63) / 64;        // 782 blocks
    const int gA = (n + 15) / 16;        // 3125 blocks (4 nodes/wave aggs)

    // ---- graph prep + weight conversion (once per call) ----
    hipMemsetAsync(deg_cnt, 0, (size_t)(zero_end - (char*)deg_cnt), stream);
    countw_k<<<gE + 88, 256, 0, stream>>>(src, dst, deg_cnt, E, gE,
                                          W0, W0h, W1, W1h, W2, W2h);
    scan1_k<<<nblk, 512, 0, stream>>>(deg_cnt, within, btot, n);
    scan3_k<<<gN, 256, 0, stream>>>(within, btot, deg_cnt, row_st, cursor,
                                    dinv, invdeg, n);
    fill_k<<<gE, 256, 0, stream>>>(src, dst, dinv, cursor, epk, E);

    // ---- layer 0 (x read as f32 directly; f16 convert fused into staging) ----
    mgemm_k<128, false, true><<<gM, 256, 0, stream>>>(x, W0h, hb1h,
                                                      nullptr, nullptr, 0.f,
                                                      n, 500, 512);
    agg128_k<<<gA, 256, 0, stream>>>(hb1h, invdeg, row_st, deg_cnt, epk, b0, hb2a, n);
    stats16_k<<<256, 256, 0, stream>>>(hb2a, gsum0, gsq0, n * 16);

    // ---- layer 1 (BN0+ReLU fused into GEMM1's A path) ----
    mgemm_k<128, true, false><<<gM, 256, 0, stream>>>(hb2a, W1h, hb1h,
                                                      gsum0, gsq0, inv_n,
                                                      n, 128, 128);
    agg128_k<<<gA, 256, 0, stream>>>(hb1h, invdeg, row_st, deg_cnt, epk, b1, hb2a, n);
    stats16_k<<<256, 256, 0, stream>>>(hb2a, gsum1, gsq1, n * 16);

    // ---- classifier (BN1+ReLU fused into GEMM2; log_softmax fused into agg) ----
    mgemm_k<64, true, false><<<gM, 256, 0, stream>>>(hb2a, W2h, hb1h,
                                                     gsum1, gsq1, inv_n,
                                                     n, 128, 128);
    aggsm_k<<<gA, 256, 0, stream>>>(hb1h, invdeg, row_st, deg_cnt, epk, b2, out, n);
}

// Round 16
// 214.557 us; speedup vs baseline: 3.0169x; 1.0650x over previous
//
#include <hip/hip_runtime.h>
#include <hip/hip_bf16.h>
#include <math.h>

// ---------------------------------------------------------------------------
// PMLP_GCN forward:  3x (GEMM -> GCN-agg[+bias]) with BN+ReLU between,
// log_softmax at the end.  N=50000 E=640000 IN=500 HID=128 OUT=64, f32.
// R15: fill_k merged into mgemm0's launch (independent work, overlapped);
//      aggsm 8 nodes/wave (8 lanes x f16x8 = full 64-col row, 8 chains/wave).
// ---------------------------------------------------------------------------

#define EPS_BN 1e-5f

typedef __attribute__((ext_vector_type(8))) _Float16 f16x8;
typedef __attribute__((ext_vector_type(4))) _Float16 f16x4;
typedef __attribute__((ext_vector_type(2))) _Float16 f16x2;
typedef __attribute__((ext_vector_type(4))) float    f32x4;

__device__ __forceinline__ void gload16(const void* g, void* l) {
    __builtin_amdgcn_global_load_lds(
        (const __attribute__((address_space(1))) void*)g,
        (__attribute__((address_space(3))) void*)l, 16, 0, 0);
}

// ---------------- graph prep ----------------

// blocks [0,gE): edge counting.  blocks [gE, gE+88): W0/W1/W2 f32->f16.
__global__ void countw_k(const int* __restrict__ src, const int* __restrict__ dst,
                         int* __restrict__ cnt, int E, int gE,
                         const float* __restrict__ W0, _Float16* __restrict__ W0h,
                         const float* __restrict__ W1, _Float16* __restrict__ W1h,
                         const float* __restrict__ W2, _Float16* __restrict__ W2h) {
    if (blockIdx.x < (unsigned)gE) {
        int e = blockIdx.x * 256 + threadIdx.x;
        if (e >= E) return;
        int s = src[e], d = dst[e];
        if (s != d) atomicAdd(&cnt[d], 1);
        return;
    }
    int idx = (blockIdx.x - gE) * 256 + threadIdx.x;   // 0..22527
    if (idx < 16384) {
        int r = idx >> 7, k4 = (idx & 127) * 4;
        f16x4 h = {(_Float16)0.f, (_Float16)0.f, (_Float16)0.f, (_Float16)0.f};
        if (k4 < 500) {
            float4 v = *(const float4*)(W0 + (size_t)r * 500 + k4);
            h[0] = (_Float16)v.x; h[1] = (_Float16)v.y;
            h[2] = (_Float16)v.z; h[3] = (_Float16)v.w;
        }
        *(f16x4*)(W0h + (size_t)r * 512 + k4) = h;
    } else if (idx < 16384 + 4096) {
        int t = idx - 16384;
        float4 v = *(const float4*)(W1 + (size_t)t * 4);
        f16x4 h;
        h[0] = (_Float16)v.x; h[1] = (_Float16)v.y;
        h[2] = (_Float16)v.z; h[3] = (_Float16)v.w;
        *(f16x4*)(W1h + (size_t)t * 4) = h;
    } else if (idx < 22528) {
        int t = idx - 20480;
        float4 v = *(const float4*)(W2 + (size_t)t * 4);
        f16x4 h;
        h[0] = (_Float16)v.x; h[1] = (_Float16)v.y;
        h[2] = (_Float16)v.z; h[3] = (_Float16)v.w;
        *(f16x4*)(W2h + (size_t)t * 4) = h;
    }
}

// block-level exclusive prefix scan over cnt[n] (512-windows)
__global__ void scan1_k(const int* __restrict__ cnt, int* __restrict__ within,
                        int* __restrict__ btot, int n) {
    __shared__ int s[512];
    int tid = threadIdx.x;
    int i = blockIdx.x * 512 + tid;
    int val = (i < n) ? cnt[i] : 0;
    s[tid] = val;
    __syncthreads();
    for (int off = 1; off < 512; off <<= 1) {
        int v = (tid >= off) ? s[tid - off] : 0;
        __syncthreads();
        s[tid] += v;
        __syncthreads();
    }
    if (i < n) within[i] = s[tid] - val;   // exclusive
    if (tid == 511) btot[blockIdx.x] = s[511];
}

// merged: window-offset reduce + row_start/cursor + degree transforms
__global__ void scan3_k(const int* __restrict__ within, const int* __restrict__ btot,
                        const int* __restrict__ cnt, int* __restrict__ row_start,
                        int* __restrict__ cursor, float* __restrict__ dinv,
                        float* __restrict__ invdeg, int n) {
    __shared__ int sred[256];
    const int tid = threadIdx.x;
    const int w = (blockIdx.x * 256) >> 9;          // 512-window index (<= 97)
    sred[tid] = (tid < w) ? btot[tid] : 0;
    __syncthreads();
    #pragma unroll
    for (int off = 128; off >= 1; off >>= 1) {
        if (tid < off) sred[tid] += sred[tid + off];
        __syncthreads();
    }
    const int base = sred[0];
    int i = blockIdx.x * 256 + tid;
    if (i < n) {
        int rs = within[i] + base;
        row_start[i] = rs;
        cursor[i]    = rs;
        float deg = (float)cnt[i] + 1.0f;           // +1 for added self loop
        dinv[i]   = rsqrtf(deg);
        invdeg[i] = 1.0f / deg;
    }
}

// ---------------- MFMA GEMM: C[M,NC] = BN?(A)[M,K] * Wh[NC,Kp]^T ------------
// (structure unchanged from R12/R13.)  FILL=true additionally runs the CSR
// fill (packed int2 edge records) in blocks >= gM — independent work that
// overlaps with the GEMM instead of a separate serial dispatch.

template <int NC, bool BN, bool AF32, bool FILL>
__global__ __launch_bounds__(256) void mgemm_k(const void* __restrict__ Av,
                                               const _Float16* __restrict__ Wh,
                                               _Float16* __restrict__ C,
                                               const float* __restrict__ gsum,
                                               const float* __restrict__ gsq,
                                               float inv_n, int M, int K, int Kp,
                                               const int* __restrict__ src,
                                               const int* __restrict__ dst,
                                               const float* __restrict__ dinv,
                                               int* __restrict__ cursor,
                                               int2* __restrict__ epk,
                                               int E, int gM) {
    constexpr int CT = NC / 16;            // col frags per wave
    constexpr int WJ = NC / 32;            // W gload insts per wave
    __shared__ __align__(16) _Float16 As[2][64 * 64];
    __shared__ __align__(16) _Float16 Ws[2][NC * 64];
    __shared__ __align__(16) float ssc[128], ssh[128];

    if constexpr (FILL) {
        if ((int)blockIdx.x >= gM) {       // fill path: no LDS, no barriers
            int e = (blockIdx.x - gM) * 256 + threadIdx.x;
            if (e < E) {
                int s = src[e], d = dst[e];
                if (s != d) {
                    int pos = atomicAdd(&cursor[d], 1);
                    epk[pos] = make_int2(s, __float_as_int(dinv[s] * dinv[d]));
                }
            }
            return;
        }
    }

    const int tid  = threadIdx.x;
    const int lane = tid & 63, wave = tid >> 6;
    const int lrow = lane & 15, kg = lane >> 4;
    const int row0 = blockIdx.x * 64;

    f32x4 acc[CT] = {};
    float4 aw[4];                           // depth-1 A prefetch (AF32 path)

    const float*    Af = (const float*)Av;
    const _Float16* Ah = (const _Float16*)Av;

    auto stage = [&](int c0, int b) {
        const int k0 = c0 * 64;
        if constexpr (!AF32) {
            #pragma unroll
            for (int j = 0; j < 2; ++j) {
                int li  = wave * 128 + j * 64 + lane;      // 0..511
                int row = li >> 3, s = li & 7;
                int gr  = row0 + row;
                int gs  = s ^ (row & 7);
                if (gr < M)
                    gload16(Ah + (size_t)gr * Kp + k0 + gs * 8,
                            (char*)&As[b][0] + (wave * 128 + j * 64) * 16);
            }
        }
        #pragma unroll
        for (int j = 0; j < WJ; ++j) {
            int li  = wave * (WJ * 64) + j * 64 + lane;
            int row = li >> 3, s = li & 7;
            int gs  = s ^ (row & 7);
            gload16(Wh + (size_t)row * Kp + k0 + gs * 8,
                    (char*)&Ws[b][0] + (wave * WJ + j) * 1024);
        }
    };

    auto load_a = [&](int c0) {
        const int k0 = c0 * 64;
        #pragma unroll
        for (int it = 0; it < 4; ++it) {
            int idx = tid + it * 256;
            int row = idx >> 4, slot = idx & 15;
            int gr = row0 + row, gk = k0 + slot * 4;
            aw[it] = make_float4(0.f, 0.f, 0.f, 0.f);
            if (gr < M && gk < K)                      // K%4==0 -> all-or-none
                aw[it] = *(const float4*)(Af + (size_t)gr * K + gk);
        }
    };
    auto store_a = [&](int b) {
        #pragma unroll
        for (int it = 0; it < 4; ++it) {
            int idx = tid + it * 256;
            int row = idx >> 4, slot = idx & 15;
            f16x4 h;
            h[0] = (_Float16)aw[it].x; h[1] = (_Float16)aw[it].y;
            h[2] = (_Float16)aw[it].z; h[3] = (_Float16)aw[it].w;
            int cb = (slot * 8) ^ ((row & 7) << 4);
            *(f16x4*)((char*)&As[b][0] + row * 128 + cb) = h;
        }
    };

    auto compute = [&](int b, int kofs) {
        const char* AsB = (const char*)&As[b][0];
        const char* WsB = (const char*)&Ws[b][0];
        #pragma unroll
        for (int ks = 0; ks < 2; ++ks) {
            const int cbase = ks * 64 + kg * 16;       // byte offset in row
            f16x8 af, bf[CT];
            {
                int row = wave * 16 + lrow;
                af = *(const f16x8*)(AsB + row * 128 + (cbase ^ ((row & 7) << 4)));
            }
            if constexpr (BN) {
                const int kb = kofs + ks * 32 + kg * 8;
                f32x4 sc0 = *(const f32x4*)&ssc[kb];
                f32x4 sc1 = *(const f32x4*)&ssc[kb + 4];
                f32x4 sh0 = *(const f32x4*)&ssh[kb];
                f32x4 sh1 = *(const f32x4*)&ssh[kb + 4];
                f16x8 a2;
                #pragma unroll
                for (int j = 0; j < 4; ++j) {
                    a2[j]     = (_Float16)fmaxf(0.f, fmaf((float)af[j],     sc0[j], sh0[j]));
                    a2[j + 4] = (_Float16)fmaxf(0.f, fmaf((float)af[j + 4], sc1[j], sh1[j]));
                }
                af = a2;
            }
            #pragma unroll
            for (int ct = 0; ct < CT; ++ct) {
                int row = ct * 16 + lrow;
                bf[ct] = *(const f16x8*)(WsB + row * 128 + (cbase ^ ((row & 7) << 4)));
            }
            #pragma unroll
            for (int ct = 0; ct < CT; ++ct)
                acc[ct] = __builtin_amdgcn_mfma_f32_16x16x32_f16(
                    af, bf[ct], acc[ct], 0, 0, 0);
        }
    };

    if constexpr (BN) {
        if (tid < 128) {                   // Kp == 128 on the BN path
            float mean = gsum[tid] * inv_n;
            float var  = gsq[tid] * inv_n - mean * mean;
            float sc   = rsqrtf(var + EPS_BN);
            ssc[tid] = sc;
            ssh[tid] = -mean * sc;
        }
    }

    const int nchunk = Kp >> 6;            // Kp % 64 == 0
    if constexpr (AF32) { load_a(0); }
    stage(0, 0);
    if constexpr (AF32) { store_a(0); }
    asm volatile("s_waitcnt vmcnt(0) lgkmcnt(0)" ::: "memory");
    __builtin_amdgcn_s_barrier();
    __builtin_amdgcn_sched_barrier(0);

    for (int c = 0; c < nchunk; ++c) {
        const int b = c & 1;
        const bool more = (c + 1 < nchunk);
        if (more) {
            stage(c + 1, b ^ 1);
            if constexpr (AF32) load_a(c + 1);
        }
        compute(b, c * 64);
        if (more) {
            if constexpr (AF32) store_a(b ^ 1);
            asm volatile("s_waitcnt vmcnt(0) lgkmcnt(0)" ::: "memory");
            __builtin_amdgcn_s_barrier();
            __builtin_amdgcn_sched_barrier(0);
        }
    }

    // ---- epilogue: D lane map col=lane&15, row=(lane>>4)*4+r ----
    #pragma unroll
    for (int r = 0; r < 4; ++r) {
        int grow = row0 + wave * 16 + kg * 4 + r;
        if (grow >= M) continue;
        #pragma unroll
        for (int ct = 0; ct < CT; ++ct)
            C[(size_t)grow * NC + ct * 16 + lrow] = (_Float16)acc[ct][r];
    }
}

// ---------------- GCN aggregation (gather over CSR, f16 in/out) ----------------
// 4 nodes/wave (16 lanes x f16x8), software-pipelined edge records (R14).

__global__ void agg128_k(const _Float16* __restrict__ h, const float* __restrict__ invdeg,
                         const int* __restrict__ row_start, const int* __restrict__ cnt,
                         const int2* __restrict__ epk,
                         const float* __restrict__ bias, _Float16* __restrict__ out, int n) {
    const int grp = threadIdx.x >> 4;           // 0..15 node-groups per block
    const int l = threadIdx.x & 15;
    const int i = blockIdx.x * 16 + grp;
    if (i >= n) return;
    const int st = row_start[i], en = st + cnt[i];
    const float id = invdeg[i];
    const int c = l * 8;

    float a[8];
    {
        f16x8 hv = *(const f16x8*)(h + (size_t)i * 128 + c);
        #pragma unroll
        for (int j = 0; j < 8; ++j)
            a[j] = fmaf(id, (float)hv[j], bias[c + j]);
    }

    auto gfma = [&](int2 e0, int2 e1, int2 e2, int2 e3) {
        f16x8 v0 = *(const f16x8*)(h + (size_t)e0.x * 128 + c);
        f16x8 v1 = *(const f16x8*)(h + (size_t)e1.x * 128 + c);
        f16x8 v2 = *(const f16x8*)(h + (size_t)e2.x * 128 + c);
        f16x8 v3 = *(const f16x8*)(h + (size_t)e3.x * 128 + c);
        float w0 = __int_as_float(e0.y), w1 = __int_as_float(e1.y);
        float w2 = __int_as_float(e2.y), w3 = __int_as_float(e3.y);
        #pragma unroll
        for (int j = 0; j < 8; ++j) {
            a[j] = fmaf(w0, (float)v0[j], a[j]);
            a[j] = fmaf(w1, (float)v1[j], a[j]);
            a[j] = fmaf(w2, (float)v2[j], a[j]);
            a[j] = fmaf(w3, (float)v3[j], a[j]);
        }
    };

    int p = st;
    if (p + 3 < en) {
        int2 eA0 = epk[p], eA1 = epk[p + 1], eA2 = epk[p + 2], eA3 = epk[p + 3];
        while (p + 7 < en) {
            int2 eB0 = epk[p + 4], eB1 = epk[p + 5];
            int2 eB2 = epk[p + 6], eB3 = epk[p + 7];
            gfma(eA0, eA1, eA2, eA3);
            eA0 = eB0; eA1 = eB1; eA2 = eB2; eA3 = eB3;
            p += 4;
        }
        gfma(eA0, eA1, eA2, eA3);
        p += 4;
    }
    for (; p < en; ++p) {
        int2 e0 = epk[p];
        float w0 = __int_as_float(e0.y);
        f16x8 v0 = *(const f16x8*)(h + (size_t)e0.x * 128 + c);
        #pragma unroll
        for (int j = 0; j < 8; ++j)
            a[j] = fmaf(w0, (float)v0[j], a[j]);
    }
    f16x8 o;
    #pragma unroll
    for (int j = 0; j < 8; ++j) o[j] = (_Float16)a[j];
    *(f16x8*)(out + (size_t)i * 128 + c) = o;
}

// ---------------- BN stats over f16 activations (12.8 MB read) ----------------

__global__ void stats16_k(const _Float16* __restrict__ a, float* __restrict__ gsum,
                          float* __restrict__ gsq, int total8) {
    const int tid = threadIdx.x;
    float s[8] = {}, q[8] = {};
    for (int idx = blockIdx.x * 256 + tid; idx < total8; idx += gridDim.x * 256) {
        f16x8 v = *(const f16x8*)(a + (size_t)idx * 8);
        #pragma unroll
        for (int j = 0; j < 8; ++j) {
            float f = (float)v[j];
            s[j] += f;
            q[j] = fmaf(f, f, q[j]);
        }
    }
    __shared__ float red[2][16][16][8];     // [sum/sq][k-group][col-group][col]
    const int g = tid & 15, k = tid >> 4;
    #pragma unroll
    for (int j = 0; j < 8; ++j) {
        red[0][k][g][j] = s[j];
        red[1][k][g][j] = q[j];
    }
    __syncthreads();
    if (tid < 128) {
        const int g2 = tid & 15, j2 = tid >> 4;     // j2 in 0..7
        float ts = 0.f, tq = 0.f;
        #pragma unroll
        for (int k2 = 0; k2 < 16; ++k2) {
            ts += red[0][k2][g2][j2];
            tq += red[1][k2][g2][j2];
        }
        atomicAdd(&gsum[g2 * 8 + j2], ts);
        atomicAdd(&gsq[g2 * 8 + j2], tq);
    }
}

// ---- classifier agg (64 cols) + log_softmax; 8 nodes/wave, pipelined ----
// 8 lanes per node, f16x8 per lane (full row); shfl_xor d<=4 stays in-group.

__global__ void aggsm_k(const _Float16* __restrict__ h, const float* __restrict__ invdeg,
                        const int* __restrict__ row_start, const int* __restrict__ cnt,
                        const int2* __restrict__ epk,
                        const float* __restrict__ bias, float* __restrict__ out, int n) {
    const int grp = threadIdx.x >> 3;           // 0..31 node-groups per block
    const int l = threadIdx.x & 7;
    const int i = blockIdx.x * 32 + grp;
    if (i >= n) return;
    const int st = row_start[i], en = st + cnt[i];
    const float id = invdeg[i];
    const int c = l * 8;

    float a[8];
    {
        f16x8 hv = *(const f16x8*)(h + (size_t)i * 64 + c);
        #pragma unroll
        for (int j = 0; j < 8; ++j)
            a[j] = fmaf(id, (float)hv[j], bias[c + j]);
    }

    auto gfma = [&](int2 e0, int2 e1, int2 e2, int2 e3) {
        f16x8 v0 = *(const f16x8*)(h + (size_t)e0.x * 64 + c);
        f16x8 v1 = *(const f16x8*)(h + (size_t)e1.x * 64 + c);
        f16x8 v2 = *(const f16x8*)(h + (size_t)e2.x * 64 + c);
        f16x8 v3 = *(const f16x8*)(h + (size_t)e3.x * 64 + c);
        float w0 = __int_as_float(e0.y), w1 = __int_as_float(e1.y);
        float w2 = __int_as_float(e2.y), w3 = __int_as_float(e3.y);
        #pragma unroll
        for (int j = 0; j < 8; ++j) {
            a[j] = fmaf(w0, (float)v0[j], a[j]);
            a[j] = fmaf(w1, (float)v1[j], a[j]);
            a[j] = fmaf(w2, (float)v2[j], a[j]);
            a[j] = fmaf(w3, (float)v3[j], a[j]);
        }
    };

    int p = st;
    if (p + 3 < en) {
        int2 eA0 = epk[p], eA1 = epk[p + 1], eA2 = epk[p + 2], eA3 = epk[p + 3];
        while (p + 7 < en) {
            int2 eB0 = epk[p + 4], eB1 = epk[p + 5];
            int2 eB2 = epk[p + 6], eB3 = epk[p + 7];
            gfma(eA0, eA1, eA2, eA3);
            eA0 = eB0; eA1 = eB1; eA2 = eB2; eA3 = eB3;
            p += 4;
        }
        gfma(eA0, eA1, eA2, eA3);
        p += 4;
    }
    for (; p < en; ++p) {
        int2 e0 = epk[p];
        float w0 = __int_as_float(e0.y);
        f16x8 v0 = *(const f16x8*)(h + (size_t)e0.x * 64 + c);
        #pragma unroll
        for (int j = 0; j < 8; ++j)
            a[j] = fmaf(w0, (float)v0[j], a[j]);
    }

    // fused log_softmax over 64 cols held by this 8-lane group
    float m = a[0];
    #pragma unroll
    for (int j = 1; j < 8; ++j) m = fmaxf(m, a[j]);
    #pragma unroll
    for (int d = 4; d >= 1; d >>= 1) m = fmaxf(m, __shfl_xor(m, d, 64));
    float s = 0.f;
    float e[8];
    #pragma unroll
    for (int j = 0; j < 8; ++j) { e[j] = __expf(a[j] - m); s += e[j]; }
    #pragma unroll
    for (int d = 4; d >= 1; d >>= 1) s += __shfl_xor(s, d, 64);
    float ls = __logf(s);
    float4 o0 = make_float4(a[0] - m - ls, a[1] - m - ls,
                            a[2] - m - ls, a[3] - m - ls);
    float4 o1 = make_float4(a[4] - m - ls, a[5] - m - ls,
                            a[6] - m - ls, a[7] - m - ls);
    *(float4*)(out + (size_t)i * 64 + c)     = o0;
    *(float4*)(out + (size_t)i * 64 + c + 4) = o1;
}

// ---------------------------------------------------------------------------

extern "C" void kernel_launch(void* const* d_in, const int* in_sizes, int n_in,
                              void* d_out, int out_size, void* d_ws, size_t ws_size,
                              hipStream_t stream) {
    const float* x  = (const float*)d_in[0];
    const int*   ei = (const int*)d_in[1];
    const float* W0 = (const float*)d_in[2];
    const float* b0 = (const float*)d_in[3];
    const float* W1 = (const float*)d_in[4];
    const float* b1 = (const float*)d_in[5];
    const float* W2 = (const float*)d_in[6];
    const float* b2 = (const float*)d_in[7];

    const int IN = 500;
    const int n = in_sizes[0] / IN;      // 50000
    const int E = in_sizes[1] / 2;       // 640000
    const int* src = ei;
    const int* dst = ei + E;

    // ---- workspace bump allocator (256B aligned) ----
    char* p = (char*)d_ws;
    auto alloc = [&](size_t bytes) -> void* {
        char* r = p;
        p += (bytes + 255) & ~(size_t)255;
        return (void*)r;
    };
    _Float16*  hb1h    = (_Float16*)alloc((size_t)n * 128 * 2);  // GEMM out / agg in
    _Float16*  hb2a    = (_Float16*)alloc((size_t)n * 128 * 2);  // agg out (pre-BN f16)
    _Float16*  W0h     = (_Float16*)alloc((size_t)128 * 512 * 2);
    _Float16*  W1h     = (_Float16*)alloc((size_t)128 * 128 * 2);
    _Float16*  W2h     = (_Float16*)alloc((size_t)64 * 128 * 2);
    // deg_cnt + BN stat buffers allocated contiguously -> single memset
    int*   deg_cnt  = (int*)alloc((size_t)n * 4);
    float* gsum0    = (float*)alloc(128 * 4);
    float* gsq0     = (float*)alloc(128 * 4);
    float* gsum1    = (float*)alloc(128 * 4);
    float* gsq1     = (float*)alloc(128 * 4);
    char*  zero_end = p;
    float* dinv     = (float*)alloc((size_t)n * 4);
    float* invdeg   = (float*)alloc((size_t)n * 4);
    int*   row_st   = (int*)alloc((size_t)n * 4);
    int*   cursor   = (int*)alloc((size_t)n * 4);
    int*   within   = (int*)alloc((size_t)n * 4);
    int*   btot     = (int*)alloc(256 * 4);
    int2*  epk      = (int2*)alloc((size_t)E * 8);
    (void)ws_size; (void)n_in; (void)out_size;

    float* out = (float*)d_out;
    const float inv_n = 1.0f / (float)n;

    const int gE = (E + 255) / 256;      // 2500
    const int gN = (n + 255) / 256;
    const int nblk = (n + 511) / 512;
    const int gM = (n + 63) / 64;        // 782 blocks
    const int gA = (n + 15) / 16;        // 3125 blocks (agg128)
    const int gS = (n + 31) / 32;        // 1563 blocks (aggsm, 8 nodes/wave)

    // ---- graph prep + weight conversion (once per call) ----
    hipMemsetAsync(deg_cnt, 0, (size_t)(zero_end - (char*)deg_cnt), stream);
    countw_k<<<gE + 88, 256, 0, stream>>>(src, dst, deg_cnt, E, gE,
                                          W0, W0h, W1, W1h, W2, W2h);
    scan1_k<<<nblk, 512, 0, stream>>>(deg_cnt, within, btot, n);
    scan3_k<<<gN, 256, 0, stream>>>(within, btot, deg_cnt, row_st, cursor,
                                    dinv, invdeg, n);

    // ---- layer 0: GEMM0 + CSR fill in ONE launch (independent work) ----
    mgemm_k<128, false, true, true><<<gM + gE, 256, 0, stream>>>(
        x, W0h, hb1h, nullptr, nullptr, 0.f, n, 500, 512,
        src, dst, dinv, cursor, epk, E, gM);
    agg128_k<<<gA, 256, 0, stream>>>(hb1h, invdeg, row_st, deg_cnt, epk, b0, hb2a, n);
    stats16_k<<<256, 256, 0, stream>>>(hb2a, gsum0, gsq0, n * 16);

    // ---- layer 1 (BN0+ReLU fused into GEMM1's A path) ----
    mgemm_k<128, true, false, false><<<gM, 256, 0, stream>>>(
        hb2a, W1h, hb1h, gsum0, gsq0, inv_n, n, 128, 128,
        nullptr, nullptr, nullptr, nullptr, nullptr, 0, gM);
    agg128_k<<<gA, 256, 0, stream>>>(hb1h, invdeg, row_st, deg_cnt, epk, b1, hb2a, n);
    stats16_k<<<256, 256, 0, stream>>>(hb2a, gsum1, gsq1, n * 16);

    // ---- classifier (BN1+ReLU fused into GEMM2; log_softmax fused into agg) ----
    mgemm_k<64, true, false, false><<<gM, 256, 0, stream>>>(
        hb2a, W2h, hb1h, gsum1, gsq1, inv_n, n, 128, 128,
        nullptr, nullptr, nullptr, nullptr, nullptr, 0, gM);
    aggsm_k<<<gS, 256, 0, stream>>>(hb1h, invdeg, row_st, deg_cnt, epk, b2, out, n);
}

// Round 17
// 212.982 us; speedup vs baseline: 3.0392x; 1.0074x over previous
//
#include <hip/hip_runtime.h>
#include <hip/hip_bf16.h>
#include <math.h>

// ---------------------------------------------------------------------------
// PMLP_GCN forward:  3x (GEMM -> GCN-agg[+bias]) with BN+ReLU between,
// log_softmax at the end.  N=50000 E=640000 IN=500 HID=128 OUT=64, f32.
// R16: mgemm0 (AF32) A-path depth-2 register prefetch: named reg sets,
//      unrolled-by-2 loop, counted s_waitcnt vmcnt(4) so A(c+2) stays in
//      flight across the barrier (only W's gload_lds drains). A loads are
//      guard-free (clamped addr + select-zero) so vmcnt counts are uniform.
// ---------------------------------------------------------------------------

#define EPS_BN 1e-5f

typedef __attribute__((ext_vector_type(8))) _Float16 f16x8;
typedef __attribute__((ext_vector_type(4))) _Float16 f16x4;
typedef __attribute__((ext_vector_type(2))) _Float16 f16x2;
typedef __attribute__((ext_vector_type(4))) float    f32x4;

__device__ __forceinline__ void gload16(const void* g, void* l) {
    __builtin_amdgcn_global_load_lds(
        (const __attribute__((address_space(1))) void*)g,
        (__attribute__((address_space(3))) void*)l, 16, 0, 0);
}

// ---------------- graph prep ----------------

// blocks [0,gE): edge counting.  blocks [gE, gE+88): W0/W1/W2 f32->f16.
__global__ void countw_k(const int* __restrict__ src, const int* __restrict__ dst,
                         int* __restrict__ cnt, int E, int gE,
                         const float* __restrict__ W0, _Float16* __restrict__ W0h,
                         const float* __restrict__ W1, _Float16* __restrict__ W1h,
                         const float* __restrict__ W2, _Float16* __restrict__ W2h) {
    if (blockIdx.x < (unsigned)gE) {
        int e = blockIdx.x * 256 + threadIdx.x;
        if (e >= E) return;
        int s = src[e], d = dst[e];
        if (s != d) atomicAdd(&cnt[d], 1);
        return;
    }
    int idx = (blockIdx.x - gE) * 256 + threadIdx.x;   // 0..22527
    if (idx < 16384) {
        int r = idx >> 7, k4 = (idx & 127) * 4;
        f16x4 h = {(_Float16)0.f, (_Float16)0.f, (_Float16)0.f, (_Float16)0.f};
        if (k4 < 500) {
            float4 v = *(const float4*)(W0 + (size_t)r * 500 + k4);
            h[0] = (_Float16)v.x; h[1] = (_Float16)v.y;
            h[2] = (_Float16)v.z; h[3] = (_Float16)v.w;
        }
        *(f16x4*)(W0h + (size_t)r * 512 + k4) = h;
    } else if (idx < 16384 + 4096) {
        int t = idx - 16384;
        float4 v = *(const float4*)(W1 + (size_t)t * 4);
        f16x4 h;
        h[0] = (_Float16)v.x; h[1] = (_Float16)v.y;
        h[2] = (_Float16)v.z; h[3] = (_Float16)v.w;
        *(f16x4*)(W1h + (size_t)t * 4) = h;
    } else if (idx < 22528) {
        int t = idx - 20480;
        float4 v = *(const float4*)(W2 + (size_t)t * 4);
        f16x4 h;
        h[0] = (_Float16)v.x; h[1] = (_Float16)v.y;
        h[2] = (_Float16)v.z; h[3] = (_Float16)v.w;
        *(f16x4*)(W2h + (size_t)t * 4) = h;
    }
}

// block-level exclusive prefix scan over cnt[n] (512-windows)
__global__ void scan1_k(const int* __restrict__ cnt, int* __restrict__ within,
                        int* __restrict__ btot, int n) {
    __shared__ int s[512];
    int tid = threadIdx.x;
    int i = blockIdx.x * 512 + tid;
    int val = (i < n) ? cnt[i] : 0;
    s[tid] = val;
    __syncthreads();
    for (int off = 1; off < 512; off <<= 1) {
        int v = (tid >= off) ? s[tid - off] : 0;
        __syncthreads();
        s[tid] += v;
        __syncthreads();
    }
    if (i < n) within[i] = s[tid] - val;   // exclusive
    if (tid == 511) btot[blockIdx.x] = s[511];
}

// merged: window-offset reduce + row_start/cursor + degree transforms
__global__ void scan3_k(const int* __restrict__ within, const int* __restrict__ btot,
                        const int* __restrict__ cnt, int* __restrict__ row_start,
                        int* __restrict__ cursor, float* __restrict__ dinv,
                        float* __restrict__ invdeg, int n) {
    __shared__ int sred[256];
    const int tid = threadIdx.x;
    const int w = (blockIdx.x * 256) >> 9;          // 512-window index (<= 97)
    sred[tid] = (tid < w) ? btot[tid] : 0;
    __syncthreads();
    #pragma unroll
    for (int off = 128; off >= 1; off >>= 1) {
        if (tid < off) sred[tid] += sred[tid + off];
        __syncthreads();
    }
    const int base = sred[0];
    int i = blockIdx.x * 256 + tid;
    if (i < n) {
        int rs = within[i] + base;
        row_start[i] = rs;
        cursor[i]    = rs;
        float deg = (float)cnt[i] + 1.0f;           // +1 for added self loop
        dinv[i]   = rsqrtf(deg);
        invdeg[i] = 1.0f / deg;
    }
}

// ---------------- MFMA GEMM: C[M,NC] = BN?(A)[M,K] * Wh[NC,Kp]^T ------------
// Wh f16 (padded Kp). f32 accumulate, f16 out. 4 waves; tile 64 x NC; chunk 64.
// !AF32: A f16 via global_load_lds (inverse-swizzled source, linear dest).
// AF32 (layer 0): A = raw f32 x; DEPTH-2 register prefetch (named sets
//   awA*/awB*, unroll-2 loop, by-value float4 -> SROA-safe), f32->f16
//   convert + swizzled ds_write; counted vmcnt(4) keeps A(c+2) in flight
//   across barriers (only W's gload_lds drains). Loads are guard-free
//   (clamped address + select-zero) so per-wave vmcnt counts are uniform.
// FILL=true: blocks >= gM run the CSR fill (independent, overlapped).
// BN=true (Kp==128): per-k scale/shift from LDS applied to the A fragment.

template <int NC, bool BN, bool AF32, bool FILL>
__global__ __launch_bounds__(256) void mgemm_k(const void* __restrict__ Av,
                                               const _Float16* __restrict__ Wh,
                                               _Float16* __restrict__ C,
                                               const float* __restrict__ gsum,
                                               const float* __restrict__ gsq,
                                               float inv_n, int M, int K, int Kp,
                                               const int* __restrict__ src,
                                               const int* __restrict__ dst,
                                               const float* __restrict__ dinv,
                                               int* __restrict__ cursor,
                                               int2* __restrict__ epk,
                                               int E, int gM) {
    constexpr int CT = NC / 16;            // col frags per wave
    constexpr int WJ = NC / 32;            // W gload insts per wave
    __shared__ __align__(16) _Float16 As[2][64 * 64];
    __shared__ __align__(16) _Float16 Ws[2][NC * 64];
    __shared__ __align__(16) float ssc[128], ssh[128];

    if constexpr (FILL) {
        if ((int)blockIdx.x >= gM) {       // fill path: no barriers used
            int e = (blockIdx.x - gM) * 256 + threadIdx.x;
            if (e < E) {
                int s = src[e], d = dst[e];
                if (s != d) {
                    int pos = atomicAdd(&cursor[d], 1);
                    epk[pos] = make_int2(s, __float_as_int(dinv[s] * dinv[d]));
                }
            }
            return;
        }
    }

    const int tid  = threadIdx.x;
    const int lane = tid & 63, wave = tid >> 6;
    const int lrow = lane & 15, kg = lane >> 4;
    const int row0 = blockIdx.x * 64;

    f32x4 acc[CT] = {};
    // depth-2 A prefetch register sets (AF32 path) — named scalars, by value
    float4 awA0, awA1, awA2, awA3;
    float4 awB0, awB1, awB2, awB3;

    const float*    Af = (const float*)Av;
    const _Float16* Ah = (const _Float16*)Av;

    auto stage = [&](int c0, int b) {
        const int k0 = c0 * 64;
        if constexpr (!AF32) {
            #pragma unroll
            for (int j = 0; j < 2; ++j) {
                int li  = wave * 128 + j * 64 + lane;      // 0..511
                int row = li >> 3, s = li & 7;
                int gr  = row0 + row;
                int gs  = s ^ (row & 7);
                if (gr < M)
                    gload16(Ah + (size_t)gr * Kp + k0 + gs * 8,
                            (char*)&As[b][0] + (wave * 128 + j * 64) * 16);
            }
        }
        #pragma unroll
        for (int j = 0; j < WJ; ++j) {
            int li  = wave * (WJ * 64) + j * 64 + lane;
            int row = li >> 3, s = li & 7;
            int gs  = s ^ (row & 7);
            gload16(Wh + (size_t)row * Kp + k0 + gs * 8,
                    (char*)&Ws[b][0] + (wave * WJ + j) * 1024);
        }
    };

    // guard-free A load: clamped address, select-zero after (uniform vmcnt)
    auto load_one = [&](int c0, int it) -> float4 {
        int idx = tid + it * 256;
        int row = idx >> 4, slot = idx & 15;
        int gr = row0 + row, gk = c0 * 64 + slot * 4;
        bool ok = (gr < M) && (gk < K);
        int grc = ok ? gr : 0;
        int gkc = ok ? gk : 0;
        float4 v = *(const float4*)(Af + (size_t)grc * K + gkc);
        if (!ok) v = make_float4(0.f, 0.f, 0.f, 0.f);
        return v;
    };
    auto load_aA = [&](int c0) {
        awA0 = load_one(c0, 0); awA1 = load_one(c0, 1);
        awA2 = load_one(c0, 2); awA3 = load_one(c0, 3);
    };
    auto load_aB = [&](int c0) {
        awB0 = load_one(c0, 0); awB1 = load_one(c0, 1);
        awB2 = load_one(c0, 2); awB3 = load_one(c0, 3);
    };
    auto store_one = [&](int b, int it, float4 v) {
        int idx = tid + it * 256;
        int row = idx >> 4, slot = idx & 15;
        f16x4 h;
        h[0] = (_Float16)v.x; h[1] = (_Float16)v.y;
        h[2] = (_Float16)v.z; h[3] = (_Float16)v.w;
        int cb = (slot * 8) ^ ((row & 7) << 4);
        *(f16x4*)((char*)&As[b][0] + row * 128 + cb) = h;
    };
    auto store_aA = [&](int b) {
        store_one(b, 0, awA0); store_one(b, 1, awA1);
        store_one(b, 2, awA2); store_one(b, 3, awA3);
    };
    auto store_aB = [&](int b) {
        store_one(b, 0, awB0); store_one(b, 1, awB1);
        store_one(b, 2, awB2); store_one(b, 3, awB3);
    };

    auto compute = [&](int b, int kofs) {
        const char* AsB = (const char*)&As[b][0];
        const char* WsB = (const char*)&Ws[b][0];
        #pragma unroll
        for (int ks = 0; ks < 2; ++ks) {
            const int cbase = ks * 64 + kg * 16;       // byte offset in row
            f16x8 af, bf[CT];
            {
                int row = wave * 16 + lrow;
                af = *(const f16x8*)(AsB + row * 128 + (cbase ^ ((row & 7) << 4)));
            }
            if constexpr (BN) {
                const int kb = kofs + ks * 32 + kg * 8;
                f32x4 sc0 = *(const f32x4*)&ssc[kb];
                f32x4 sc1 = *(const f32x4*)&ssc[kb + 4];
                f32x4 sh0 = *(const f32x4*)&ssh[kb];
                f32x4 sh1 = *(const f32x4*)&ssh[kb + 4];
                f16x8 a2;
                #pragma unroll
                for (int j = 0; j < 4; ++j) {
                    a2[j]     = (_Float16)fmaxf(0.f, fmaf((float)af[j],     sc0[j], sh0[j]));
                    a2[j + 4] = (_Float16)fmaxf(0.f, fmaf((float)af[j + 4], sc1[j], sh1[j]));
                }
                af = a2;
            }
            #pragma unroll
            for (int ct = 0; ct < CT; ++ct) {
                int row = ct * 16 + lrow;
                bf[ct] = *(const f16x8*)(WsB + row * 128 + (cbase ^ ((row & 7) << 4)));
            }
            #pragma unroll
            for (int ct = 0; ct < CT; ++ct)
                acc[ct] = __builtin_amdgcn_mfma_f32_16x16x32_f16(
                    af, bf[ct], acc[ct], 0, 0, 0);
        }
    };

    if constexpr (BN) {
        if (tid < 128) {                   // Kp == 128 on the BN path
            float mean = gsum[tid] * inv_n;
            float var  = gsq[tid] * inv_n - mean * mean;
            float sc   = rsqrtf(var + EPS_BN);
            ssc[tid] = sc;
            ssh[tid] = -mean * sc;
        }
    }

    const int nchunk = Kp >> 6;            // Kp % 64 == 0

    if constexpr (AF32) {
        // ---- depth-2 A pipeline (nchunk >= 2; Kp=512 -> 8) ----
        load_aA(0);
        stage(0, 0);                       // W(0)
        load_aB(1);
        store_aA(0);                       // compiler waits A(0) loads
        asm volatile("s_waitcnt vmcnt(4) lgkmcnt(0)" ::: "memory"); // W(0) done
        __builtin_amdgcn_s_barrier();
        __builtin_amdgcn_sched_barrier(0);

        int c = 0;
        while (true) {
            {   // even step: awB holds A(c+1)
                const int b = c & 1;
                const bool more = c + 1 < nchunk;
                const bool pf   = c + 2 < nchunk;
                if (more) stage(c + 1, b ^ 1);
                if (pf)   load_aA(c + 2);
                compute(b, 0);
                if (!more) break;
                store_aB(b ^ 1);
                if (pf) asm volatile("s_waitcnt vmcnt(4) lgkmcnt(0)" ::: "memory");
                else    asm volatile("s_waitcnt vmcnt(0) lgkmcnt(0)" ::: "memory");
                __builtin_amdgcn_s_barrier();
                __builtin_amdgcn_sched_barrier(0);
                ++c;
            }
            {   // odd step: awA holds A(c+1)
                const int b = c & 1;
                const bool more = c + 1 < nchunk;
                const bool pf   = c + 2 < nchunk;
                if (more) stage(c + 1, b ^ 1);
                if (pf)   load_aB(c + 2);
                compute(b, 0);
                if (!more) break;
                store_aA(b ^ 1);
                if (pf) asm volatile("s_waitcnt vmcnt(4) lgkmcnt(0)" ::: "memory");
                else    asm volatile("s_waitcnt vmcnt(0) lgkmcnt(0)" ::: "memory");
                __builtin_amdgcn_s_barrier();
                __builtin_amdgcn_sched_barrier(0);
                ++c;
            }
        }
    } else {
        // ---- f16-A path: gload_lds both tiles, 2-phase ----
        stage(0, 0);
        asm volatile("s_waitcnt vmcnt(0) lgkmcnt(0)" ::: "memory");
        __builtin_amdgcn_s_barrier();
        __builtin_amdgcn_sched_barrier(0);
        for (int c = 0; c < nchunk; ++c) {
            const int b = c & 1;
            const bool more = (c + 1 < nchunk);
            if (more) stage(c + 1, b ^ 1);
            compute(b, c * 64);
            if (more) {
                asm volatile("s_waitcnt vmcnt(0) lgkmcnt(0)" ::: "memory");
                __builtin_amdgcn_s_barrier();
                __builtin_amdgcn_sched_barrier(0);
            }
        }
    }

    // ---- epilogue: D lane map col=lane&15, row=(lane>>4)*4+r ----
    #pragma unroll
    for (int r = 0; r < 4; ++r) {
        int grow = row0 + wave * 16 + kg * 4 + r;
        if (grow >= M) continue;
        #pragma unroll
        for (int ct = 0; ct < CT; ++ct)
            C[(size_t)grow * NC + ct * 16 + lrow] = (_Float16)acc[ct][r];
    }
}

// ---------------- GCN aggregation (gather over CSR, f16 in/out) ----------------
// 4 nodes/wave (16 lanes x f16x8), software-pipelined edge records (R14).

__global__ void agg128_k(const _Float16* __restrict__ h, const float* __restrict__ invdeg,
                         const int* __restrict__ row_start, const int* __restrict__ cnt,
                         const int2* __restrict__ epk,
                         const float* __restrict__ bias, _Float16* __restrict__ out, int n) {
    const int grp = threadIdx.x >> 4;           // 0..15 node-groups per block
    const int l = threadIdx.x & 15;
    const int i = blockIdx.x * 16 + grp;
    if (i >= n) return;
    const int st = row_start[i], en = st + cnt[i];
    const float id = invdeg[i];
    const int c = l * 8;

    float a[8];
    {
        f16x8 hv = *(const f16x8*)(h + (size_t)i * 128 + c);
        #pragma unroll
        for (int j = 0; j < 8; ++j)
            a[j] = fmaf(id, (float)hv[j], bias[c + j]);
    }

    auto gfma = [&](int2 e0, int2 e1, int2 e2, int2 e3) {
        f16x8 v0 = *(const f16x8*)(h + (size_t)e0.x * 128 + c);
        f16x8 v1 = *(const f16x8*)(h + (size_t)e1.x * 128 + c);
        f16x8 v2 = *(const f16x8*)(h + (size_t)e2.x * 128 + c);
        f16x8 v3 = *(const f16x8*)(h + (size_t)e3.x * 128 + c);
        float w0 = __int_as_float(e0.y), w1 = __int_as_float(e1.y);
        float w2 = __int_as_float(e2.y), w3 = __int_as_float(e3.y);
        #pragma unroll
        for (int j = 0; j < 8; ++j) {
            a[j] = fmaf(w0, (float)v0[j], a[j]);
            a[j] = fmaf(w1, (float)v1[j], a[j]);
            a[j] = fmaf(w2, (float)v2[j], a[j]);
            a[j] = fmaf(w3, (float)v3[j], a[j]);
        }
    };

    int p = st;
    if (p + 3 < en) {
        int2 eA0 = epk[p], eA1 = epk[p + 1], eA2 = epk[p + 2], eA3 = epk[p + 3];
        while (p + 7 < en) {
            int2 eB0 = epk[p + 4], eB1 = epk[p + 5];
            int2 eB2 = epk[p + 6], eB3 = epk[p + 7];
            gfma(eA0, eA1, eA2, eA3);
            eA0 = eB0; eA1 = eB1; eA2 = eB2; eA3 = eB3;
            p += 4;
        }
        gfma(eA0, eA1, eA2, eA3);
        p += 4;
    }
    for (; p < en; ++p) {
        int2 e0 = epk[p];
        float w0 = __int_as_float(e0.y);
        f16x8 v0 = *(const f16x8*)(h + (size_t)e0.x * 128 + c);
        #pragma unroll
        for (int j = 0; j < 8; ++j)
            a[j] = fmaf(w0, (float)v0[j], a[j]);
    }
    f16x8 o;
    #pragma unroll
    for (int j = 0; j < 8; ++j) o[j] = (_Float16)a[j];
    *(f16x8*)(out + (size_t)i * 128 + c) = o;
}

// ---------------- BN stats over f16 activations (12.8 MB read) ----------------

__global__ void stats16_k(const _Float16* __restrict__ a, float* __restrict__ gsum,
                          float* __restrict__ gsq, int total8) {
    const int tid = threadIdx.x;
    float s[8] = {}, q[8] = {};
    for (int idx = blockIdx.x * 256 + tid; idx < total8; idx += gridDim.x * 256) {
        f16x8 v = *(const f16x8*)(a + (size_t)idx * 8);
        #pragma unroll
        for (int j = 0; j < 8; ++j) {
            float f = (float)v[j];
            s[j] += f;
            q[j] = fmaf(f, f, q[j]);
        }
    }
    __shared__ float red[2][16][16][8];     // [sum/sq][k-group][col-group][col]
    const int g = tid & 15, k = tid >> 4;
    #pragma unroll
    for (int j = 0; j < 8; ++j) {
        red[0][k][g][j] = s[j];
        red[1][k][g][j] = q[j];
    }
    __syncthreads();
    if (tid < 128) {
        const int g2 = tid & 15, j2 = tid >> 4;     // j2 in 0..7
        float ts = 0.f, tq = 0.f;
        #pragma unroll
        for (int k2 = 0; k2 < 16; ++k2) {
            ts += red[0][k2][g2][j2];
            tq += red[1][k2][g2][j2];
        }
        atomicAdd(&gsum[g2 * 8 + j2], ts);
        atomicAdd(&gsq[g2 * 8 + j2], tq);
    }
}

// ---- classifier agg (64 cols) + log_softmax; 8 nodes/wave, pipelined ----
// 8 lanes per node, f16x8 per lane (full row); shfl_xor d<=4 stays in-group.

__global__ void aggsm_k(const _Float16* __restrict__ h, const float* __restrict__ invdeg,
                        const int* __restrict__ row_start, const int* __restrict__ cnt,
                        const int2* __restrict__ epk,
                        const float* __restrict__ bias, float* __restrict__ out, int n) {
    const int grp = threadIdx.x >> 3;           // 0..31 node-groups per block
    const int l = threadIdx.x & 7;
    const int i = blockIdx.x * 32 + grp;
    if (i >= n) return;
    const int st = row_start[i], en = st + cnt[i];
    const float id = invdeg[i];
    const int c = l * 8;

    float a[8];
    {
        f16x8 hv = *(const f16x8*)(h + (size_t)i * 64 + c);
        #pragma unroll
        for (int j = 0; j < 8; ++j)
            a[j] = fmaf(id, (float)hv[j], bias[c + j]);
    }

    auto gfma = [&](int2 e0, int2 e1, int2 e2, int2 e3) {
        f16x8 v0 = *(const f16x8*)(h + (size_t)e0.x * 64 + c);
        f16x8 v1 = *(const f16x8*)(h + (size_t)e1.x * 64 + c);
        f16x8 v2 = *(const f16x8*)(h + (size_t)e2.x * 64 + c);
        f16x8 v3 = *(const f16x8*)(h + (size_t)e3.x * 64 + c);
        float w0 = __int_as_float(e0.y), w1 = __int_as_float(e1.y);
        float w2 = __int_as_float(e2.y), w3 = __int_as_float(e3.y);
        #pragma unroll
        for (int j = 0; j < 8; ++j) {
            a[j] = fmaf(w0, (float)v0[j], a[j]);
            a[j] = fmaf(w1, (float)v1[j], a[j]);
            a[j] = fmaf(w2, (float)v2[j], a[j]);
            a[j] = fmaf(w3, (float)v3[j], a[j]);
        }
    };

    int p = st;
    if (p + 3 < en) {
        int2 eA0 = epk[p], eA1 = epk[p + 1], eA2 = epk[p + 2], eA3 = epk[p + 3];
        while (p + 7 < en) {
            int2 eB0 = epk[p + 4], eB1 = epk[p + 5];
            int2 eB2 = epk[p + 6], eB3 = epk[p + 7];
            gfma(eA0, eA1, eA2, eA3);
            eA0 = eB0; eA1 = eB1; eA2 = eB2; eA3 = eB3;
            p += 4;
        }
        gfma(eA0, eA1, eA2, eA3);
        p += 4;
    }
    for (; p < en; ++p) {
        int2 e0 = epk[p];
        float w0 = __int_as_float(e0.y);
        f16x8 v0 = *(const f16x8*)(h + (size_t)e0.x * 64 + c);
        #pragma unroll
        for (int j = 0; j < 8; ++j)
            a[j] = fmaf(w0, (float)v0[j], a[j]);
    }

    // fused log_softmax over 64 cols held by this 8-lane group
    float m = a[0];
    #pragma unroll
    for (int j = 1; j < 8; ++j) m = fmaxf(m, a[j]);
    #pragma unroll
    for (int d = 4; d >= 1; d >>= 1) m = fmaxf(m, __shfl_xor(m, d, 64));
    float s = 0.f;
    float e[8];
    #pragma unroll
    for (int j = 0; j < 8; ++j) { e[j] = __expf(a[j] - m); s += e[j]; }
    #pragma unroll
    for (int d = 4; d >= 1; d >>= 1) s += __shfl_xor(s, d, 64);
    float ls = __logf(s);
    float4 o0 = make_float4(a[0] - m - ls, a[1] - m - ls,
                            a[2] - m - ls, a[3] - m - ls);
    float4 o1 = make_float4(a[4] - m - ls, a[5] - m - ls,
                            a[6] - m - ls, a[7] - m - ls);
    *(float4*)(out + (size_t)i * 64 + c)     = o0;
    *(float4*)(out + (size_t)i * 64 + c + 4) = o1;
}

// ---------------------------------------------------------------------------

extern "C" void kernel_launch(void* const* d_in, const int* in_sizes, int n_in,
                              void* d_out, int out_size, void* d_ws, size_t ws_size,
                              hipStream_t stream) {
    const float* x  = (const float*)d_in[0];
    const int*   ei = (const int*)d_in[1];
    const float* W0 = (const float*)d_in[2];
    const float* b0 = (const float*)d_in[3];
    const float* W1 = (const float*)d_in[4];
    const float* b1 = (const float*)d_in[5];
    const float* W2 = (const float*)d_in[6];
    const float* b2 = (const float*)d_in[7];

    const int IN = 500;
    const int n = in_sizes[0] / IN;      // 50000
    const int E = in_sizes[1] / 2;       // 640000
    const int* src = ei;
    const int* dst = ei + E;

    // ---- workspace bump allocator (256B aligned) ----
    char* p = (char*)d_ws;
    auto alloc = [&](size_t bytes) -> void* {
        char* r = p;
        p += (bytes + 255) & ~(size_t)255;
        return (void*)r;
    };
    _Float16*  hb1h    = (_Float16*)alloc((size_t)n * 128 * 2);  // GEMM out / agg in
    _Float16*  hb2a    = (_Float16*)alloc((size_t)n * 128 * 2);  // agg out (pre-BN f16)
    _Float16*  W0h     = (_Float16*)alloc((size_t)128 * 512 * 2);
    _Float16*  W1h     = (_Float16*)alloc((size_t)128 * 128 * 2);
    _Float16*  W2h     = (_Float16*)alloc((size_t)64 * 128 * 2);
    // deg_cnt + BN stat buffers allocated contiguously -> single memset
    int*   deg_cnt  = (int*)alloc((size_t)n * 4);
    float* gsum0    = (float*)alloc(128 * 4);
    float* gsq0     = (float*)alloc(128 * 4);
    float* gsum1    = (float*)alloc(128 * 4);
    float* gsq1     = (float*)alloc(128 * 4);
    char*  zero_end = p;
    float* dinv     = (float*)alloc((size_t)n * 4);
    float* invdeg   = (float*)alloc((size_t)n * 4);
    int*   row_st   = (int*)alloc((size_t)n * 4);
    int*   cursor   = (int*)alloc((size_t)n * 4);
    int*   within   = (int*)alloc((size_t)n * 4);
    int*   btot     = (int*)alloc(256 * 4);
    int2*  epk      = (int2*)alloc((size_t)E * 8);
    (void)ws_size; (void)n_in; (void)out_size;

    float* out = (float*)d_out;
    const float inv_n = 1.0f / (float)n;

    const int gE = (E + 255) / 256;      // 2500
    const int gN = (n + 255) / 256;
    const int nblk = (n + 511) / 512;
    const int gM = (n + 63) / 64;        // 782 blocks
    const int gA = (n + 15) / 16;        // 3125 blocks (agg128)
    const int gS = (n + 31) / 32;        // 1563 blocks (aggsm, 8 nodes/wave)

    // ---- graph prep + weight conversion (once per call) ----
    hipMemsetAsync(deg_cnt, 0, (size_t)(zero_end - (char*)deg_cnt), stream);
    countw_k<<<gE + 88, 256, 0, stream>>>(src, dst, deg_cnt, E, gE,
                                          W0, W0h, W1, W1h, W2, W2h);
    scan1_k<<<nblk, 512, 0, stream>>>(deg_cnt, within, btot, n);
    scan3_k<<<gN, 256, 0, stream>>>(within, btot, deg_cnt, row_st, cursor,
                                    dinv, invdeg, n);

    // ---- layer 0: GEMM0 + CSR fill in ONE launch (independent work) ----
    mgemm_k<128, false, true, true><<<gM + gE, 256, 0, stream>>>(
        x, W0h, hb1h, nullptr, nullptr, 0.f, n, 500, 512,
        src, dst, dinv, cursor, epk, E, gM);
    agg128_k<<<gA, 256, 0, stream>>>(hb1h, invdeg, row_st, deg_cnt, epk, b0, hb2a, n);
    stats16_k<<<256, 256, 0, stream>>>(hb2a, gsum0, gsq0, n * 16);

    // ---- layer 1 (BN0+ReLU fused into GEMM1's A path) ----
    mgemm_k<128, true, false, false><<<gM, 256, 0, stream>>>(
        hb2a, W1h, hb1h, gsum0, gsq0, inv_n, n, 128, 128,
        nullptr, nullptr, nullptr, nullptr, nullptr, 0, gM);
    agg128_k<<<gA, 256, 0, stream>>>(hb1h, invdeg, row_st, deg_cnt, epk, b1, hb2a, n);
    stats16_k<<<256, 256, 0, stream>>>(hb2a, gsum1, gsq1, n * 16);

    // ---- classifier (BN1+ReLU fused into GEMM2; log_softmax fused into agg) ----
    mgemm_k<64, true, false, false><<<gM, 256, 0, stream>>>(
        hb2a, W2h, hb1h, gsum1, gsq1, inv_n, n, 128, 128,
        nullptr, nullptr, nullptr, nullptr, nullptr, 0, gM);
    aggsm_k<<<gS, 256, 0, stream>>>(hb1h, invdeg, row_st, deg_cnt, epk, b2, out, n);
}

// Round 18
// 212.688 us; speedup vs baseline: 3.0434x; 1.0014x over previous
//
#include <hip/hip_runtime.h>
#include <hip/hip_bf16.h>
#include <math.h>

// ---------------------------------------------------------------------------
// PMLP_GCN forward:  3x (GEMM -> GCN-agg[+bias]) with BN+ReLU between,
// log_softmax at the end.  N=50000 E=640000 IN=500 HID=128 OUT=64, f32.
// R16: mgemm0 (AF32) A-path depth-2 register prefetch: named reg sets,
//      unrolled-by-2 loop, counted s_waitcnt vmcnt(4) so A(c+2) stays in
//      flight across the barrier (only W's gload_lds drains). A loads are
//      guard-free (clamped addr + select-zero) so vmcnt counts are uniform.
// ---------------------------------------------------------------------------

#define EPS_BN 1e-5f

typedef __attribute__((ext_vector_type(8))) _Float16 f16x8;
typedef __attribute__((ext_vector_type(4))) _Float16 f16x4;
typedef __attribute__((ext_vector_type(2))) _Float16 f16x2;
typedef __attribute__((ext_vector_type(4))) float    f32x4;

__device__ __forceinline__ void gload16(const void* g, void* l) {
    __builtin_amdgcn_global_load_lds(
        (const __attribute__((address_space(1))) void*)g,
        (__attribute__((address_space(3))) void*)l, 16, 0, 0);
}

// ---------------- graph prep ----------------

// blocks [0,gE): edge counting.  blocks [gE, gE+88): W0/W1/W2 f32->f16.
__global__ void countw_k(const int* __restrict__ src, const int* __restrict__ dst,
                         int* __restrict__ cnt, int E, int gE,
                         const float* __restrict__ W0, _Float16* __restrict__ W0h,
                         const float* __restrict__ W1, _Float16* __restrict__ W1h,
                         const float* __restrict__ W2, _Float16* __restrict__ W2h) {
    if (blockIdx.x < (unsigned)gE) {
        int e = blockIdx.x * 256 + threadIdx.x;
        if (e >= E) return;
        int s = src[e], d = dst[e];
        if (s != d) atomicAdd(&cnt[d], 1);
        return;
    }
    int idx = (blockIdx.x - gE) * 256 + threadIdx.x;   // 0..22527
    if (idx < 16384) {
        int r = idx >> 7, k4 = (idx & 127) * 4;
        f16x4 h = {(_Float16)0.f, (_Float16)0.f, (_Float16)0.f, (_Float16)0.f};
        if (k4 < 500) {
            float4 v = *(const float4*)(W0 + (size_t)r * 500 + k4);
            h[0] = (_Float16)v.x; h[1] = (_Float16)v.y;
            h[2] = (_Float16)v.z; h[3] = (_Float16)v.w;
        }
        *(f16x4*)(W0h + (size_t)r * 512 + k4) = h;
    } else if (idx < 16384 + 4096) {
        int t = idx - 16384;
        float4 v = *(const float4*)(W1 + (size_t)t * 4);
        f16x4 h;
        h[0] = (_Float16)v.x; h[1] = (_Float16)v.y;
        h[2] = (_Float16)v.z; h[3] = (_Float16)v.w;
        *(f16x4*)(W1h + (size_t)t * 4) = h;
    } else if (idx < 22528) {
        int t = idx - 20480;
        float4 v = *(const float4*)(W2 + (size_t)t * 4);
        f16x4 h;
        h[0] = (_Float16)v.x; h[1] = (_Float16)v.y;
        h[2] = (_Float16)v.z; h[3] = (_Float16)v.w;
        *(f16x4*)(W2h + (size_t)t * 4) = h;
    }
}

// block-level exclusive prefix scan over cnt[n] (512-windows)
__global__ void scan1_k(const int* __restrict__ cnt, int* __restrict__ within,
                        int* __restrict__ btot, int n) {
    __shared__ int s[512];
    int tid = threadIdx.x;
    int i = blockIdx.x * 512 + tid;
    int val = (i < n) ? cnt[i] : 0;
    s[tid] = val;
    __syncthreads();
    for (int off = 1; off < 512; off <<= 1) {
        int v = (tid >= off) ? s[tid - off] : 0;
        __syncthreads();
        s[tid] += v;
        __syncthreads();
    }
    if (i < n) within[i] = s[tid] - val;   // exclusive
    if (tid == 511) btot[blockIdx.x] = s[511];
}

// merged: window-offset reduce + row_start/cursor + degree transforms
__global__ void scan3_k(const int* __restrict__ within, const int* __restrict__ btot,
                        const int* __restrict__ cnt, int* __restrict__ row_start,
                        int* __restrict__ cursor, float* __restrict__ dinv,
                        float* __restrict__ invdeg, int n) {
    __shared__ int sred[256];
    const int tid = threadIdx.x;
    const int w = (blockIdx.x * 256) >> 9;          // 512-window index (<= 97)
    sred[tid] = (tid < w) ? btot[tid] : 0;
    __syncthreads();
    #pragma unroll
    for (int off = 128; off >= 1; off >>= 1) {
        if (tid < off) sred[tid] += sred[tid + off];
        __syncthreads();
    }
    const int base = sred[0];
    int i = blockIdx.x * 256 + tid;
    if (i < n) {
        int rs = within[i] + base;
        row_start[i] = rs;
        cursor[i]    = rs;
        float deg = (float)cnt[i] + 1.0f;           // +1 for added self loop
        dinv[i]   = rsqrtf(deg);
        invdeg[i] = 1.0f / deg;
    }
}

// ---------------- MFMA GEMM: C[M,NC] = BN?(A)[M,K] * Wh[NC,Kp]^T ------------
// Wh f16 (padded Kp). f32 accumulate, f16 out. 4 waves; tile 64 x NC; chunk 64.
// !AF32: A f16 via global_load_lds (inverse-swizzled source, linear dest).
// AF32 (layer 0): A = raw f32 x; DEPTH-2 register prefetch (named sets
//   awA*/awB*, unroll-2 loop, by-value float4 -> SROA-safe), f32->f16
//   convert + swizzled ds_write; counted vmcnt(4) keeps A(c+2) in flight
//   across barriers (only W's gload_lds drains). Loads are guard-free
//   (clamped address + select-zero) so per-wave vmcnt counts are uniform.
// FILL=true: blocks >= gM run the CSR fill (independent, overlapped).
// BN=true (Kp==128): per-k scale/shift from LDS applied to the A fragment.

template <int NC, bool BN, bool AF32, bool FILL>
__global__ __launch_bounds__(256) void mgemm_k(const void* __restrict__ Av,
                                               const _Float16* __restrict__ Wh,
                                               _Float16* __restrict__ C,
                                               const float* __restrict__ gsum,
                                               const float* __restrict__ gsq,
                                               float inv_n, int M, int K, int Kp,
                                               const int* __restrict__ src,
                                               const int* __restrict__ dst,
                                               const float* __restrict__ dinv,
                                               int* __restrict__ cursor,
                                               int2* __restrict__ epk,
                                               int E, int gM) {
    constexpr int CT = NC / 16;            // col frags per wave
    constexpr int WJ = NC / 32;            // W gload insts per wave
    __shared__ __align__(16) _Float16 As[2][64 * 64];
    __shared__ __align__(16) _Float16 Ws[2][NC * 64];
    __shared__ __align__(16) float ssc[128], ssh[128];

    if constexpr (FILL) {
        if ((int)blockIdx.x >= gM) {       // fill path: no barriers used
            int e = (blockIdx.x - gM) * 256 + threadIdx.x;
            if (e < E) {
                int s = src[e], d = dst[e];
                if (s != d) {
                    int pos = atomicAdd(&cursor[d], 1);
                    epk[pos] = make_int2(s, __float_as_int(dinv[s] * dinv[d]));
                }
            }
            return;
        }
    }

    const int tid  = threadIdx.x;
    const int lane = tid & 63, wave = tid >> 6;
    const int lrow = lane & 15, kg = lane >> 4;
    const int row0 = blockIdx.x * 64;

    f32x4 acc[CT] = {};
    // depth-2 A prefetch register sets (AF32 path) — named scalars, by value
    float4 awA0, awA1, awA2, awA3;
    float4 awB0, awB1, awB2, awB3;

    const float*    Af = (const float*)Av;
    const _Float16* Ah = (const _Float16*)Av;

    auto stage = [&](int c0, int b) {
        const int k0 = c0 * 64;
        if constexpr (!AF32) {
            #pragma unroll
            for (int j = 0; j < 2; ++j) {
                int li  = wave * 128 + j * 64 + lane;      // 0..511
                int row = li >> 3, s = li & 7;
                int gr  = row0 + row;
                int gs  = s ^ (row & 7);
                if (gr < M)
                    gload16(Ah + (size_t)gr * Kp + k0 + gs * 8,
                            (char*)&As[b][0] + (wave * 128 + j * 64) * 16);
            }
        }
        #pragma unroll
        for (int j = 0; j < WJ; ++j) {
            int li  = wave * (WJ * 64) + j * 64 + lane;
            int row = li >> 3, s = li & 7;
            int gs  = s ^ (row & 7);
            gload16(Wh + (size_t)row * Kp + k0 + gs * 8,
                    (char*)&Ws[b][0] + (wave * WJ + j) * 1024);
        }
    };

    // guard-free A load: clamped address, select-zero after (uniform vmcnt)
    auto load_one = [&](int c0, int it) -> float4 {
        int idx = tid + it * 256;
        int row = idx >> 4, slot = idx & 15;
        int gr = row0 + row, gk = c0 * 64 + slot * 4;
        bool ok = (gr < M) && (gk < K);
        int grc = ok ? gr : 0;
        int gkc = ok ? gk : 0;
        float4 v = *(const float4*)(Af + (size_t)grc * K + gkc);
        if (!ok) v = make_float4(0.f, 0.f, 0.f, 0.f);
        return v;
    };
    auto load_aA = [&](int c0) {
        awA0 = load_one(c0, 0); awA1 = load_one(c0, 1);
        awA2 = load_one(c0, 2); awA3 = load_one(c0, 3);
    };
    auto load_aB = [&](int c0) {
        awB0 = load_one(c0, 0); awB1 = load_one(c0, 1);
        awB2 = load_one(c0, 2); awB3 = load_one(c0, 3);
    };
    auto store_one = [&](int b, int it, float4 v) {
        int idx = tid + it * 256;
        int row = idx >> 4, slot = idx & 15;
        f16x4 h;
        h[0] = (_Float16)v.x; h[1] = (_Float16)v.y;
        h[2] = (_Float16)v.z; h[3] = (_Float16)v.w;
        int cb = (slot * 8) ^ ((row & 7) << 4);
        *(f16x4*)((char*)&As[b][0] + row * 128 + cb) = h;
    };
    auto store_aA = [&](int b) {
        store_one(b, 0, awA0); store_one(b, 1, awA1);
        store_one(b, 2, awA2); store_one(b, 3, awA3);
    };
    auto store_aB = [&](int b) {
        store_one(b, 0, awB0); store_one(b, 1, awB1);
        store_one(b, 2, awB2); store_one(b, 3, awB3);
    };

    auto compute = [&](int b, int kofs) {
        const char* AsB = (const char*)&As[b][0];
        const char* WsB = (const char*)&Ws[b][0];
        #pragma unroll
        for (int ks = 0; ks < 2; ++ks) {
            const int cbase = ks * 64 + kg * 16;       // byte offset in row
            f16x8 af, bf[CT];
            {
                int row = wave * 16 + lrow;
                af = *(const f16x8*)(AsB + row * 128 + (cbase ^ ((row & 7) << 4)));
            }
            if constexpr (BN) {
                const int kb = kofs + ks * 32 + kg * 8;
                f32x4 sc0 = *(const f32x4*)&ssc[kb];
                f32x4 sc1 = *(const f32x4*)&ssc[kb + 4];
                f32x4 sh0 = *(const f32x4*)&ssh[kb];
                f32x4 sh1 = *(const f32x4*)&ssh[kb + 4];
                f16x8 a2;
                #pragma unroll
                for (int j = 0; j < 4; ++j) {
                    a2[j]     = (_Float16)fmaxf(0.f, fmaf((float)af[j],     sc0[j], sh0[j]));
                    a2[j + 4] = (_Float16)fmaxf(0.f, fmaf((float)af[j + 4], sc1[j], sh1[j]));
                }
                af = a2;
            }
            #pragma unroll
            for (int ct = 0; ct < CT; ++ct) {
                int row = ct * 16 + lrow;
                bf[ct] = *(const f16x8*)(WsB + row * 128 + (cbase ^ ((row & 7) << 4)));
            }
            #pragma unroll
            for (int ct = 0; ct < CT; ++ct)
                acc[ct] = __builtin_amdgcn_mfma_f32_16x16x32_f16(
                    af, bf[ct], acc[ct], 0, 0, 0);
        }
    };

    if constexpr (BN) {
        if (tid < 128) {                   // Kp == 128 on the BN path
            float mean = gsum[tid] * inv_n;
            float var  = gsq[tid] * inv_n - mean * mean;
            float sc   = rsqrtf(var + EPS_BN);
            ssc[tid] = sc;
            ssh[tid] = -mean * sc;
        }
    }

    const int nchunk = Kp >> 6;            // Kp % 64 == 0

    if constexpr (AF32) {
        // ---- depth-2 A pipeline (nchunk >= 2; Kp=512 -> 8) ----
        load_aA(0);
        stage(0, 0);                       // W(0)
        load_aB(1);
        store_aA(0);                       // compiler waits A(0) loads
        asm volatile("s_waitcnt vmcnt(4) lgkmcnt(0)" ::: "memory"); // W(0) done
        __builtin_amdgcn_s_barrier();
        __builtin_amdgcn_sched_barrier(0);

        int c = 0;
        while (true) {
            {   // even step: awB holds A(c+1)
                const int b = c & 1;
                const bool more = c + 1 < nchunk;
                const bool pf   = c + 2 < nchunk;
                if (more) stage(c + 1, b ^ 1);
                if (pf)   load_aA(c + 2);
                compute(b, 0);
                if (!more) break;
                store_aB(b ^ 1);
                if (pf) asm volatile("s_waitcnt vmcnt(4) lgkmcnt(0)" ::: "memory");
                else    asm volatile("s_waitcnt vmcnt(0) lgkmcnt(0)" ::: "memory");
                __builtin_amdgcn_s_barrier();
                __builtin_amdgcn_sched_barrier(0);
                ++c;
            }
            {   // odd step: awA holds A(c+1)
                const int b = c & 1;
                const bool more = c + 1 < nchunk;
                const bool pf   = c + 2 < nchunk;
                if (more) stage(c + 1, b ^ 1);
                if (pf)   load_aB(c + 2);
                compute(b, 0);
                if (!more) break;
                store_aA(b ^ 1);
                if (pf) asm volatile("s_waitcnt vmcnt(4) lgkmcnt(0)" ::: "memory");
                else    asm volatile("s_waitcnt vmcnt(0) lgkmcnt(0)" ::: "memory");
                __builtin_amdgcn_s_barrier();
                __builtin_amdgcn_sched_barrier(0);
                ++c;
            }
        }
    } else {
        // ---- f16-A path: gload_lds both tiles, 2-phase ----
        stage(0, 0);
        asm volatile("s_waitcnt vmcnt(0) lgkmcnt(0)" ::: "memory");
        __builtin_amdgcn_s_barrier();
        __builtin_amdgcn_sched_barrier(0);
        for (int c = 0; c < nchunk; ++c) {
            const int b = c & 1;
            const bool more = (c + 1 < nchunk);
            if (more) stage(c + 1, b ^ 1);
            compute(b, c * 64);
            if (more) {
                asm volatile("s_waitcnt vmcnt(0) lgkmcnt(0)" ::: "memory");
                __builtin_amdgcn_s_barrier();
                __builtin_amdgcn_sched_barrier(0);
            }
        }
    }

    // ---- epilogue: D lane map col=lane&15, row=(lane>>4)*4+r ----
    #pragma unroll
    for (int r = 0; r < 4; ++r) {
        int grow = row0 + wave * 16 + kg * 4 + r;
        if (grow >= M) continue;
        #pragma unroll
        for (int ct = 0; ct < CT; ++ct)
            C[(size_t)grow * NC + ct * 16 + lrow] = (_Float16)acc[ct][r];
    }
}

// ---------------- GCN aggregation (gather over CSR, f16 in/out) ----------------
// 4 nodes/wave (16 lanes x f16x8), software-pipelined edge records (R14).

__global__ void agg128_k(const _Float16* __restrict__ h, const float* __restrict__ invdeg,
                         const int* __restrict__ row_start, const int* __restrict__ cnt,
                         const int2* __restrict__ epk,
                         const float* __restrict__ bias, _Float16* __restrict__ out, int n) {
    const int grp = threadIdx.x >> 4;           // 0..15 node-groups per block
    const int l = threadIdx.x & 15;
    const int i = blockIdx.x * 16 + grp;
    if (i >= n) return;
    const int st = row_start[i], en = st + cnt[i];
    const float id = invdeg[i];
    const int c = l * 8;

    float a[8];
    {
        f16x8 hv = *(const f16x8*)(h + (size_t)i * 128 + c);
        #pragma unroll
        for (int j = 0; j < 8; ++j)
            a[j] = fmaf(id, (float)hv[j], bias[c + j]);
    }

    auto gfma = [&](int2 e0, int2 e1, int2 e2, int2 e3) {
        f16x8 v0 = *(const f16x8*)(h + (size_t)e0.x * 128 + c);
        f16x8 v1 = *(const f16x8*)(h + (size_t)e1.x * 128 + c);
        f16x8 v2 = *(const f16x8*)(h + (size_t)e2.x * 128 + c);
        f16x8 v3 = *(const f16x8*)(h + (size_t)e3.x * 128 + c);
        float w0 = __int_as_float(e0.y), w1 = __int_as_float(e1.y);
        float w2 = __int_as_float(e2.y), w3 = __int_as_float(e3.y);
        #pragma unroll
        for (int j = 0; j < 8; ++j) {
            a[j] = fmaf(w0, (float)v0[j], a[j]);
            a[j] = fmaf(w1, (float)v1[j], a[j]);
            a[j] = fmaf(w2, (float)v2[j], a[j]);
            a[j] = fmaf(w3, (float)v3[j], a[j]);
        }
    };

    int p = st;
    if (p + 3 < en) {
        int2 eA0 = epk[p], eA1 = epk[p + 1], eA2 = epk[p + 2], eA3 = epk[p + 3];
        while (p + 7 < en) {
            int2 eB0 = epk[p + 4], eB1 = epk[p + 5];
            int2 eB2 = epk[p + 6], eB3 = epk[p + 7];
            gfma(eA0, eA1, eA2, eA3);
            eA0 = eB0; eA1 = eB1; eA2 = eB2; eA3 = eB3;
            p += 4;
        }
        gfma(eA0, eA1, eA2, eA3);
        p += 4;
    }
    for (; p < en; ++p) {
        int2 e0 = epk[p];
        float w0 = __int_as_float(e0.y);
        f16x8 v0 = *(const f16x8*)(h + (size_t)e0.x * 128 + c);
        #pragma unroll
        for (int j = 0; j < 8; ++j)
            a[j] = fmaf(w0, (float)v0[j], a[j]);
    }
    f16x8 o;
    #pragma unroll
    for (int j = 0; j < 8; ++j) o[j] = (_Float16)a[j];
    *(f16x8*)(out + (size_t)i * 128 + c) = o;
}

// ---------------- BN stats over f16 activations (12.8 MB read) ----------------

__global__ void stats16_k(const _Float16* __restrict__ a, float* __restrict__ gsum,
                          float* __restrict__ gsq, int total8) {
    const int tid = threadIdx.x;
    float s[8] = {}, q[8] = {};
    for (int idx = blockIdx.x * 256 + tid; idx < total8; idx += gridDim.x * 256) {
        f16x8 v = *(const f16x8*)(a + (size_t)idx * 8);
        #pragma unroll
        for (int j = 0; j < 8; ++j) {
            float f = (float)v[j];
            s[j] += f;
            q[j] = fmaf(f, f, q[j]);
        }
    }
    __shared__ float red[2][16][16][8];     // [sum/sq][k-group][col-group][col]
    const int g = tid & 15, k = tid >> 4;
    #pragma unroll
    for (int j = 0; j < 8; ++j) {
        red[0][k][g][j] = s[j];
        red[1][k][g][j] = q[j];
    }
    __syncthreads();
    if (tid < 128) {
        const int g2 = tid & 15, j2 = tid >> 4;     // j2 in 0..7
        float ts = 0.f, tq = 0.f;
        #pragma unroll
        for (int k2 = 0; k2 < 16; ++k2) {
            ts += red[0][k2][g2][j2];
            tq += red[1][k2][g2][j2];
        }
        atomicAdd(&gsum[g2 * 8 + j2], ts);
        atomicAdd(&gsq[g2 * 8 + j2], tq);
    }
}

// ---- classifier agg (64 cols) + log_softmax; 8 nodes/wave, pipelined ----
// 8 lanes per node, f16x8 per lane (full row); shfl_xor d<=4 stays in-group.

__global__ void aggsm_k(const _Float16* __restrict__ h, const float* __restrict__ invdeg,
                        const int* __restrict__ row_start, const int* __restrict__ cnt,
                        const int2* __restrict__ epk,
                        const float* __restrict__ bias, float* __restrict__ out, int n) {
    const int grp = threadIdx.x >> 3;           // 0..31 node-groups per block
    const int l = threadIdx.x & 7;
    const int i = blockIdx.x * 32 + grp;
    if (i >= n) return;
    const int st = row_start[i], en = st + cnt[i];
    const float id = invdeg[i];
    const int c = l * 8;

    float a[8];
    {
        f16x8 hv = *(const f16x8*)(h + (size_t)i * 64 + c);
        #pragma unroll
        for (int j = 0; j < 8; ++j)
            a[j] = fmaf(id, (float)hv[j], bias[c + j]);
    }

    auto gfma = [&](int2 e0, int2 e1, int2 e2, int2 e3) {
        f16x8 v0 = *(const f16x8*)(h + (size_t)e0.x * 64 + c);
        f16x8 v1 = *(const f16x8*)(h + (size_t)e1.x * 64 + c);
        f16x8 v2 = *(const f16x8*)(h + (size_t)e2.x * 64 + c);
        f16x8 v3 = *(const f16x8*)(h + (size_t)e3.x * 64 + c);
        float w0 = __int_as_float(e0.y), w1 = __int_as_float(e1.y);
        float w2 = __int_as_float(e2.y), w3 = __int_as_float(e3.y);
        #pragma unroll
        for (int j = 0; j < 8; ++j) {
            a[j] = fmaf(w0, (float)v0[j], a[j]);
            a[j] = fmaf(w1, (float)v1[j], a[j]);
            a[j] = fmaf(w2, (float)v2[j], a[j]);
            a[j] = fmaf(w3, (float)v3[j], a[j]);
        }
    };

    int p = st;
    if (p + 3 < en) {
        int2 eA0 = epk[p], eA1 = epk[p + 1], eA2 = epk[p + 2], eA3 = epk[p + 3];
        while (p + 7 < en) {
            int2 eB0 = epk[p + 4], eB1 = epk[p + 5];
            int2 eB2 = epk[p + 6], eB3 = epk[p + 7];
            gfma(eA0, eA1, eA2, eA3);
            eA0 = eB0; eA1 = eB1; eA2 = eB2; eA3 = eB3;
            p += 4;
        }
        gfma(eA0, eA1, eA2, eA3);
        p += 4;
    }
    for (; p < en; ++p) {
        int2 e0 = epk[p];
        float w0 = __int_as_float(e0.y);
        f16x8 v0 = *(const f16x8*)(h + (size_t)e0.x * 64 + c);
        #pragma unroll
        for (int j = 0; j < 8; ++j)
            a[j] = fmaf(w0, (float)v0[j], a[j]);
    }

    // fused log_softmax over 64 cols held by this 8-lane group
    float m = a[0];
    #pragma unroll
    for (int j = 1; j < 8; ++j) m = fmaxf(m, a[j]);
    #pragma unroll
    for (int d = 4; d >= 1; d >>= 1) m = fmaxf(m, __shfl_xor(m, d, 64));
    float s = 0.f;
    float e[8];
    #pragma unroll
    for (int j = 0; j < 8; ++j) { e[j] = __expf(a[j] - m); s += e[j]; }
    #pragma unroll
    for (int d = 4; d >= 1; d >>= 1) s += __shfl_xor(s, d, 64);
    float ls = __logf(s);
    float4 o0 = make_float4(a[0] - m - ls, a[1] - m - ls,
                            a[2] - m - ls, a[3] - m - ls);
    float4 o1 = make_float4(a[4] - m - ls, a[5] - m - ls,
                            a[6] - m - ls, a[7] - m - ls);
    *(float4*)(out + (size_t)i * 64 + c)     = o0;
    *(float4*)(out + (size_t)i * 64 + c + 4) = o1;
}

// ---------------------------------------------------------------------------

extern "C" void kernel_launch(void* const* d_in, const int* in_sizes, int n_in,
                              void* d_out, int out_size, void* d_ws, size_t ws_size,
                              hipStream_t stream) {
    const float* x  = (const float*)d_in[0];
    const int*   ei = (const int*)d_in[1];
    const float* W0 = (const float*)d_in[2];
    const float* b0 = (const float*)d_in[3];
    const float* W1 = (const float*)d_in[4];
    const float* b1 = (const float*)d_in[5];
    const float* W2 = (const float*)d_in[6];
    const float* b2 = (const float*)d_in[7];

    const int IN = 500;
    const int n = in_sizes[0] / IN;      // 50000
    const int E = in_sizes[1] / 2;       // 640000
    const int* src = ei;
    const int* dst = ei + E;

    // ---- workspace bump allocator (256B aligned) ----
    char* p = (char*)d_ws;
    auto alloc = [&](size_t bytes) -> void* {
        char* r = p;
        p += (bytes + 255) & ~(size_t)255;
        return (void*)r;
    };
    _Float16*  hb1h    = (_Float16*)alloc((size_t)n * 128 * 2);  // GEMM out / agg in
    _Float16*  hb2a    = (_Float16*)alloc((size_t)n * 128 * 2);  // agg out (pre-BN f16)
    _Float16*  W0h     = (_Float16*)alloc((size_t)128 * 512 * 2);
    _Float16*  W1h     = (_Float16*)alloc((size_t)128 * 128 * 2);
    _Float16*  W2h     = (_Float16*)alloc((size_t)64 * 128 * 2);
    // deg_cnt + BN stat buffers allocated contiguously -> single memset
    int*   deg_cnt  = (int*)alloc((size_t)n * 4);
    float* gsum0    = (float*)alloc(128 * 4);
    float* gsq0     = (float*)alloc(128 * 4);
    float* gsum1    = (float*)alloc(128 * 4);
    float* gsq1     = (float*)alloc(128 * 4);
    char*  zero_end = p;
    float* dinv     = (float*)alloc((size_t)n * 4);
    float* invdeg   = (float*)alloc((size_t)n * 4);
    int*   row_st   = (int*)alloc((size_t)n * 4);
    int*   cursor   = (int*)alloc((size_t)n * 4);
    int*   within   = (int*)alloc((size_t)n * 4);
    int*   btot     = (int*)alloc(256 * 4);
    int2*  epk      = (int2*)alloc((size_t)E * 8);
    (void)ws_size; (void)n_in; (void)out_size;

    float* out = (float*)d_out;
    const float inv_n = 1.0f / (float)n;

    const int gE = (E + 255) / 256;      // 2500
    const int gN = (n + 255) / 256;
    const int nblk = (n + 511) / 512;
    const int gM = (n + 63) / 64;        // 782 blocks
    const int gA = (n + 15) / 16;        // 3125 blocks (agg128)
    const int gS = (n + 31) / 32;        // 1563 blocks (aggsm, 8 nodes/wave)

    // ---- graph prep + weight conversion (once per call) ----
    hipMemsetAsync(deg_cnt, 0, (size_t)(zero_end - (char*)deg_cnt), stream);
    countw_k<<<gE + 88, 256, 0, stream>>>(src, dst, deg_cnt, E, gE,
                                          W0, W0h, W1, W1h, W2, W2h);
    scan1_k<<<nblk, 512, 0, stream>>>(deg_cnt, within, btot, n);
    scan3_k<<<gN, 256, 0, stream>>>(within, btot, deg_cnt, row_st, cursor,
                                    dinv, invdeg, n);

    // ---- layer 0: GEMM0 + CSR fill in ONE launch (independent work) ----
    mgemm_k<128, false, true, true><<<gM + gE, 256, 0, stream>>>(
        x, W0h, hb1h, nullptr, nullptr, 0.f, n, 500, 512,
        src, dst, dinv, cursor, epk, E, gM);
    agg128_k<<<gA, 256, 0, stream>>>(hb1h, invdeg, row_st, deg_cnt, epk, b0, hb2a, n);
    stats16_k<<<256, 256, 0, stream>>>(hb2a, gsum0, gsq0, n * 16);

    // ---- layer 1 (BN0+ReLU fused into GEMM1's A path) ----
    mgemm_k<128, true, false, false><<<gM, 256, 0, stream>>>(
        hb2a, W1h, hb1h, gsum0, gsq0, inv_n, n, 128, 128,
        nullptr, nullptr, nullptr, nullptr, nullptr, 0, gM);
    agg128_k<<<gA, 256, 0, stream>>>(hb1h, invdeg, row_st, deg_cnt, epk, b1, hb2a, n);
    stats16_k<<<256, 256, 0, stream>>>(hb2a, gsum1, gsq1, n * 16);

    // ---- classifier (BN1+ReLU fused into GEMM2; log_softmax fused into agg) ----
    mgemm_k<64, true, false, false><<<gM, 256, 0, stream>>>(
        hb2a, W2h, hb1h, gsum1, gsq1, inv_n, n, 128, 128,
        nullptr, nullptr, nullptr, nullptr, nullptr, 0, gM);
    aggsm_k<<<gS, 256, 0, stream>>>(hb1h, invdeg, row_st, deg_cnt, epk, b2, out, n);
}